// Round 1
// 1474.696 us; speedup vs baseline: 1.0034x; 1.0034x over previous
//
#include <hip/hip_runtime.h>
#include <math.h>

// Problem constants
#define Bn   8
#define Sn   1024
#define Dn   512
#define Hn   8
#define DKn  64
#define Ln   6
#define DFFn 2048
#define Mn   (Bn * Sn)   // 8192 rows

typedef __bf16 bf16x8 __attribute__((ext_vector_type(8)));
typedef __bf16 bf16x4 __attribute__((ext_vector_type(4)));
typedef float  f32x4  __attribute__((ext_vector_type(4)));

// async global->LDS, 16B per lane. LDS dest must be wave-uniform base + lane*16.
__device__ __forceinline__ void gl_lds16(const void* g, void* l) {
    __builtin_amdgcn_global_load_lds(
        (const __attribute__((address_space(1))) void*)g,
        (__attribute__((address_space(3))) void*)l, 16, 0, 0);
}

// ---------------------------------------------------------------------------
// fp32 -> bf16 cast
// ---------------------------------------------------------------------------
__global__ __launch_bounds__(256) void k_cast_bf16(const float* __restrict__ in,
                                                   __bf16* __restrict__ out, int n) {
    int i = blockIdx.x * 256 + threadIdx.x;
    if (i < n) out[i] = (__bf16)in[i];
}

// ---------------------------------------------------------------------------
// All 4 weight matrices of one layer: W[K][N] fp32 -> Wt[N][K] bf16.
// 32x32 tiles, 32x8 threads. Tile ranges: Wq 768 | Wo 256 | W1 1024 | W2 1024.
// ---------------------------------------------------------------------------
__global__ __launch_bounds__(256) void k_trans_all(
    const float* __restrict__ qkv_w, const float* __restrict__ out_w,
    const float* __restrict__ w1, const float* __restrict__ w2,
    __bf16* __restrict__ Wq, __bf16* __restrict__ Wo,
    __bf16* __restrict__ W1o, __bf16* __restrict__ W2o)
{
    const int t = blockIdx.x;
    const float* src; __bf16* dst; int K, N, n0, k0;
    if (t < 768)       { src = qkv_w; dst = Wq;  K = 512;  N = 1536; int u = t;        n0 = (u % 48) * 32; k0 = (u / 48) * 32; }
    else if (t < 1024) { src = out_w; dst = Wo;  K = 512;  N = 512;  int u = t - 768;  n0 = (u % 16) * 32; k0 = (u / 16) * 32; }
    else if (t < 2048) { src = w1;    dst = W1o; K = 512;  N = 2048; int u = t - 1024; n0 = (u % 64) * 32; k0 = (u / 64) * 32; }
    else               { src = w2;    dst = W2o; K = 2048; N = 512;  int u = t - 2048; n0 = (u % 16) * 32; k0 = (u / 16) * 32; }

    __shared__ float tt[32][33];
    const int tx = threadIdx.x, ty = threadIdx.y;
    #pragma unroll
    for (int r = 0; r < 4; r++)
        tt[ty + 8 * r][tx] = src[(size_t)(k0 + ty + 8 * r) * N + n0 + tx];
    __syncthreads();
    #pragma unroll
    for (int r = 0; r < 4; r++)
        dst[(size_t)(n0 + ty + 8 * r) * K + k0 + tx] = (__bf16)tt[tx][ty + 8 * r];
}

// ---------------------------------------------------------------------------
// MFMA GEMM: C[M,N] = act(A[M,K]bf16 @ Bt[N,K]bf16^T + bias[N]fp32)
// Block: 256 thr = 4 waves (2x2). Tile: 128 x (JT*32). BK=64.
// A/B fragment: elem[j] = X[lane&15][ (lane>>4)*8 + j ]  (m97-verified)
// C/D: col = lane&15, row = (lane>>4)*4 + reg            (m89/m91-verified)
// VW=1 (QKV only): cols >=1024 are V -> also scatter into Vt[b*8+h][d][s].
// ---------------------------------------------------------------------------
template <int RELU, int OUTBF, int JT, int VW>
__global__ __launch_bounds__(256) void k_gemm_mfma(
    const __bf16* __restrict__ A, const __bf16* __restrict__ Bt,
    const float* __restrict__ bias, void* __restrict__ Cout,
    __bf16* __restrict__ Vt, int M, int N, int K)
{
    constexpr int BN = JT * 32;   // 128 or 64
    __shared__ __bf16 As[128][64];
    __shared__ __bf16 Bs[BN][64];
    const int tid  = threadIdx.x;
    const int lane = tid & 63;
    const int wave = tid >> 6;
    const int wy   = wave >> 1, wx = wave & 1;
    const int m16  = lane & 15, quad = lane >> 4;
    const int bm   = blockIdx.y * 128, bn = blockIdx.x * BN;

    f32x4 acc[4][JT];
    #pragma unroll
    for (int i = 0; i < 4; i++)
        #pragma unroll
        for (int j = 0; j < JT; j++)
            acc[i][j] = (f32x4){0.f, 0.f, 0.f, 0.f};

    const __bf16* Ap = A  + (size_t)bm * K;
    const __bf16* Bp = Bt + (size_t)bn * K;

    for (int k0 = 0; k0 < K; k0 += 64) {
        __syncthreads();
        #pragma unroll
        for (int c = 0; c < 4; c++) {           // A: 128x64 bf16 = 1024 x 16B
            int lin = tid + c * 256;
            int row = lin >> 3, kc = (lin & 7) << 3;
            gl_lds16(Ap + (size_t)row * K + k0 + kc, (void*)(&As[0][0] + lin * 8));
        }
        #pragma unroll
        for (int c = 0; c < JT; c++) {          // B: BNx64 bf16
            int lin = tid + c * 256;
            int row = lin >> 3, kc = (lin & 7) << 3;
            gl_lds16(Bp + (size_t)row * K + k0 + kc, (void*)(&Bs[0][0] + lin * 8));
        }
        __syncthreads();

        bf16x8 af[4][2], bfr[JT][2];
        #pragma unroll
        for (int i = 0; i < 4; i++) {
            af[i][0] = *(const bf16x8*)&As[wy * 64 + i * 16 + m16][quad * 8];
            af[i][1] = *(const bf16x8*)&As[wy * 64 + i * 16 + m16][32 + quad * 8];
        }
        #pragma unroll
        for (int j = 0; j < JT; j++) {
            bfr[j][0] = *(const bf16x8*)&Bs[wx * JT * 16 + j * 16 + m16][quad * 8];
            bfr[j][1] = *(const bf16x8*)&Bs[wx * JT * 16 + j * 16 + m16][32 + quad * 8];
        }
        #pragma unroll
        for (int hc = 0; hc < 2; hc++)
            #pragma unroll
            for (int i = 0; i < 4; i++)
                #pragma unroll
                for (int j = 0; j < JT; j++)
                    acc[i][j] = __builtin_amdgcn_mfma_f32_16x16x32_bf16(
                        af[i][hc], bfr[j][hc], acc[i][j], 0, 0, 0);
    }

    float*  Cf = (float*)Cout;
    __bf16* Cb = (__bf16*)Cout;
    #pragma unroll
    for (int i = 0; i < 4; i++) {
        const int row0 = bm + wy * 64 + i * 16 + quad * 4;
        #pragma unroll
        for (int j = 0; j < JT; j++) {
            const int col = bn + wx * JT * 16 + j * 16 + m16;
            const float bv = bias[col];
            float vv[4];
            #pragma unroll
            for (int r = 0; r < 4; r++) {
                float v = acc[i][j][r] + bv;
                if (RELU) v = fmaxf(v, 0.f);
                vv[r] = v;
                if (OUTBF) Cb[(size_t)(row0 + r) * N + col] = (__bf16)v;
                else       Cf[(size_t)(row0 + r) * N + col] = v;
            }
            if (VW && col >= 1024) {            // V slice -> Vt[b*8+h][d][s]
                const int cc = col - 1024;
                const int bb = row0 >> 10, ss = row0 & 1023;
                bf16x4 pv;
                #pragma unroll
                for (int r = 0; r < 4; r++) pv[r] = (__bf16)vv[r];
                *(bf16x4*)&Vt[((size_t)(bb * Hn + (cc >> 6)) * DKn + (cc & 63)) * Sn + ss] = pv;
            }
        }
    }
}

// ---------------------------------------------------------------------------
// Barrier-free MFMA flash attention (causal), register-prefetched.
// qkv: [M][1536] bf16; Vt: [b*8+h][64][1024] bf16.
// Block = (pair pr, h, b): handles q-tiles qtA=pr and qtB=15-pr (uniform 17
// MFMA-tiles). 4 waves, wave w owns q-rows w*16..+15 of each tile.
// v2: K[kt+1] and V[kt+1] fragments are PREFETCHED into a second register
// buffer while kt's QK/softmax/PV executes (grid-limited occupancy leaves
// ~128 spare VGPRs, so the double-buffer is free). A/B tiles get separate
// P scratch so the two softmax LDS round-trips don't serialize on in-order DS.
// s_setprio(1) wraps the MFMA clusters (T5: barrier-free waves at different
// phases -> scheduler favors the MFMA-issuing wave).
// ---------------------------------------------------------------------------
__device__ __forceinline__ void softmax_update(
    f32x4 sv[4], float m[4], float l[4], f32x4 acc[4],
    bool diag, int wave16, int quad, int m16,
    __bf16 (*Pw)[72], bf16x8& pf0, bf16x8& pf1)
{
    #pragma unroll
    for (int j = 0; j < 4; j++)
        #pragma unroll
        for (int r = 0; r < 4; r++) {
            float v = sv[j][r] * 0.125f;    // 1/sqrt(64)
            if (diag && (j * 16 + m16) > (wave16 + quad * 4 + r)) v = -1e30f;
            sv[j][r] = v;
        }

    float pm[4];
    #pragma unroll
    for (int r = 0; r < 4; r++)
        pm[r] = fmaxf(fmaxf(sv[0][r], sv[1][r]), fmaxf(sv[2][r], sv[3][r]));
    #pragma unroll
    for (int off = 1; off < 16; off <<= 1)
        #pragma unroll
        for (int r = 0; r < 4; r++)
            pm[r] = fmaxf(pm[r], __shfl_xor(pm[r], off, 16));

    float al[4];
    #pragma unroll
    for (int r = 0; r < 4; r++) {
        float mn = fmaxf(m[r], pm[r]);
        al[r] = __expf(m[r] - mn);
        m[r] = mn;
    }

    float rs[4] = {0.f, 0.f, 0.f, 0.f};
    #pragma unroll
    for (int j = 0; j < 4; j++)
        #pragma unroll
        for (int r = 0; r < 4; r++) {
            float p = __expf(sv[j][r] - m[r]);
            rs[r] += p;
            Pw[quad * 4 + r][j * 16 + m16] = (__bf16)p;
        }
    #pragma unroll
    for (int off = 1; off < 16; off <<= 1)
        #pragma unroll
        for (int r = 0; r < 4; r++)
            rs[r] += __shfl_xor(rs[r], off, 16);
    #pragma unroll
    for (int r = 0; r < 4; r++) l[r] = l[r] * al[r] + rs[r];

    #pragma unroll
    for (int j = 0; j < 4; j++)
        #pragma unroll
        for (int r = 0; r < 4; r++) acc[j][r] *= al[r];

    pf0 = *(const bf16x8*)&Pw[m16][quad * 8];
    pf1 = *(const bf16x8*)&Pw[m16][32 + quad * 8];
}

__device__ __forceinline__ void load_kfrag(const __bf16* __restrict__ base,
                                           int kt, int m16, int quad,
                                           bf16x8 (&kf)[4][2])
{
    #pragma unroll
    for (int j = 0; j < 4; j++) {
        const __bf16* kp = base + (size_t)(kt * 64 + j * 16 + m16) * 1536 + 512 + quad * 8;
        kf[j][0] = *(const bf16x8*)kp;
        kf[j][1] = *(const bf16x8*)(kp + 32);
    }
}

__device__ __forceinline__ void load_vfrag(const __bf16* __restrict__ vtb,
                                           int kt, int m16, int quad,
                                           bf16x8 (&vf)[4][2])
{
    #pragma unroll
    for (int jd = 0; jd < 4; jd++) {
        const __bf16* vp = vtb + (size_t)(jd * 16 + m16) * Sn + kt * 64 + quad * 8;
        vf[jd][0] = *(const bf16x8*)vp;
        vf[jd][1] = *(const bf16x8*)(vp + 32);
    }
}

// One k-tile step: prefetch kt+1 into (KN,VN), compute with (KC,VC).
#define ATTN_STEP(KT, KC, VC, KN, VN)                                              \
    {                                                                              \
        const int kt_ = (KT);                                                      \
        const bool actA = (kt_ <= qtA);                                            \
        if (kt_ + 1 <= qtB) {                                                      \
            load_kfrag(base, kt_ + 1, m16, quad, KN);                              \
            load_vfrag(vtb, kt_ + 1, m16, quad, VN);                               \
        }                                                                          \
        f32x4 svA[4], svB[4];                                                      \
        __builtin_amdgcn_s_setprio(1);                                             \
        _Pragma("unroll")                                                          \
        for (int j = 0; j < 4; j++) {                                              \
            f32x4 s = (f32x4){0.f, 0.f, 0.f, 0.f};                                 \
            s = __builtin_amdgcn_mfma_f32_16x16x32_bf16(qB0, KC[j][0], s, 0, 0, 0);\
            s = __builtin_amdgcn_mfma_f32_16x16x32_bf16(qB1, KC[j][1], s, 0, 0, 0);\
            svB[j] = s;                                                            \
            if (actA) {                                                            \
                f32x4 s2 = (f32x4){0.f, 0.f, 0.f, 0.f};                            \
                s2 = __builtin_amdgcn_mfma_f32_16x16x32_bf16(qA0, KC[j][0], s2, 0, 0, 0); \
                s2 = __builtin_amdgcn_mfma_f32_16x16x32_bf16(qA1, KC[j][1], s2, 0, 0, 0); \
                svA[j] = s2;                                                       \
            }                                                                      \
        }                                                                          \
        __builtin_amdgcn_s_setprio(0);                                             \
        bf16x8 pB0, pB1, pA0, pA1;                                                 \
        softmax_update(svB, mB, lB, accB, kt_ == qtB, wave16, quad, m16, PsB, pB0, pB1); \
        if (actA)                                                                  \
            softmax_update(svA, mA, lA, accA, kt_ == qtA, wave16, quad, m16, PsA, pA0, pA1); \
        __builtin_amdgcn_s_setprio(1);                                             \
        _Pragma("unroll")                                                          \
        for (int jd = 0; jd < 4; jd++) {                                           \
            accB[jd] = __builtin_amdgcn_mfma_f32_16x16x32_bf16(pB0, VC[jd][0], accB[jd], 0, 0, 0); \
            accB[jd] = __builtin_amdgcn_mfma_f32_16x16x32_bf16(pB1, VC[jd][1], accB[jd], 0, 0, 0); \
            if (actA) {                                                            \
                accA[jd] = __builtin_amdgcn_mfma_f32_16x16x32_bf16(pA0, VC[jd][0], accA[jd], 0, 0, 0); \
                accA[jd] = __builtin_amdgcn_mfma_f32_16x16x32_bf16(pA1, VC[jd][1], accA[jd], 0, 0, 0); \
            }                                                                      \
        }                                                                          \
        __builtin_amdgcn_s_setprio(0);                                             \
    }

__global__ __launch_bounds__(256) void k_attn_mfma(
    const __bf16* __restrict__ qkv, const __bf16* __restrict__ Vt,
    __bf16* __restrict__ o)
{
    const int pr  = blockIdx.x;          // 0..7
    const int h   = blockIdx.y;
    const int b   = blockIdx.z;
    const int tid  = threadIdx.x;
    const int lane = tid & 63, wave = tid >> 6;
    const int m16  = lane & 15, quad = lane >> 4;
    const int qtA  = pr, qtB = 15 - pr;
    const int wave16 = wave * 16;

    __shared__ __bf16 Ps[4][2][16][72];  // per-wave, per-tile P scratch

    const __bf16* base = qkv + (size_t)b * Sn * 1536 + h * DKn;   // Q +0, K +512
    const __bf16* vtb  = Vt + (size_t)(b * Hn + h) * DKn * Sn;

    __bf16 (*PsA)[72] = Ps[wave][0];
    __bf16 (*PsB)[72] = Ps[wave][1];

    bf16x8 qA0, qA1, qB0, qB1;
    {
        const __bf16* qa = base + (size_t)(qtA * 64 + wave16 + m16) * 1536 + quad * 8;
        qA0 = *(const bf16x8*)qa; qA1 = *(const bf16x8*)(qa + 32);
        const __bf16* qb = base + (size_t)(qtB * 64 + wave16 + m16) * 1536 + quad * 8;
        qB0 = *(const bf16x8*)qb; qB1 = *(const bf16x8*)(qb + 32);
    }

    float mA[4], lA[4], mB[4], lB[4];
    f32x4 accA[4], accB[4];
    #pragma unroll
    for (int r = 0; r < 4; r++) {
        mA[r] = -1e30f; lA[r] = 0.f; mB[r] = -1e30f; lB[r] = 0.f;
        accA[r] = (f32x4){0.f, 0.f, 0.f, 0.f};
        accB[r] = (f32x4){0.f, 0.f, 0.f, 0.f};
    }

    // register double-buffers for K and V fragments
    bf16x8 kf0[4][2], kf1[4][2], vf0[4][2], vf1[4][2];
    load_kfrag(base, 0, m16, quad, kf0);
    load_vfrag(vtb, 0, m16, quad, vf0);

    for (int kt = 0; kt <= qtB; kt += 2) {
        ATTN_STEP(kt, kf0, vf0, kf1, vf1);
        if (kt + 1 <= qtB)
            ATTN_STEP(kt + 1, kf1, vf1, kf0, vf0);
    }

    // epilogue: O / l for both tiles
    #pragma unroll
    for (int r = 0; r < 4; r++) { lA[r] = 1.0f / lA[r]; lB[r] = 1.0f / lB[r]; }
    #pragma unroll
    for (int jd = 0; jd < 4; jd++)
        #pragma unroll
        for (int r = 0; r < 4; r++) {
            const int rowA = b * Sn + qtA * 64 + wave16 + quad * 4 + r;
            const int rowB = b * Sn + qtB * 64 + wave16 + quad * 4 + r;
            o[(size_t)rowA * Dn + h * DKn + jd * 16 + m16] = (__bf16)(accA[jd][r] * lA[r]);
            o[(size_t)rowB * Dn + h * DKn + jd * 16 + m16] = (__bf16)(accB[jd][r] * lB[r]);
        }
}

// ---------------------------------------------------------------------------
// x = LayerNorm(t + x); writes fp32 x and bf16 copy xb.
// ---------------------------------------------------------------------------
__device__ inline float block_reduce_sum(float v, float* red, int tid) {
    red[tid] = v;
    __syncthreads();
    for (int s = 128; s > 0; s >>= 1) {
        if (tid < s) red[tid] += red[tid + s];
        __syncthreads();
    }
    float r = red[0];
    __syncthreads();
    return r;
}

__global__ __launch_bounds__(256) void k_residual_ln(
    const float* __restrict__ t, float* __restrict__ x, __bf16* __restrict__ xb,
    const float* __restrict__ g, const float* __restrict__ be)
{
    __shared__ float red[256];
    const int row = blockIdx.x, tid = threadIdx.x;
    const size_t base = (size_t)row * Dn;

    float v0 = t[base + tid] + x[base + tid];
    float v1 = t[base + 256 + tid] + x[base + 256 + tid];

    float mean = block_reduce_sum(v0 + v1, red, tid) * (1.0f / Dn);
    float d0 = v0 - mean, d1 = v1 - mean;
    float var = block_reduce_sum(d0 * d0 + d1 * d1, red, tid) * (1.0f / Dn);
    float inv = rsqrtf(var + 1e-5f);

    float o0 = d0 * inv * g[tid]       + be[tid];
    float o1 = d1 * inv * g[256 + tid] + be[256 + tid];
    x[base + tid]        = o0;
    x[base + 256 + tid]  = o1;
    xb[base + tid]       = (__bf16)o0;
    xb[base + 256 + tid] = (__bf16)o1;
}

// ---------------------------------------------------------------------------
// launcher
// ---------------------------------------------------------------------------
extern "C" void kernel_launch(void* const* d_in, const int* in_sizes, int n_in,
                              void* d_out, int out_size, void* d_ws, size_t ws_size,
                              hipStream_t stream)
{
    const float* x_in   = (const float*)d_in[0];
    const float* qkv_w  = (const float*)d_in[1];
    const float* qkv_b  = (const float*)d_in[2];
    const float* out_w  = (const float*)d_in[3];
    const float* out_b  = (const float*)d_in[4];
    const float* ln1_g  = (const float*)d_in[5];
    const float* ln1_b  = (const float*)d_in[6];
    const float* mlp_w1 = (const float*)d_in[7];
    const float* mlp_b1 = (const float*)d_in[8];
    const float* mlp_w2 = (const float*)d_in[9];
    const float* mlp_b2 = (const float*)d_in[10];
    const float* ln2_g  = (const float*)d_in[11];
    const float* ln2_b  = (const float*)d_in[12];

    // workspace layout (~94 MB)
    char* p = (char*)d_ws;
    float*  X    = (float*)p;  p += (size_t)Mn * Dn * 4;        // 16 MB fp32 residual
    __bf16* Xb   = (__bf16*)p; p += (size_t)Mn * Dn * 2;        //  8 MB bf16 x
    __bf16* QKVb = (__bf16*)p; p += (size_t)Mn * 3 * Dn * 2;    // 24 MB
    __bf16* AOb  = (__bf16*)p; p += (size_t)Mn * Dn * 2;        //  8 MB attn out
    __bf16* Hb   = (__bf16*)p; p += (size_t)Mn * DFFn * 2;      // 32 MB mlp hidden
    __bf16* Wq   = (__bf16*)p; p += (size_t)3 * Dn * Dn * 2;    // 1.5 MB  [1536][512]
    __bf16* Wo   = (__bf16*)p; p += (size_t)Dn * Dn * 2;        // 0.5 MB  [512][512]
    __bf16* W1   = (__bf16*)p; p += (size_t)DFFn * Dn * 2;      // 2 MB    [2048][512]
    __bf16* W2   = (__bf16*)p; p += (size_t)Dn * DFFn * 2;      // 2 MB    [512][2048]
    __bf16* Vt   = Hb;             // 8 MB, aliased: Hb dead during attention
    float* BUF3 = (float*)d_out;   // pre-LN temp lives in d_out

    const size_t xBytes = (size_t)Mn * Dn * sizeof(float);
    hipMemcpyAsync(X, x_in, xBytes, hipMemcpyDeviceToDevice, stream);
    k_cast_bf16<<<(Mn * Dn) / 256, 256, 0, stream>>>(x_in, Xb, Mn * Dn);

    for (int l = 0; l < Ln; l++) {
        // all 4 weight transposes in one launch
        k_trans_all<<<3072, dim3(32, 8), 0, stream>>>(
            qkv_w + (size_t)l * Dn * 3 * Dn, out_w + (size_t)l * Dn * Dn,
            mlp_w1 + (size_t)l * Dn * DFFn, mlp_w2 + (size_t)l * DFFn * Dn,
            Wq, Wo, W1, W2);

        // QKV projection -> bf16 [M,1536] + fused Vt scatter
        k_gemm_mfma<0, 1, 4, 1><<<dim3(12, 64), 256, 0, stream>>>(
            Xb, Wq, qkv_b + (size_t)l * 3 * Dn, QKVb, Vt, Mn, 3 * Dn, Dn);
        // barrier-free MFMA flash attention -> bf16 [M,512]
        k_attn_mfma<<<dim3(8, Hn, Bn), 256, 0, stream>>>(QKVb, Vt, AOb);
        // output projection -> fp32 BUF3
        k_gemm_mfma<0, 0, 2, 0><<<dim3(8, 64), 256, 0, stream>>>(
            AOb, Wo, out_b + (size_t)l * Dn, BUF3, nullptr, Mn, Dn, Dn);
        // x = LN(proj + x)
        k_residual_ln<<<Mn, 256, 0, stream>>>(BUF3, X, Xb,
            ln1_g + (size_t)l * Dn, ln1_b + (size_t)l * Dn);
        // MLP up + ReLU -> bf16 [M,2048]  (overwrites Vt alias; attn done)
        k_gemm_mfma<1, 1, 4, 0><<<dim3(16, 64), 256, 0, stream>>>(
            Xb, W1, mlp_b1 + (size_t)l * DFFn, Hb, nullptr, Mn, DFFn, Dn);
        // MLP down -> fp32 BUF3
        k_gemm_mfma<0, 0, 2, 0><<<dim3(8, 64), 256, 0, stream>>>(
            Hb, W2, mlp_b2 + (size_t)l * Dn, BUF3, nullptr, Mn, Dn, DFFn);
        // x = LN(x + mlp)
        k_residual_ln<<<Mn, 256, 0, stream>>>(BUF3, X, Xb,
            ln2_g + (size_t)l * Dn, ln2_b + (size_t)l * Dn);
    }

    hipMemcpyAsync(d_out, X, xBytes, hipMemcpyDeviceToDevice, stream);
}

// Round 2
// 1281.197 us; speedup vs baseline: 1.1550x; 1.1510x over previous
//
#include <hip/hip_runtime.h>
#include <math.h>

// Problem constants
#define Bn   8
#define Sn   1024
#define Dn   512
#define Hn   8
#define DKn  64
#define Ln   6
#define DFFn 2048
#define Mn   (Bn * Sn)   // 8192 rows

typedef __bf16 bf16x8 __attribute__((ext_vector_type(8)));
typedef __bf16 bf16x4 __attribute__((ext_vector_type(4)));
typedef float  f32x4  __attribute__((ext_vector_type(4)));

// async global->LDS, 16B per lane. LDS dest must be wave-uniform base + lane*16.
__device__ __forceinline__ void gl_lds16(const void* g, void* l) {
    __builtin_amdgcn_global_load_lds(
        (const __attribute__((address_space(1))) void*)g,
        (__attribute__((address_space(3))) void*)l, 16, 0, 0);
}

// ---------------------------------------------------------------------------
// fp32 -> bf16 cast
// ---------------------------------------------------------------------------
__global__ __launch_bounds__(256) void k_cast_bf16(const float* __restrict__ in,
                                                   __bf16* __restrict__ out, int n) {
    int i = blockIdx.x * 256 + threadIdx.x;
    if (i < n) out[i] = (__bf16)in[i];
}

// ---------------------------------------------------------------------------
// All 4 weight matrices of one layer: W[K][N] fp32 -> Wt[N][K] bf16.
// 32x32 tiles, 32x8 threads. Tile ranges: Wq 768 | Wo 256 | W1 1024 | W2 1024.
// ---------------------------------------------------------------------------
__global__ __launch_bounds__(256) void k_trans_all(
    const float* __restrict__ qkv_w, const float* __restrict__ out_w,
    const float* __restrict__ w1, const float* __restrict__ w2,
    __bf16* __restrict__ Wq, __bf16* __restrict__ Wo,
    __bf16* __restrict__ W1o, __bf16* __restrict__ W2o)
{
    const int t = blockIdx.x;
    const float* src; __bf16* dst; int K, N, n0, k0;
    if (t < 768)       { src = qkv_w; dst = Wq;  K = 512;  N = 1536; int u = t;        n0 = (u % 48) * 32; k0 = (u / 48) * 32; }
    else if (t < 1024) { src = out_w; dst = Wo;  K = 512;  N = 512;  int u = t - 768;  n0 = (u % 16) * 32; k0 = (u / 16) * 32; }
    else if (t < 2048) { src = w1;    dst = W1o; K = 512;  N = 2048; int u = t - 1024; n0 = (u % 64) * 32; k0 = (u / 64) * 32; }
    else               { src = w2;    dst = W2o; K = 2048; N = 512;  int u = t - 2048; n0 = (u % 16) * 32; k0 = (u / 16) * 32; }

    __shared__ float tt[32][33];
    const int tx = threadIdx.x, ty = threadIdx.y;
    #pragma unroll
    for (int r = 0; r < 4; r++)
        tt[ty + 8 * r][tx] = src[(size_t)(k0 + ty + 8 * r) * N + n0 + tx];
    __syncthreads();
    #pragma unroll
    for (int r = 0; r < 4; r++)
        dst[(size_t)(n0 + ty + 8 * r) * K + k0 + tx] = (__bf16)tt[tx][ty + 8 * r];
}

// ---------------------------------------------------------------------------
// MFMA GEMM: C[M,N] = act(A[M,K]bf16 @ Bt[N,K]bf16^T + bias[N]fp32)
// Block: 256 thr = 4 waves (2x2). Tile: 128 x (JT*32). BK=64.
// A/B fragment: elem[j] = X[lane&15][ (lane>>4)*8 + j ]  (m97-verified)
// C/D: col = lane&15, row = (lane>>4)*4 + reg            (m89/m91-verified)
// VW=1 (QKV only): cols >=1024 are V -> also scatter into Vt[b*8+h][d][s].
// ---------------------------------------------------------------------------
template <int RELU, int OUTBF, int JT, int VW>
__global__ __launch_bounds__(256) void k_gemm_mfma(
    const __bf16* __restrict__ A, const __bf16* __restrict__ Bt,
    const float* __restrict__ bias, void* __restrict__ Cout,
    __bf16* __restrict__ Vt, int M, int N, int K)
{
    constexpr int BN = JT * 32;   // 128 or 64
    __shared__ __bf16 As[128][64];
    __shared__ __bf16 Bs[BN][64];
    const int tid  = threadIdx.x;
    const int lane = tid & 63;
    const int wave = tid >> 6;
    const int wy   = wave >> 1, wx = wave & 1;
    const int m16  = lane & 15, quad = lane >> 4;
    const int bm   = blockIdx.y * 128, bn = blockIdx.x * BN;

    f32x4 acc[4][JT];
    #pragma unroll
    for (int i = 0; i < 4; i++)
        #pragma unroll
        for (int j = 0; j < JT; j++)
            acc[i][j] = (f32x4){0.f, 0.f, 0.f, 0.f};

    const __bf16* Ap = A  + (size_t)bm * K;
    const __bf16* Bp = Bt + (size_t)bn * K;

    for (int k0 = 0; k0 < K; k0 += 64) {
        __syncthreads();
        #pragma unroll
        for (int c = 0; c < 4; c++) {           // A: 128x64 bf16 = 1024 x 16B
            int lin = tid + c * 256;
            int row = lin >> 3, kc = (lin & 7) << 3;
            gl_lds16(Ap + (size_t)row * K + k0 + kc, (void*)(&As[0][0] + lin * 8));
        }
        #pragma unroll
        for (int c = 0; c < JT; c++) {          // B: BNx64 bf16
            int lin = tid + c * 256;
            int row = lin >> 3, kc = (lin & 7) << 3;
            gl_lds16(Bp + (size_t)row * K + k0 + kc, (void*)(&Bs[0][0] + lin * 8));
        }
        __syncthreads();

        bf16x8 af[4][2], bfr[JT][2];
        #pragma unroll
        for (int i = 0; i < 4; i++) {
            af[i][0] = *(const bf16x8*)&As[wy * 64 + i * 16 + m16][quad * 8];
            af[i][1] = *(const bf16x8*)&As[wy * 64 + i * 16 + m16][32 + quad * 8];
        }
        #pragma unroll
        for (int j = 0; j < JT; j++) {
            bfr[j][0] = *(const bf16x8*)&Bs[wx * JT * 16 + j * 16 + m16][quad * 8];
            bfr[j][1] = *(const bf16x8*)&Bs[wx * JT * 16 + j * 16 + m16][32 + quad * 8];
        }
        #pragma unroll
        for (int hc = 0; hc < 2; hc++)
            #pragma unroll
            for (int i = 0; i < 4; i++)
                #pragma unroll
                for (int j = 0; j < JT; j++)
                    acc[i][j] = __builtin_amdgcn_mfma_f32_16x16x32_bf16(
                        af[i][hc], bfr[j][hc], acc[i][j], 0, 0, 0);
    }

    float*  Cf = (float*)Cout;
    __bf16* Cb = (__bf16*)Cout;
    #pragma unroll
    for (int i = 0; i < 4; i++) {
        const int row0 = bm + wy * 64 + i * 16 + quad * 4;
        #pragma unroll
        for (int j = 0; j < JT; j++) {
            const int col = bn + wx * JT * 16 + j * 16 + m16;
            const float bv = bias[col];
            float vv[4];
            #pragma unroll
            for (int r = 0; r < 4; r++) {
                float v = acc[i][j][r] + bv;
                if (RELU) v = fmaxf(v, 0.f);
                vv[r] = v;
                if (OUTBF) Cb[(size_t)(row0 + r) * N + col] = (__bf16)v;
                else       Cf[(size_t)(row0 + r) * N + col] = v;
            }
            if (VW && col >= 1024) {            // V slice -> Vt[b*8+h][d][s]
                const int cc = col - 1024;
                const int bb = row0 >> 10, ss = row0 & 1023;
                bf16x4 pv;
                #pragma unroll
                for (int r = 0; r < 4; r++) pv[r] = (__bf16)vv[r];
                *(bf16x4*)&Vt[((size_t)(bb * Hn + (cc >> 6)) * DKn + (cc & 63)) * Sn + ss] = pv;
            }
        }
    }
}

// ---------------------------------------------------------------------------
// MFMA flash attention (causal), LDS-staged K/V.
// qkv: [M][1536] bf16; Vt: [b*8+h][64][1024] bf16.
// Block = (pair pr, h, b): q-tiles qtA=pr, qtB=15-pr (uniform 17 MFMA-tiles).
// 4 waves; wave w owns q-rows w*16..+15 of each tile.
// v3: K/V tiles staged ONCE per block into LDS via global_load_lds
// (v1/v2 had all 4 waves redundantly loading identical 16-line-scattered
// fragments from global -> request-throughput bound, 4x duplicated).
// Double-buffered LDS, one __syncthreads per k-step (proven GEMM pattern:
// barrier drains vmcnt). XOR swizzle u^=(row&7) applied BOTH sides
// (pre-swizzled global source for the linear gl_lds16 dest + swizzled
// ds_read) -> fragment reads spread evenly over all 8 16B slots per row.
// Grid linearized so id%8==h: all 8 pr-blocks of one (b,h) share an XCD L2.
// ---------------------------------------------------------------------------
__device__ __forceinline__ void softmax_update(
    f32x4 sv[4], float m[4], float l[4], f32x4 acc[4],
    bool diag, int wave16, int quad, int m16,
    __bf16 (*Pw)[72], bf16x8& pf0, bf16x8& pf1)
{
    #pragma unroll
    for (int j = 0; j < 4; j++)
        #pragma unroll
        for (int r = 0; r < 4; r++) {
            float v = sv[j][r] * 0.125f;    // 1/sqrt(64)
            if (diag && (j * 16 + m16) > (wave16 + quad * 4 + r)) v = -1e30f;
            sv[j][r] = v;
        }

    float pm[4];
    #pragma unroll
    for (int r = 0; r < 4; r++)
        pm[r] = fmaxf(fmaxf(sv[0][r], sv[1][r]), fmaxf(sv[2][r], sv[3][r]));
    #pragma unroll
    for (int off = 1; off < 16; off <<= 1)
        #pragma unroll
        for (int r = 0; r < 4; r++)
            pm[r] = fmaxf(pm[r], __shfl_xor(pm[r], off, 16));

    float al[4];
    #pragma unroll
    for (int r = 0; r < 4; r++) {
        float mn = fmaxf(m[r], pm[r]);
        al[r] = __expf(m[r] - mn);
        m[r] = mn;
    }

    float rs[4] = {0.f, 0.f, 0.f, 0.f};
    #pragma unroll
    for (int j = 0; j < 4; j++)
        #pragma unroll
        for (int r = 0; r < 4; r++) {
            float p = __expf(sv[j][r] - m[r]);
            rs[r] += p;
            Pw[quad * 4 + r][j * 16 + m16] = (__bf16)p;
        }
    #pragma unroll
    for (int off = 1; off < 16; off <<= 1)
        #pragma unroll
        for (int r = 0; r < 4; r++)
            rs[r] += __shfl_xor(rs[r], off, 16);
    #pragma unroll
    for (int r = 0; r < 4; r++) l[r] = l[r] * al[r] + rs[r];

    #pragma unroll
    for (int j = 0; j < 4; j++)
        #pragma unroll
        for (int r = 0; r < 4; r++) acc[j][r] *= al[r];

    pf0 = *(const bf16x8*)&Pw[m16][quad * 8];
    pf1 = *(const bf16x8*)&Pw[m16][32 + quad * 8];
}

__global__ __launch_bounds__(256) void k_attn_mfma(
    const __bf16* __restrict__ qkv, const __bf16* __restrict__ Vt,
    __bf16* __restrict__ o)
{
    const int id = blockIdx.x;
    const int pr = id >> 6;            // 0..7
    const int b  = (id >> 3) & 7;
    const int h  = id & 7;             // id%8 = h -> pr/b blocks of one h share an XCD
    const int tid  = threadIdx.x;
    const int lane = tid & 63, wave = tid >> 6;
    const int m16  = lane & 15, quad = lane >> 4;
    const int qtA  = pr, qtB = 15 - pr;
    const int wave16 = wave * 16;

    __shared__ __bf16 Kb[2][64][64];     // double-buffered K tile (swizzled)
    __shared__ __bf16 Vb[2][64][64];     // double-buffered V tile (swizzled)
    __shared__ __bf16 Ps[4][2][16][72];  // per-wave, per-tile P scratch

    const __bf16* base = qkv + (size_t)b * Sn * 1536 + h * DKn;   // Q +0, K +512
    const __bf16* vtb  = Vt + (size_t)(b * Hn + h) * DKn * Sn;

    __bf16 (*PsA)[72] = Ps[wave][0];
    __bf16 (*PsB)[72] = Ps[wave][1];

    // swizzled 16B-unit offsets for fragment reads (involution of stage swizzle)
    const int sw0 = ((quad    ) ^ (m16 & 7)) * 8;
    const int sw1 = ((quad + 4) ^ (m16 & 7)) * 8;

    // stage K and V tile KT into LDS buffer BB. Linear LDS dest (gl_lds16
    // requirement), global source pre-swizzled: unit u' = u ^ (row&7).
    #define STAGE(KT, BB)                                                       \
        {                                                                       \
            _Pragma("unroll")                                                   \
            for (int c = 0; c < 2; c++) {                                       \
                const int lin = tid + c * 256;                                  \
                const int row = lin >> 3, uu = lin & 7;                         \
                const int su  = (uu ^ (row & 7)) * 8;                           \
                gl_lds16(base + (size_t)((KT) * 64 + row) * 1536 + 512 + su,    \
                         (void*)(&Kb[BB][0][0] + lin * 8));                     \
                gl_lds16(vtb + (size_t)row * Sn + (KT) * 64 + su,               \
                         (void*)(&Vb[BB][0][0] + lin * 8));                     \
            }                                                                   \
        }

    STAGE(0, 0);   // issue tile-0 staging first, Q loads overlap it

    bf16x8 qA0, qA1, qB0, qB1;
    {
        const __bf16* qa = base + (size_t)(qtA * 64 + wave16 + m16) * 1536 + quad * 8;
        qA0 = *(const bf16x8*)qa; qA1 = *(const bf16x8*)(qa + 32);
        const __bf16* qb = base + (size_t)(qtB * 64 + wave16 + m16) * 1536 + quad * 8;
        qB0 = *(const bf16x8*)qb; qB1 = *(const bf16x8*)(qb + 32);
    }

    float mA[4], lA[4], mB[4], lB[4];
    f32x4 accA[4], accB[4];
    #pragma unroll
    for (int r = 0; r < 4; r++) {
        mA[r] = -1e30f; lA[r] = 0.f; mB[r] = -1e30f; lB[r] = 0.f;
        accA[r] = (f32x4){0.f, 0.f, 0.f, 0.f};
        accB[r] = (f32x4){0.f, 0.f, 0.f, 0.f};
    }

    __syncthreads();   // tile 0 staged (barrier drains vmcnt)

    for (int kt = 0; kt <= qtB; kt++) {
        const int buf = kt & 1;
        if (kt < qtB) STAGE(kt + 1, buf ^ 1);   // issue-only; drains at barrier
        const bool actA = (kt <= qtA);

        // ---- S = Q K^T from LDS ----
        f32x4 svA[4], svB[4];
        __builtin_amdgcn_s_setprio(1);
        #pragma unroll
        for (int j = 0; j < 4; j++) {
            const int rk = j * 16 + m16;
            bf16x8 kf0 = *(const bf16x8*)&Kb[buf][rk][sw0];
            bf16x8 kf1 = *(const bf16x8*)&Kb[buf][rk][sw1];
            f32x4 s = (f32x4){0.f, 0.f, 0.f, 0.f};
            s = __builtin_amdgcn_mfma_f32_16x16x32_bf16(qB0, kf0, s, 0, 0, 0);
            s = __builtin_amdgcn_mfma_f32_16x16x32_bf16(qB1, kf1, s, 0, 0, 0);
            svB[j] = s;
            if (actA) {
                f32x4 s2 = (f32x4){0.f, 0.f, 0.f, 0.f};
                s2 = __builtin_amdgcn_mfma_f32_16x16x32_bf16(qA0, kf0, s2, 0, 0, 0);
                s2 = __builtin_amdgcn_mfma_f32_16x16x32_bf16(qA1, kf1, s2, 0, 0, 0);
                svA[j] = s2;
            }
        }
        __builtin_amdgcn_s_setprio(0);

        // ---- V fragments from LDS (issued before softmax; latency hides) ----
        bf16x8 vf[4][2];
        #pragma unroll
        for (int jd = 0; jd < 4; jd++) {
            const int rv = jd * 16 + m16;
            vf[jd][0] = *(const bf16x8*)&Vb[buf][rv][sw0];
            vf[jd][1] = *(const bf16x8*)&Vb[buf][rv][sw1];
        }

        // ---- online softmax (per-wave LDS round-trip, in-order DS) ----
        bf16x8 pB0, pB1, pA0, pA1;
        softmax_update(svB, mB, lB, accB, kt == qtB, wave16, quad, m16, PsB, pB0, pB1);
        if (actA)
            softmax_update(svA, mA, lA, accA, kt == qtA, wave16, quad, m16, PsA, pA0, pA1);

        // ---- O += P V ----
        __builtin_amdgcn_s_setprio(1);
        #pragma unroll
        for (int jd = 0; jd < 4; jd++) {
            accB[jd] = __builtin_amdgcn_mfma_f32_16x16x32_bf16(pB0, vf[jd][0], accB[jd], 0, 0, 0);
            accB[jd] = __builtin_amdgcn_mfma_f32_16x16x32_bf16(pB1, vf[jd][1], accB[jd], 0, 0, 0);
            if (actA) {
                accA[jd] = __builtin_amdgcn_mfma_f32_16x16x32_bf16(pA0, vf[jd][0], accA[jd], 0, 0, 0);
                accA[jd] = __builtin_amdgcn_mfma_f32_16x16x32_bf16(pA1, vf[jd][1], accA[jd], 0, 0, 0);
            }
        }
        __builtin_amdgcn_s_setprio(0);

        __syncthreads();   // all reads of buf done + next-tile staging drained
    }
    #undef STAGE

    // epilogue: O / l for both tiles
    #pragma unroll
    for (int r = 0; r < 4; r++) { lA[r] = 1.0f / lA[r]; lB[r] = 1.0f / lB[r]; }
    #pragma unroll
    for (int jd = 0; jd < 4; jd++)
        #pragma unroll
        for (int r = 0; r < 4; r++) {
            const int rowA = b * Sn + qtA * 64 + wave16 + quad * 4 + r;
            const int rowB = b * Sn + qtB * 64 + wave16 + quad * 4 + r;
            o[(size_t)rowA * Dn + h * DKn + jd * 16 + m16] = (__bf16)(accA[jd][r] * lA[r]);
            o[(size_t)rowB * Dn + h * DKn + jd * 16 + m16] = (__bf16)(accB[jd][r] * lB[r]);
        }
}

// ---------------------------------------------------------------------------
// x = LayerNorm(t + x); writes fp32 x and bf16 copy xb.
// ---------------------------------------------------------------------------
__device__ inline float block_reduce_sum(float v, float* red, int tid) {
    red[tid] = v;
    __syncthreads();
    for (int s = 128; s > 0; s >>= 1) {
        if (tid < s) red[tid] += red[tid + s];
        __syncthreads();
    }
    float r = red[0];
    __syncthreads();
    return r;
}

__global__ __launch_bounds__(256) void k_residual_ln(
    const float* __restrict__ t, float* __restrict__ x, __bf16* __restrict__ xb,
    const float* __restrict__ g, const float* __restrict__ be)
{
    __shared__ float red[256];
    const int row = blockIdx.x, tid = threadIdx.x;
    const size_t base = (size_t)row * Dn;

    float v0 = t[base + tid] + x[base + tid];
    float v1 = t[base + 256 + tid] + x[base + 256 + tid];

    float mean = block_reduce_sum(v0 + v1, red, tid) * (1.0f / Dn);
    float d0 = v0 - mean, d1 = v1 - mean;
    float var = block_reduce_sum(d0 * d0 + d1 * d1, red, tid) * (1.0f / Dn);
    float inv = rsqrtf(var + 1e-5f);

    float o0 = d0 * inv * g[tid]       + be[tid];
    float o1 = d1 * inv * g[256 + tid] + be[256 + tid];
    x[base + tid]        = o0;
    x[base + 256 + tid]  = o1;
    xb[base + tid]       = (__bf16)o0;
    xb[base + 256 + tid] = (__bf16)o1;
}

// ---------------------------------------------------------------------------
// launcher
// ---------------------------------------------------------------------------
extern "C" void kernel_launch(void* const* d_in, const int* in_sizes, int n_in,
                              void* d_out, int out_size, void* d_ws, size_t ws_size,
                              hipStream_t stream)
{
    const float* x_in   = (const float*)d_in[0];
    const float* qkv_w  = (const float*)d_in[1];
    const float* qkv_b  = (const float*)d_in[2];
    const float* out_w  = (const float*)d_in[3];
    const float* out_b  = (const float*)d_in[4];
    const float* ln1_g  = (const float*)d_in[5];
    const float* ln1_b  = (const float*)d_in[6];
    const float* mlp_w1 = (const float*)d_in[7];
    const float* mlp_b1 = (const float*)d_in[8];
    const float* mlp_w2 = (const float*)d_in[9];
    const float* mlp_b2 = (const float*)d_in[10];
    const float* ln2_g  = (const float*)d_in[11];
    const float* ln2_b  = (const float*)d_in[12];

    // workspace layout (~94 MB)
    char* p = (char*)d_ws;
    float*  X    = (float*)p;  p += (size_t)Mn * Dn * 4;        // 16 MB fp32 residual
    __bf16* Xb   = (__bf16*)p; p += (size_t)Mn * Dn * 2;        //  8 MB bf16 x
    __bf16* QKVb = (__bf16*)p; p += (size_t)Mn * 3 * Dn * 2;    // 24 MB
    __bf16* AOb  = (__bf16*)p; p += (size_t)Mn * Dn * 2;        //  8 MB attn out
    __bf16* Hb   = (__bf16*)p; p += (size_t)Mn * DFFn * 2;      // 32 MB mlp hidden
    __bf16* Wq   = (__bf16*)p; p += (size_t)3 * Dn * Dn * 2;    // 1.5 MB  [1536][512]
    __bf16* Wo   = (__bf16*)p; p += (size_t)Dn * Dn * 2;        // 0.5 MB  [512][512]
    __bf16* W1   = (__bf16*)p; p += (size_t)DFFn * Dn * 2;      // 2 MB    [2048][512]
    __bf16* W2   = (__bf16*)p; p += (size_t)Dn * DFFn * 2;      // 2 MB    [512][2048]
    __bf16* Vt   = Hb;             // 8 MB, aliased: Hb dead during attention
    float* BUF3 = (float*)d_out;   // pre-LN temp lives in d_out

    const size_t xBytes = (size_t)Mn * Dn * sizeof(float);
    hipMemcpyAsync(X, x_in, xBytes, hipMemcpyDeviceToDevice, stream);
    k_cast_bf16<<<(Mn * Dn) / 256, 256, 0, stream>>>(x_in, Xb, Mn * Dn);

    for (int l = 0; l < Ln; l++) {
        // all 4 weight transposes in one launch
        k_trans_all<<<3072, dim3(32, 8), 0, stream>>>(
            qkv_w + (size_t)l * Dn * 3 * Dn, out_w + (size_t)l * Dn * Dn,
            mlp_w1 + (size_t)l * Dn * DFFn, mlp_w2 + (size_t)l * DFFn * Dn,
            Wq, Wo, W1, W2);

        // QKV projection -> bf16 [M,1536] + fused Vt scatter
        k_gemm_mfma<0, 1, 4, 1><<<dim3(12, 64), 256, 0, stream>>>(
            Xb, Wq, qkv_b + (size_t)l * 3 * Dn, QKVb, Vt, Mn, 3 * Dn, Dn);
        // LDS-staged MFMA flash attention -> bf16 [M,512]
        k_attn_mfma<<<512, 256, 0, stream>>>(QKVb, Vt, AOb);
        // output projection -> fp32 BUF3
        k_gemm_mfma<0, 0, 2, 0><<<dim3(8, 64), 256, 0, stream>>>(
            AOb, Wo, out_b + (size_t)l * Dn, BUF3, nullptr, Mn, Dn, Dn);
        // x = LN(proj + x)
        k_residual_ln<<<Mn, 256, 0, stream>>>(BUF3, X, Xb,
            ln1_g + (size_t)l * Dn, ln1_b + (size_t)l * Dn);
        // MLP up + ReLU -> bf16 [M,2048]  (overwrites Vt alias; attn done)
        k_gemm_mfma<1, 1, 4, 0><<<dim3(16, 64), 256, 0, stream>>>(
            Xb, W1, mlp_b1 + (size_t)l * DFFn, Hb, nullptr, Mn, DFFn, Dn);
        // MLP down -> fp32 BUF3
        k_gemm_mfma<0, 0, 2, 0><<<dim3(8, 64), 256, 0, stream>>>(
            Hb, W2, mlp_b2 + (size_t)l * Dn, BUF3, nullptr, Mn, Dn, DFFn);
        // x = LN(x + mlp)
        k_residual_ln<<<Mn, 256, 0, stream>>>(BUF3, X, Xb,
            ln2_g + (size_t)l * Dn, ln2_b + (size_t)l * Dn);
    }

    hipMemcpyAsync(d_out, X, xBytes, hipMemcpyDeviceToDevice, stream);
}

// Round 3
// 1101.734 us; speedup vs baseline: 1.3431x; 1.1629x over previous
//
#include <hip/hip_runtime.h>
#include <math.h>

// Problem constants
#define Bn   8
#define Sn   1024
#define Dn   512
#define Hn   8
#define DKn  64
#define Ln   6
#define DFFn 2048
#define Mn   (Bn * Sn)   // 8192 rows

typedef __bf16 bf16x8 __attribute__((ext_vector_type(8)));
typedef __bf16 bf16x4 __attribute__((ext_vector_type(4)));
typedef float  f32x4  __attribute__((ext_vector_type(4)));

// async global->LDS, 16B per lane. LDS dest must be wave-uniform base + lane*16.
__device__ __forceinline__ void gl_lds16(const void* g, void* l) {
    __builtin_amdgcn_global_load_lds(
        (const __attribute__((address_space(1))) void*)g,
        (__attribute__((address_space(3))) void*)l, 16, 0, 0);
}

// ---------------------------------------------------------------------------
// fp32 -> bf16 cast
// ---------------------------------------------------------------------------
__global__ __launch_bounds__(256) void k_cast_bf16(const float* __restrict__ in,
                                                   __bf16* __restrict__ out, int n) {
    int i = blockIdx.x * 256 + threadIdx.x;
    if (i < n) out[i] = (__bf16)in[i];
}

// ---------------------------------------------------------------------------
// All 4 weight matrices of one layer: W[K][N] fp32 -> Wt[N][K] bf16.
// 32x32 tiles, 32x8 threads. Tile ranges: Wq 768 | Wo 256 | W1 1024 | W2 1024.
// ---------------------------------------------------------------------------
__global__ __launch_bounds__(256) void k_trans_all(
    const float* __restrict__ qkv_w, const float* __restrict__ out_w,
    const float* __restrict__ w1, const float* __restrict__ w2,
    __bf16* __restrict__ Wq, __bf16* __restrict__ Wo,
    __bf16* __restrict__ W1o, __bf16* __restrict__ W2o)
{
    const int t = blockIdx.x;
    const float* src; __bf16* dst; int K, N, n0, k0;
    if (t < 768)       { src = qkv_w; dst = Wq;  K = 512;  N = 1536; int u = t;        n0 = (u % 48) * 32; k0 = (u / 48) * 32; }
    else if (t < 1024) { src = out_w; dst = Wo;  K = 512;  N = 512;  int u = t - 768;  n0 = (u % 16) * 32; k0 = (u / 16) * 32; }
    else if (t < 2048) { src = w1;    dst = W1o; K = 512;  N = 2048; int u = t - 1024; n0 = (u % 64) * 32; k0 = (u / 64) * 32; }
    else               { src = w2;    dst = W2o; K = 2048; N = 512;  int u = t - 2048; n0 = (u % 16) * 32; k0 = (u / 16) * 32; }

    __shared__ float tt[32][33];
    const int tx = threadIdx.x, ty = threadIdx.y;
    #pragma unroll
    for (int r = 0; r < 4; r++)
        tt[ty + 8 * r][tx] = src[(size_t)(k0 + ty + 8 * r) * N + n0 + tx];
    __syncthreads();
    #pragma unroll
    for (int r = 0; r < 4; r++)
        dst[(size_t)(n0 + ty + 8 * r) * K + k0 + tx] = (__bf16)tt[tx][ty + 8 * r];
}

// ---------------------------------------------------------------------------
// MFMA GEMM: C[M,N] = act(A[M,K]bf16 @ Bt[N,K]bf16^T + bias[N]fp32)
// Block: 256 thr = 4 waves (2x2). Tile: 128 x (JT*32). BK=64.
// v4: (a) 1D grid + bijective chunked XCD swizzle: work-id
//     id=(bid%8)*(nwg/8)+bid/8, row-major decompose -> the NBX col-blocks of
//     one A row-panel are consecutive ids -> co-resident on ONE XCD's L2 ->
//     each A panel crosses HBM once (chunk size multiple of NBX for all
//     launches, so panels never straddle chunks).
//     (b) XOR LDS swizzle both-sides (rule #21): gl_lds16 dest linear,
//     global SOURCE unit pre-swizzled u^=(row&7), ds_read applies same XOR.
//     Kills the 16-way bank conflict of 128B-stride fragment reads.
// A/B fragment: elem[j] = X[lane&15][ (lane>>4)*8 + j ]  (m97-verified)
// C/D: col = lane&15, row = (lane>>4)*4 + reg            (m89/m91-verified)
// VW=1 (QKV only): cols >=1024 are V -> also scatter into Vt[b*8+h][d][s].
// ---------------------------------------------------------------------------
template <int RELU, int OUTBF, int JT, int VW>
__global__ __launch_bounds__(256) void k_gemm_mfma(
    const __bf16* __restrict__ A, const __bf16* __restrict__ Bt,
    const float* __restrict__ bias, void* __restrict__ Cout,
    __bf16* __restrict__ Vt, int M, int N, int K, int NBX)
{
    constexpr int BN = JT * 32;   // 128 or 64
    __shared__ __bf16 As[128][64];
    __shared__ __bf16 Bs[BN][64];
    const int tid  = threadIdx.x;
    const int lane = tid & 63;
    const int wave = tid >> 6;
    const int wy   = wave >> 1, wx = wave & 1;
    const int m16  = lane & 15, quad = lane >> 4;

    // chunked XCD swizzle (all launches have gridDim.x % 8 == 0)
    const int cpx = gridDim.x >> 3;
    const int id  = (blockIdx.x & 7) * cpx + (blockIdx.x >> 3);
    const int bm  = (id / NBX) * 128;
    const int bn  = (id % NBX) * BN;

    f32x4 acc[4][JT];
    #pragma unroll
    for (int i = 0; i < 4; i++)
        #pragma unroll
        for (int j = 0; j < JT; j++)
            acc[i][j] = (f32x4){0.f, 0.f, 0.f, 0.f};

    const __bf16* Ap = A  + (size_t)bm * K;
    const __bf16* Bp = Bt + (size_t)bn * K;

    // swizzled 16B-unit byte offsets for fragment reads (involution of stage)
    const int sw0 = ((quad    ) ^ (m16 & 7)) * 8;
    const int sw1 = ((quad + 4) ^ (m16 & 7)) * 8;

    for (int k0 = 0; k0 < K; k0 += 64) {
        __syncthreads();
        #pragma unroll
        for (int c = 0; c < 4; c++) {           // A: 128x64 bf16 = 1024 x 16B
            int lin = tid + c * 256;
            int row = lin >> 3, uu = lin & 7;
            int su  = (uu ^ (row & 7)) << 3;
            gl_lds16(Ap + (size_t)row * K + k0 + su, (void*)(&As[0][0] + lin * 8));
        }
        #pragma unroll
        for (int c = 0; c < JT; c++) {          // B: BNx64 bf16
            int lin = tid + c * 256;
            int row = lin >> 3, uu = lin & 7;
            int su  = (uu ^ (row & 7)) << 3;
            gl_lds16(Bp + (size_t)row * K + k0 + su, (void*)(&Bs[0][0] + lin * 8));
        }
        __syncthreads();

        bf16x8 af[4][2], bfr[JT][2];
        #pragma unroll
        for (int i = 0; i < 4; i++) {
            af[i][0] = *(const bf16x8*)&As[wy * 64 + i * 16 + m16][sw0];
            af[i][1] = *(const bf16x8*)&As[wy * 64 + i * 16 + m16][sw1];
        }
        #pragma unroll
        for (int j = 0; j < JT; j++) {
            bfr[j][0] = *(const bf16x8*)&Bs[wx * JT * 16 + j * 16 + m16][sw0];
            bfr[j][1] = *(const bf16x8*)&Bs[wx * JT * 16 + j * 16 + m16][sw1];
        }
        #pragma unroll
        for (int hc = 0; hc < 2; hc++)
            #pragma unroll
            for (int i = 0; i < 4; i++)
                #pragma unroll
                for (int j = 0; j < JT; j++)
                    acc[i][j] = __builtin_amdgcn_mfma_f32_16x16x32_bf16(
                        af[i][hc], bfr[j][hc], acc[i][j], 0, 0, 0);
    }

    float*  Cf = (float*)Cout;
    __bf16* Cb = (__bf16*)Cout;
    #pragma unroll
    for (int i = 0; i < 4; i++) {
        const int row0 = bm + wy * 64 + i * 16 + quad * 4;
        #pragma unroll
        for (int j = 0; j < JT; j++) {
            const int col = bn + wx * JT * 16 + j * 16 + m16;
            const float bv = bias[col];
            float vv[4];
            #pragma unroll
            for (int r = 0; r < 4; r++) {
                float v = acc[i][j][r] + bv;
                if (RELU) v = fmaxf(v, 0.f);
                vv[r] = v;
                if (OUTBF) Cb[(size_t)(row0 + r) * N + col] = (__bf16)v;
                else       Cf[(size_t)(row0 + r) * N + col] = v;
            }
            if (VW && col >= 1024) {            // V slice -> Vt[b*8+h][d][s]
                const int cc = col - 1024;
                const int bb = row0 >> 10, ss = row0 & 1023;
                bf16x4 pv;
                #pragma unroll
                for (int r = 0; r < 4; r++) pv[r] = (__bf16)vv[r];
                *(bf16x4*)&Vt[((size_t)(bb * Hn + (cc >> 6)) * DKn + (cc & 63)) * Sn + ss] = pv;
            }
        }
    }
}

// ---------------------------------------------------------------------------
// MFMA flash attention (causal), LDS-staged K/V.
// qkv: [M][1536] bf16; Vt: [b*8+h][64][1024] bf16.
// Block = (pair pr, h, b): q-tiles qtA=pr, qtB=15-pr (uniform 17 MFMA-tiles).
// 4 waves; wave w owns q-rows w*16..+15 of each tile.
// K/V tiles staged ONCE per block into LDS via global_load_lds, double-
// buffered, one __syncthreads per k-step. XOR swizzle u^=(row&7) both sides.
// Grid linearized so id%8==h: all pr/b blocks of one h share an XCD L2.
// ---------------------------------------------------------------------------
__device__ __forceinline__ void softmax_update(
    f32x4 sv[4], float m[4], float l[4], f32x4 acc[4],
    bool diag, int wave16, int quad, int m16,
    __bf16 (*Pw)[72], bf16x8& pf0, bf16x8& pf1)
{
    #pragma unroll
    for (int j = 0; j < 4; j++)
        #pragma unroll
        for (int r = 0; r < 4; r++) {
            float v = sv[j][r] * 0.125f;    // 1/sqrt(64)
            if (diag && (j * 16 + m16) > (wave16 + quad * 4 + r)) v = -1e30f;
            sv[j][r] = v;
        }

    float pm[4];
    #pragma unroll
    for (int r = 0; r < 4; r++)
        pm[r] = fmaxf(fmaxf(sv[0][r], sv[1][r]), fmaxf(sv[2][r], sv[3][r]));
    #pragma unroll
    for (int off = 1; off < 16; off <<= 1)
        #pragma unroll
        for (int r = 0; r < 4; r++)
            pm[r] = fmaxf(pm[r], __shfl_xor(pm[r], off, 16));

    float al[4];
    #pragma unroll
    for (int r = 0; r < 4; r++) {
        float mn = fmaxf(m[r], pm[r]);
        al[r] = __expf(m[r] - mn);
        m[r] = mn;
    }

    float rs[4] = {0.f, 0.f, 0.f, 0.f};
    #pragma unroll
    for (int j = 0; j < 4; j++)
        #pragma unroll
        for (int r = 0; r < 4; r++) {
            float p = __expf(sv[j][r] - m[r]);
            rs[r] += p;
            Pw[quad * 4 + r][j * 16 + m16] = (__bf16)p;
        }
    #pragma unroll
    for (int off = 1; off < 16; off <<= 1)
        #pragma unroll
        for (int r = 0; r < 4; r++)
            rs[r] += __shfl_xor(rs[r], off, 16);
    #pragma unroll
    for (int r = 0; r < 4; r++) l[r] = l[r] * al[r] + rs[r];

    #pragma unroll
    for (int j = 0; j < 4; j++)
        #pragma unroll
        for (int r = 0; r < 4; r++) acc[j][r] *= al[r];

    pf0 = *(const bf16x8*)&Pw[m16][quad * 8];
    pf1 = *(const bf16x8*)&Pw[m16][32 + quad * 8];
}

__global__ __launch_bounds__(256) void k_attn_mfma(
    const __bf16* __restrict__ qkv, const __bf16* __restrict__ Vt,
    __bf16* __restrict__ o)
{
    const int id = blockIdx.x;
    const int pr = id >> 6;            // 0..7
    const int b  = (id >> 3) & 7;
    const int h  = id & 7;             // id%8 = h -> pr/b blocks of one h share an XCD
    const int tid  = threadIdx.x;
    const int lane = tid & 63, wave = tid >> 6;
    const int m16  = lane & 15, quad = lane >> 4;
    const int qtA  = pr, qtB = 15 - pr;
    const int wave16 = wave * 16;

    __shared__ __bf16 Kb[2][64][64];     // double-buffered K tile (swizzled)
    __shared__ __bf16 Vb[2][64][64];     // double-buffered V tile (swizzled)
    __shared__ __bf16 Ps[4][2][16][72];  // per-wave, per-tile P scratch

    const __bf16* base = qkv + (size_t)b * Sn * 1536 + h * DKn;   // Q +0, K +512
    const __bf16* vtb  = Vt + (size_t)(b * Hn + h) * DKn * Sn;

    __bf16 (*PsA)[72] = Ps[wave][0];
    __bf16 (*PsB)[72] = Ps[wave][1];

    // swizzled 16B-unit offsets for fragment reads (involution of stage swizzle)
    const int sw0 = ((quad    ) ^ (m16 & 7)) * 8;
    const int sw1 = ((quad + 4) ^ (m16 & 7)) * 8;

    // stage K and V tile KT into LDS buffer BB. Linear LDS dest (gl_lds16
    // requirement), global source pre-swizzled: unit u' = u ^ (row&7).
    #define STAGE(KT, BB)                                                       \
        {                                                                       \
            _Pragma("unroll")                                                   \
            for (int c = 0; c < 2; c++) {                                       \
                const int lin = tid + c * 256;                                  \
                const int row = lin >> 3, uu = lin & 7;                         \
                const int su  = (uu ^ (row & 7)) * 8;                           \
                gl_lds16(base + (size_t)((KT) * 64 + row) * 1536 + 512 + su,    \
                         (void*)(&Kb[BB][0][0] + lin * 8));                     \
                gl_lds16(vtb + (size_t)row * Sn + (KT) * 64 + su,               \
                         (void*)(&Vb[BB][0][0] + lin * 8));                     \
            }                                                                   \
        }

    STAGE(0, 0);   // issue tile-0 staging first, Q loads overlap it

    bf16x8 qA0, qA1, qB0, qB1;
    {
        const __bf16* qa = base + (size_t)(qtA * 64 + wave16 + m16) * 1536 + quad * 8;
        qA0 = *(const bf16x8*)qa; qA1 = *(const bf16x8*)(qa + 32);
        const __bf16* qb = base + (size_t)(qtB * 64 + wave16 + m16) * 1536 + quad * 8;
        qB0 = *(const bf16x8*)qb; qB1 = *(const bf16x8*)(qb + 32);
    }

    float mA[4], lA[4], mB[4], lB[4];
    f32x4 accA[4], accB[4];
    #pragma unroll
    for (int r = 0; r < 4; r++) {
        mA[r] = -1e30f; lA[r] = 0.f; mB[r] = -1e30f; lB[r] = 0.f;
        accA[r] = (f32x4){0.f, 0.f, 0.f, 0.f};
        accB[r] = (f32x4){0.f, 0.f, 0.f, 0.f};
    }

    __syncthreads();   // tile 0 staged (barrier drains vmcnt)

    for (int kt = 0; kt <= qtB; kt++) {
        const int buf = kt & 1;
        if (kt < qtB) STAGE(kt + 1, buf ^ 1);   // issue-only; drains at barrier
        const bool actA = (kt <= qtA);

        // ---- S = Q K^T from LDS ----
        f32x4 svA[4], svB[4];
        __builtin_amdgcn_s_setprio(1);
        #pragma unroll
        for (int j = 0; j < 4; j++) {
            const int rk = j * 16 + m16;
            bf16x8 kf0 = *(const bf16x8*)&Kb[buf][rk][sw0];
            bf16x8 kf1 = *(const bf16x8*)&Kb[buf][rk][sw1];
            f32x4 s = (f32x4){0.f, 0.f, 0.f, 0.f};
            s = __builtin_amdgcn_mfma_f32_16x16x32_bf16(qB0, kf0, s, 0, 0, 0);
            s = __builtin_amdgcn_mfma_f32_16x16x32_bf16(qB1, kf1, s, 0, 0, 0);
            svB[j] = s;
            if (actA) {
                f32x4 s2 = (f32x4){0.f, 0.f, 0.f, 0.f};
                s2 = __builtin_amdgcn_mfma_f32_16x16x32_bf16(qA0, kf0, s2, 0, 0, 0);
                s2 = __builtin_amdgcn_mfma_f32_16x16x32_bf16(qA1, kf1, s2, 0, 0, 0);
                svA[j] = s2;
            }
        }
        __builtin_amdgcn_s_setprio(0);

        // ---- V fragments from LDS (issued before softmax; latency hides) ----
        bf16x8 vf[4][2];
        #pragma unroll
        for (int jd = 0; jd < 4; jd++) {
            const int rv = jd * 16 + m16;
            vf[jd][0] = *(const bf16x8*)&Vb[buf][rv][sw0];
            vf[jd][1] = *(const bf16x8*)&Vb[buf][rv][sw1];
        }

        // ---- online softmax (per-wave LDS round-trip, in-order DS) ----
        bf16x8 pB0, pB1, pA0, pA1;
        softmax_update(svB, mB, lB, accB, kt == qtB, wave16, quad, m16, PsB, pB0, pB1);
        if (actA)
            softmax_update(svA, mA, lA, accA, kt == qtA, wave16, quad, m16, PsA, pA0, pA1);

        // ---- O += P V ----
        __builtin_amdgcn_s_setprio(1);
        #pragma unroll
        for (int jd = 0; jd < 4; jd++) {
            accB[jd] = __builtin_amdgcn_mfma_f32_16x16x32_bf16(pB0, vf[jd][0], accB[jd], 0, 0, 0);
            accB[jd] = __builtin_amdgcn_mfma_f32_16x16x32_bf16(pB1, vf[jd][1], accB[jd], 0, 0, 0);
            if (actA) {
                accA[jd] = __builtin_amdgcn_mfma_f32_16x16x32_bf16(pA0, vf[jd][0], accA[jd], 0, 0, 0);
                accA[jd] = __builtin_amdgcn_mfma_f32_16x16x32_bf16(pA1, vf[jd][1], accA[jd], 0, 0, 0);
            }
        }
        __builtin_amdgcn_s_setprio(0);

        __syncthreads();   // all reads of buf done + next-tile staging drained
    }
    #undef STAGE

    // epilogue: O / l for both tiles
    #pragma unroll
    for (int r = 0; r < 4; r++) { lA[r] = 1.0f / lA[r]; lB[r] = 1.0f / lB[r]; }
    #pragma unroll
    for (int jd = 0; jd < 4; jd++)
        #pragma unroll
        for (int r = 0; r < 4; r++) {
            const int rowA = b * Sn + qtA * 64 + wave16 + quad * 4 + r;
            const int rowB = b * Sn + qtB * 64 + wave16 + quad * 4 + r;
            o[(size_t)rowA * Dn + h * DKn + jd * 16 + m16] = (__bf16)(accA[jd][r] * lA[r]);
            o[(size_t)rowB * Dn + h * DKn + jd * 16 + m16] = (__bf16)(accB[jd][r] * lB[r]);
        }
}

// ---------------------------------------------------------------------------
// x = LayerNorm(t + x); writes fp32 x and bf16 copy xb.
// ---------------------------------------------------------------------------
__device__ inline float block_reduce_sum(float v, float* red, int tid) {
    red[tid] = v;
    __syncthreads();
    for (int s = 128; s > 0; s >>= 1) {
        if (tid < s) red[tid] += red[tid + s];
        __syncthreads();
    }
    float r = red[0];
    __syncthreads();
    return r;
}

__global__ __launch_bounds__(256) void k_residual_ln(
    const float* __restrict__ t, float* __restrict__ x, __bf16* __restrict__ xb,
    const float* __restrict__ g, const float* __restrict__ be)
{
    __shared__ float red[256];
    const int row = blockIdx.x, tid = threadIdx.x;
    const size_t base = (size_t)row * Dn;

    float v0 = t[base + tid] + x[base + tid];
    float v1 = t[base + 256 + tid] + x[base + 256 + tid];

    float mean = block_reduce_sum(v0 + v1, red, tid) * (1.0f / Dn);
    float d0 = v0 - mean, d1 = v1 - mean;
    float var = block_reduce_sum(d0 * d0 + d1 * d1, red, tid) * (1.0f / Dn);
    float inv = rsqrtf(var + 1e-5f);

    float o0 = d0 * inv * g[tid]       + be[tid];
    float o1 = d1 * inv * g[256 + tid] + be[256 + tid];
    x[base + tid]        = o0;
    x[base + 256 + tid]  = o1;
    xb[base + tid]       = (__bf16)o0;
    xb[base + 256 + tid] = (__bf16)o1;
}

// ---------------------------------------------------------------------------
// launcher
// ---------------------------------------------------------------------------
extern "C" void kernel_launch(void* const* d_in, const int* in_sizes, int n_in,
                              void* d_out, int out_size, void* d_ws, size_t ws_size,
                              hipStream_t stream)
{
    const float* x_in   = (const float*)d_in[0];
    const float* qkv_w  = (const float*)d_in[1];
    const float* qkv_b  = (const float*)d_in[2];
    const float* out_w  = (const float*)d_in[3];
    const float* out_b  = (const float*)d_in[4];
    const float* ln1_g  = (const float*)d_in[5];
    const float* ln1_b  = (const float*)d_in[6];
    const float* mlp_w1 = (const float*)d_in[7];
    const float* mlp_b1 = (const float*)d_in[8];
    const float* mlp_w2 = (const float*)d_in[9];
    const float* mlp_b2 = (const float*)d_in[10];
    const float* ln2_g  = (const float*)d_in[11];
    const float* ln2_b  = (const float*)d_in[12];

    // workspace layout (~94 MB)
    char* p = (char*)d_ws;
    float*  X    = (float*)p;  p += (size_t)Mn * Dn * 4;        // 16 MB fp32 residual
    __bf16* Xb   = (__bf16*)p; p += (size_t)Mn * Dn * 2;        //  8 MB bf16 x
    __bf16* QKVb = (__bf16*)p; p += (size_t)Mn * 3 * Dn * 2;    // 24 MB
    __bf16* AOb  = (__bf16*)p; p += (size_t)Mn * Dn * 2;        //  8 MB attn out
    __bf16* Hb   = (__bf16*)p; p += (size_t)Mn * DFFn * 2;      // 32 MB mlp hidden
    __bf16* Wq   = (__bf16*)p; p += (size_t)3 * Dn * Dn * 2;    // 1.5 MB  [1536][512]
    __bf16* Wo   = (__bf16*)p; p += (size_t)Dn * Dn * 2;        // 0.5 MB  [512][512]
    __bf16* W1   = (__bf16*)p; p += (size_t)DFFn * Dn * 2;      // 2 MB    [2048][512]
    __bf16* W2   = (__bf16*)p; p += (size_t)Dn * DFFn * 2;      // 2 MB    [512][2048]
    __bf16* Vt   = Hb;             // 8 MB, aliased: Hb dead during attention
    float* BUF3 = (float*)d_out;   // pre-LN temp lives in d_out

    const size_t xBytes = (size_t)Mn * Dn * sizeof(float);
    hipMemcpyAsync(X, x_in, xBytes, hipMemcpyDeviceToDevice, stream);
    k_cast_bf16<<<(Mn * Dn) / 256, 256, 0, stream>>>(x_in, Xb, Mn * Dn);

    for (int l = 0; l < Ln; l++) {
        // all 4 weight transposes in one launch
        k_trans_all<<<3072, dim3(32, 8), 0, stream>>>(
            qkv_w + (size_t)l * Dn * 3 * Dn, out_w + (size_t)l * Dn * Dn,
            mlp_w1 + (size_t)l * Dn * DFFn, mlp_w2 + (size_t)l * DFFn * Dn,
            Wq, Wo, W1, W2);

        // QKV projection -> bf16 [M,1536] + fused Vt scatter
        k_gemm_mfma<0, 1, 4, 1><<<768, 256, 0, stream>>>(
            Xb, Wq, qkv_b + (size_t)l * 3 * Dn, QKVb, Vt, Mn, 3 * Dn, Dn, 12);
        // LDS-staged MFMA flash attention -> bf16 [M,512]
        k_attn_mfma<<<512, 256, 0, stream>>>(QKVb, Vt, AOb);
        // output projection -> fp32 BUF3
        k_gemm_mfma<0, 0, 2, 0><<<512, 256, 0, stream>>>(
            AOb, Wo, out_b + (size_t)l * Dn, BUF3, nullptr, Mn, Dn, Dn, 8);
        // x = LN(proj + x)
        k_residual_ln<<<Mn, 256, 0, stream>>>(BUF3, X, Xb,
            ln1_g + (size_t)l * Dn, ln1_b + (size_t)l * Dn);
        // MLP up + ReLU -> bf16 [M,2048]  (overwrites Vt alias; attn done)
        k_gemm_mfma<1, 1, 4, 0><<<1024, 256, 0, stream>>>(
            Xb, W1, mlp_b1 + (size_t)l * DFFn, Hb, nullptr, Mn, DFFn, Dn, 16);
        // MLP down -> fp32 BUF3
        k_gemm_mfma<0, 0, 2, 0><<<512, 256, 0, stream>>>(
            Hb, W2, mlp_b2 + (size_t)l * Dn, BUF3, nullptr, Mn, Dn, DFFn, 8);
        // x = LN(x + mlp)
        k_residual_ln<<<Mn, 256, 0, stream>>>(BUF3, X, Xb,
            ln2_g + (size_t)l * Dn, ln2_b + (size_t)l * Dn);
    }

    hipMemcpyAsync(d_out, X, xBytes, hipMemcpyDeviceToDevice, stream);
}

// Round 4
// 1064.491 us; speedup vs baseline: 1.3901x; 1.0350x over previous
//
#include <hip/hip_runtime.h>
#include <math.h>

// Problem constants
#define Bn   8
#define Sn   1024
#define Dn   512
#define Hn   8
#define DKn  64
#define Ln   6
#define DFFn 2048
#define Mn   (Bn * Sn)   // 8192 rows

typedef __bf16 bf16x8 __attribute__((ext_vector_type(8)));
typedef __bf16 bf16x4 __attribute__((ext_vector_type(4)));
typedef float  f32x4  __attribute__((ext_vector_type(4)));

// async global->LDS, 16B per lane. LDS dest must be wave-uniform base + lane*16.
__device__ __forceinline__ void gl_lds16(const void* g, void* l) {
    __builtin_amdgcn_global_load_lds(
        (const __attribute__((address_space(1))) void*)g,
        (__attribute__((address_space(3))) void*)l, 16, 0, 0);
}

// ---------------------------------------------------------------------------
// fp32 -> bf16 cast
// ---------------------------------------------------------------------------
__global__ __launch_bounds__(256) void k_cast_bf16(const float* __restrict__ in,
                                                   __bf16* __restrict__ out, int n) {
    int i = blockIdx.x * 256 + threadIdx.x;
    if (i < n) out[i] = (__bf16)in[i];
}

// ---------------------------------------------------------------------------
// All 4 weight matrices of one layer: W[K][N] fp32 -> Wt[N][K] bf16.
// 32x32 tiles, 32x8 threads. Tile ranges: Wq 768 | Wo 256 | W1 1024 | W2 1024.
// ---------------------------------------------------------------------------
__global__ __launch_bounds__(256) void k_trans_all(
    const float* __restrict__ qkv_w, const float* __restrict__ out_w,
    const float* __restrict__ w1, const float* __restrict__ w2,
    __bf16* __restrict__ Wq, __bf16* __restrict__ Wo,
    __bf16* __restrict__ W1o, __bf16* __restrict__ W2o)
{
    const int t = blockIdx.x;
    const float* src; __bf16* dst; int K, N, n0, k0;
    if (t < 768)       { src = qkv_w; dst = Wq;  K = 512;  N = 1536; int u = t;        n0 = (u % 48) * 32; k0 = (u / 48) * 32; }
    else if (t < 1024) { src = out_w; dst = Wo;  K = 512;  N = 512;  int u = t - 768;  n0 = (u % 16) * 32; k0 = (u / 16) * 32; }
    else if (t < 2048) { src = w1;    dst = W1o; K = 512;  N = 2048; int u = t - 1024; n0 = (u % 64) * 32; k0 = (u / 64) * 32; }
    else               { src = w2;    dst = W2o; K = 2048; N = 512;  int u = t - 2048; n0 = (u % 16) * 32; k0 = (u / 16) * 32; }

    __shared__ float tt[32][33];
    const int tx = threadIdx.x, ty = threadIdx.y;
    #pragma unroll
    for (int r = 0; r < 4; r++)
        tt[ty + 8 * r][tx] = src[(size_t)(k0 + ty + 8 * r) * N + n0 + tx];
    __syncthreads();
    #pragma unroll
    for (int r = 0; r < 4; r++)
        dst[(size_t)(n0 + ty + 8 * r) * K + k0 + tx] = (__bf16)tt[tx][ty + 8 * r];
}

// ---------------------------------------------------------------------------
// MFMA GEMM: C[M,N] = act(A[M,K]bf16 @ Bt[N,K]bf16^T + bias[N]fp32)
// Block: 256 thr = 4 waves (2x2). Tile: 128 x (JT*32). BK=64.
// (a) 1D grid + bijective chunked XCD swizzle: work-id
//     id=(bid%8)*(nwg/8)+bid/8, row-major decompose -> the NBX col-blocks of
//     one A row-panel are consecutive ids -> co-resident on ONE XCD's L2.
// (b) XOR LDS swizzle both-sides (rule #21): gl_lds16 dest linear,
//     global SOURCE unit pre-swizzled u^=(row&7), ds_read applies same XOR.
// A/B fragment: elem[j] = X[lane&15][ (lane>>4)*8 + j ]  (m97-verified)
// C/D: col = lane&15, row = (lane>>4)*4 + reg            (m89/m91-verified)
// VW=1 (QKV only): cols >=1024 are V -> also scatter into Vt[b*8+h][d][s].
// ---------------------------------------------------------------------------
template <int RELU, int OUTBF, int JT, int VW>
__global__ __launch_bounds__(256) void k_gemm_mfma(
    const __bf16* __restrict__ A, const __bf16* __restrict__ Bt,
    const float* __restrict__ bias, void* __restrict__ Cout,
    __bf16* __restrict__ Vt, int M, int N, int K, int NBX)
{
    constexpr int BN = JT * 32;   // 128 or 64
    __shared__ __bf16 As[128][64];
    __shared__ __bf16 Bs[BN][64];
    const int tid  = threadIdx.x;
    const int lane = tid & 63;
    const int wave = tid >> 6;
    const int wy   = wave >> 1, wx = wave & 1;
    const int m16  = lane & 15, quad = lane >> 4;

    // chunked XCD swizzle (all launches have gridDim.x % 8 == 0)
    const int cpx = gridDim.x >> 3;
    const int id  = (blockIdx.x & 7) * cpx + (blockIdx.x >> 3);
    const int bm  = (id / NBX) * 128;
    const int bn  = (id % NBX) * BN;

    f32x4 acc[4][JT];
    #pragma unroll
    for (int i = 0; i < 4; i++)
        #pragma unroll
        for (int j = 0; j < JT; j++)
            acc[i][j] = (f32x4){0.f, 0.f, 0.f, 0.f};

    const __bf16* Ap = A  + (size_t)bm * K;
    const __bf16* Bp = Bt + (size_t)bn * K;

    // swizzled 16B-unit byte offsets for fragment reads (involution of stage)
    const int sw0 = ((quad    ) ^ (m16 & 7)) * 8;
    const int sw1 = ((quad + 4) ^ (m16 & 7)) * 8;

    for (int k0 = 0; k0 < K; k0 += 64) {
        __syncthreads();
        #pragma unroll
        for (int c = 0; c < 4; c++) {           // A: 128x64 bf16 = 1024 x 16B
            int lin = tid + c * 256;
            int row = lin >> 3, uu = lin & 7;
            int su  = (uu ^ (row & 7)) << 3;
            gl_lds16(Ap + (size_t)row * K + k0 + su, (void*)(&As[0][0] + lin * 8));
        }
        #pragma unroll
        for (int c = 0; c < JT; c++) {          // B: BNx64 bf16
            int lin = tid + c * 256;
            int row = lin >> 3, uu = lin & 7;
            int su  = (uu ^ (row & 7)) << 3;
            gl_lds16(Bp + (size_t)row * K + k0 + su, (void*)(&Bs[0][0] + lin * 8));
        }
        __syncthreads();

        bf16x8 af[4][2], bfr[JT][2];
        #pragma unroll
        for (int i = 0; i < 4; i++) {
            af[i][0] = *(const bf16x8*)&As[wy * 64 + i * 16 + m16][sw0];
            af[i][1] = *(const bf16x8*)&As[wy * 64 + i * 16 + m16][sw1];
        }
        #pragma unroll
        for (int j = 0; j < JT; j++) {
            bfr[j][0] = *(const bf16x8*)&Bs[wx * JT * 16 + j * 16 + m16][sw0];
            bfr[j][1] = *(const bf16x8*)&Bs[wx * JT * 16 + j * 16 + m16][sw1];
        }
        #pragma unroll
        for (int hc = 0; hc < 2; hc++)
            #pragma unroll
            for (int i = 0; i < 4; i++)
                #pragma unroll
                for (int j = 0; j < JT; j++)
                    acc[i][j] = __builtin_amdgcn_mfma_f32_16x16x32_bf16(
                        af[i][hc], bfr[j][hc], acc[i][j], 0, 0, 0);
    }

    float*  Cf = (float*)Cout;
    __bf16* Cb = (__bf16*)Cout;
    #pragma unroll
    for (int i = 0; i < 4; i++) {
        const int row0 = bm + wy * 64 + i * 16 + quad * 4;
        #pragma unroll
        for (int j = 0; j < JT; j++) {
            const int col = bn + wx * JT * 16 + j * 16 + m16;
            const float bv = bias[col];
            float vv[4];
            #pragma unroll
            for (int r = 0; r < 4; r++) {
                float v = acc[i][j][r] + bv;
                if (RELU) v = fmaxf(v, 0.f);
                vv[r] = v;
                if (OUTBF) Cb[(size_t)(row0 + r) * N + col] = (__bf16)v;
                else       Cf[(size_t)(row0 + r) * N + col] = v;
            }
            if (VW && col >= 1024) {            // V slice -> Vt[b*8+h][d][s]
                const int cc = col - 1024;
                const int bb = row0 >> 10, ss = row0 & 1023;
                bf16x4 pv;
                #pragma unroll
                for (int r = 0; r < 4; r++) pv[r] = (__bf16)vv[r];
                *(bf16x4*)&Vt[((size_t)(bb * Hn + (cc >> 6)) * DKn + (cc & 63)) * Sn + ss] = pv;
            }
        }
    }
}

// ---------------------------------------------------------------------------
// MFMA flash attention (causal), LDS-staged K/V, wave-split tile pair.
// qkv: [M][1536] bf16; Vt: [b*8+h][64][1024] bf16.
// Block = (pair pr, h, b), 512 threads = 8 waves:
//   waves 0-3 own q-tile qtA=pr (16 rows each), waves 4-7 own qtB=15-pr.
// v5: the A/B softmaxes (independent) now run CONCURRENTLY on different
// waves instead of serially in one wave; waves/CU 8 -> 16 (2 blocks x 8).
// K/V tiles staged ONCE per block (shared by all 8 waves), double-buffered,
// one __syncthreads per k-step. XOR swizzle u^=(row&7) both sides.
// Grid linearized so id%8==h: all pr/b blocks of one h share an XCD L2.
// ---------------------------------------------------------------------------
__device__ __forceinline__ void softmax_update(
    f32x4 sv[4], float m[4], float l[4], f32x4 acc[4],
    bool diag, int wave16, int quad, int m16,
    __bf16 (*Pw)[72], bf16x8& pf0, bf16x8& pf1)
{
    #pragma unroll
    for (int j = 0; j < 4; j++)
        #pragma unroll
        for (int r = 0; r < 4; r++) {
            float v = sv[j][r] * 0.125f;    // 1/sqrt(64)
            if (diag && (j * 16 + m16) > (wave16 + quad * 4 + r)) v = -1e30f;
            sv[j][r] = v;
        }

    float pm[4];
    #pragma unroll
    for (int r = 0; r < 4; r++)
        pm[r] = fmaxf(fmaxf(sv[0][r], sv[1][r]), fmaxf(sv[2][r], sv[3][r]));
    #pragma unroll
    for (int off = 1; off < 16; off <<= 1)
        #pragma unroll
        for (int r = 0; r < 4; r++)
            pm[r] = fmaxf(pm[r], __shfl_xor(pm[r], off, 16));

    float al[4];
    #pragma unroll
    for (int r = 0; r < 4; r++) {
        float mn = fmaxf(m[r], pm[r]);
        al[r] = __expf(m[r] - mn);
        m[r] = mn;
    }

    float rs[4] = {0.f, 0.f, 0.f, 0.f};
    #pragma unroll
    for (int j = 0; j < 4; j++)
        #pragma unroll
        for (int r = 0; r < 4; r++) {
            float p = __expf(sv[j][r] - m[r]);
            rs[r] += p;
            Pw[quad * 4 + r][j * 16 + m16] = (__bf16)p;
        }
    #pragma unroll
    for (int off = 1; off < 16; off <<= 1)
        #pragma unroll
        for (int r = 0; r < 4; r++)
            rs[r] += __shfl_xor(rs[r], off, 16);
    #pragma unroll
    for (int r = 0; r < 4; r++) l[r] = l[r] * al[r] + rs[r];

    #pragma unroll
    for (int j = 0; j < 4; j++)
        #pragma unroll
        for (int r = 0; r < 4; r++) acc[j][r] *= al[r];

    pf0 = *(const bf16x8*)&Pw[m16][quad * 8];
    pf1 = *(const bf16x8*)&Pw[m16][32 + quad * 8];
}

__global__ __launch_bounds__(512, 4) void k_attn_mfma(
    const __bf16* __restrict__ qkv, const __bf16* __restrict__ Vt,
    __bf16* __restrict__ o)
{
    const int id = blockIdx.x;
    const int pr = id >> 6;            // 0..7
    const int b  = (id >> 3) & 7;
    const int h  = id & 7;             // id%8 = h -> pr/b blocks of one h share an XCD
    const int tid  = threadIdx.x;
    const int lane = tid & 63, wave = tid >> 6;   // 0..7
    const int m16  = lane & 15, quad = lane >> 4;
    const int isB  = wave >> 2;        // 0: tile A (qtA=pr), 1: tile B (qtB=15-pr)
    const int wave16 = (wave & 3) * 16;
    const int qtA  = pr, qtB = 15 - pr;
    const int qt   = isB ? qtB : qtA;

    __shared__ __bf16 Kb[2][64][64];     // double-buffered K tile (swizzled)
    __shared__ __bf16 Vb[2][64][64];     // double-buffered V tile (swizzled)
    __shared__ __bf16 Ps[8][16][72];     // per-wave P scratch

    const __bf16* base = qkv + (size_t)b * Sn * 1536 + h * DKn;   // Q +0, K +512
    const __bf16* vtb  = Vt + (size_t)(b * Hn + h) * DKn * Sn;
    __bf16 (*Pw)[72] = Ps[wave];

    // swizzled 16B-unit offsets for fragment reads (involution of stage swizzle)
    const int sw0 = ((quad    ) ^ (m16 & 7)) * 8;
    const int sw1 = ((quad + 4) ^ (m16 & 7)) * 8;

    // staging coords: 512 threads x 16B cover one 64x64 bf16 tile per call
    const int srow = tid >> 3;
    const int ssu  = ((tid & 7) ^ (srow & 7)) * 8;

    // stage K and V tile KT into LDS buffer BB. Linear LDS dest (gl_lds16
    // requirement), global source pre-swizzled: unit u' = u ^ (row&7).
    #define STAGE(KT, BB)                                                       \
        {                                                                       \
            gl_lds16(base + (size_t)((KT) * 64 + srow) * 1536 + 512 + ssu,      \
                     (void*)(&Kb[BB][0][0] + tid * 8));                         \
            gl_lds16(vtb + (size_t)srow * Sn + (KT) * 64 + ssu,                 \
                     (void*)(&Vb[BB][0][0] + tid * 8));                         \
        }

    STAGE(0, 0);   // issue tile-0 staging first, Q loads overlap it

    bf16x8 q0, q1;
    {
        const __bf16* qa = base + (size_t)(qt * 64 + wave16 + m16) * 1536 + quad * 8;
        q0 = *(const bf16x8*)qa; q1 = *(const bf16x8*)(qa + 32);
    }

    float m[4], l[4];
    f32x4 acc[4];
    #pragma unroll
    for (int r = 0; r < 4; r++) {
        m[r] = -1e30f; l[r] = 0.f;
        acc[r] = (f32x4){0.f, 0.f, 0.f, 0.f};
    }

    __syncthreads();   // tile 0 staged (barrier drains vmcnt)

    for (int kt = 0; kt <= qtB; kt++) {
        const int buf = kt & 1;
        if (kt < qtB) STAGE(kt + 1, buf ^ 1);   // issue-only; drains at barrier

        if (isB || kt <= qtA) {
            // ---- S = Q K^T from LDS ----
            f32x4 sv[4];
            __builtin_amdgcn_s_setprio(1);
            #pragma unroll
            for (int j = 0; j < 4; j++) {
                const int rk = j * 16 + m16;
                bf16x8 kf0 = *(const bf16x8*)&Kb[buf][rk][sw0];
                bf16x8 kf1 = *(const bf16x8*)&Kb[buf][rk][sw1];
                f32x4 s = (f32x4){0.f, 0.f, 0.f, 0.f};
                s = __builtin_amdgcn_mfma_f32_16x16x32_bf16(q0, kf0, s, 0, 0, 0);
                s = __builtin_amdgcn_mfma_f32_16x16x32_bf16(q1, kf1, s, 0, 0, 0);
                sv[j] = s;
            }
            __builtin_amdgcn_s_setprio(0);

            // ---- V fragments from LDS (issued before softmax; latency hides) ----
            bf16x8 vf[4][2];
            #pragma unroll
            for (int jd = 0; jd < 4; jd++) {
                const int rv = jd * 16 + m16;
                vf[jd][0] = *(const bf16x8*)&Vb[buf][rv][sw0];
                vf[jd][1] = *(const bf16x8*)&Vb[buf][rv][sw1];
            }

            // ---- online softmax (per-wave LDS round-trip, in-order DS) ----
            bf16x8 p0, p1;
            softmax_update(sv, m, l, acc, kt == qt, wave16, quad, m16, Pw, p0, p1);

            // ---- O += P V ----
            __builtin_amdgcn_s_setprio(1);
            #pragma unroll
            for (int jd = 0; jd < 4; jd++) {
                acc[jd] = __builtin_amdgcn_mfma_f32_16x16x32_bf16(p0, vf[jd][0], acc[jd], 0, 0, 0);
                acc[jd] = __builtin_amdgcn_mfma_f32_16x16x32_bf16(p1, vf[jd][1], acc[jd], 0, 0, 0);
            }
            __builtin_amdgcn_s_setprio(0);
        }

        __syncthreads();   // all reads of buf done + next-tile staging drained
    }
    #undef STAGE

    // epilogue: O / l for own tile
    #pragma unroll
    for (int r = 0; r < 4; r++) l[r] = 1.0f / l[r];
    #pragma unroll
    for (int jd = 0; jd < 4; jd++)
        #pragma unroll
        for (int r = 0; r < 4; r++) {
            const int row = b * Sn + qt * 64 + wave16 + quad * 4 + r;
            o[(size_t)row * Dn + h * DKn + jd * 16 + m16] = (__bf16)(acc[jd][r] * l[r]);
        }
}

// ---------------------------------------------------------------------------
// x = LayerNorm(t + x); writes fp32 x and bf16 copy xb.
// ---------------------------------------------------------------------------
__device__ inline float block_reduce_sum(float v, float* red, int tid) {
    red[tid] = v;
    __syncthreads();
    for (int s = 128; s > 0; s >>= 1) {
        if (tid < s) red[tid] += red[tid + s];
        __syncthreads();
    }
    float r = red[0];
    __syncthreads();
    return r;
}

__global__ __launch_bounds__(256) void k_residual_ln(
    const float* __restrict__ t, float* __restrict__ x, __bf16* __restrict__ xb,
    const float* __restrict__ g, const float* __restrict__ be)
{
    __shared__ float red[256];
    const int row = blockIdx.x, tid = threadIdx.x;
    const size_t base = (size_t)row * Dn;

    float v0 = t[base + tid] + x[base + tid];
    float v1 = t[base + 256 + tid] + x[base + 256 + tid];

    float mean = block_reduce_sum(v0 + v1, red, tid) * (1.0f / Dn);
    float d0 = v0 - mean, d1 = v1 - mean;
    float var = block_reduce_sum(d0 * d0 + d1 * d1, red, tid) * (1.0f / Dn);
    float inv = rsqrtf(var + 1e-5f);

    float o0 = d0 * inv * g[tid]       + be[tid];
    float o1 = d1 * inv * g[256 + tid] + be[256 + tid];
    x[base + tid]        = o0;
    x[base + 256 + tid]  = o1;
    xb[base + tid]       = (__bf16)o0;
    xb[base + 256 + tid] = (__bf16)o1;
}

// ---------------------------------------------------------------------------
// launcher
// ---------------------------------------------------------------------------
extern "C" void kernel_launch(void* const* d_in, const int* in_sizes, int n_in,
                              void* d_out, int out_size, void* d_ws, size_t ws_size,
                              hipStream_t stream)
{
    const float* x_in   = (const float*)d_in[0];
    const float* qkv_w  = (const float*)d_in[1];
    const float* qkv_b  = (const float*)d_in[2];
    const float* out_w  = (const float*)d_in[3];
    const float* out_b  = (const float*)d_in[4];
    const float* ln1_g  = (const float*)d_in[5];
    const float* ln1_b  = (const float*)d_in[6];
    const float* mlp_w1 = (const float*)d_in[7];
    const float* mlp_b1 = (const float*)d_in[8];
    const float* mlp_w2 = (const float*)d_in[9];
    const float* mlp_b2 = (const float*)d_in[10];
    const float* ln2_g  = (const float*)d_in[11];
    const float* ln2_b  = (const float*)d_in[12];

    // workspace layout (~94 MB)
    char* p = (char*)d_ws;
    float*  X    = (float*)p;  p += (size_t)Mn * Dn * 4;        // 16 MB fp32 residual
    __bf16* Xb   = (__bf16*)p; p += (size_t)Mn * Dn * 2;        //  8 MB bf16 x
    __bf16* QKVb = (__bf16*)p; p += (size_t)Mn * 3 * Dn * 2;    // 24 MB
    __bf16* AOb  = (__bf16*)p; p += (size_t)Mn * Dn * 2;        //  8 MB attn out
    __bf16* Hb   = (__bf16*)p; p += (size_t)Mn * DFFn * 2;      // 32 MB mlp hidden
    __bf16* Wq   = (__bf16*)p; p += (size_t)3 * Dn * Dn * 2;    // 1.5 MB  [1536][512]
    __bf16* Wo   = (__bf16*)p; p += (size_t)Dn * Dn * 2;        // 0.5 MB  [512][512]
    __bf16* W1   = (__bf16*)p; p += (size_t)DFFn * Dn * 2;      // 2 MB    [2048][512]
    __bf16* W2   = (__bf16*)p; p += (size_t)Dn * DFFn * 2;      // 2 MB    [512][2048]
    __bf16* Vt   = Hb;             // 8 MB, aliased: Hb dead during attention
    float* BUF3 = (float*)d_out;   // pre-LN temp lives in d_out

    const size_t xBytes = (size_t)Mn * Dn * sizeof(float);
    hipMemcpyAsync(X, x_in, xBytes, hipMemcpyDeviceToDevice, stream);
    k_cast_bf16<<<(Mn * Dn) / 256, 256, 0, stream>>>(x_in, Xb, Mn * Dn);

    for (int l = 0; l < Ln; l++) {
        // all 4 weight transposes in one launch
        k_trans_all<<<3072, dim3(32, 8), 0, stream>>>(
            qkv_w + (size_t)l * Dn * 3 * Dn, out_w + (size_t)l * Dn * Dn,
            mlp_w1 + (size_t)l * Dn * DFFn, mlp_w2 + (size_t)l * DFFn * Dn,
            Wq, Wo, W1, W2);

        // QKV projection -> bf16 [M,1536] + fused Vt scatter
        k_gemm_mfma<0, 1, 4, 1><<<768, 256, 0, stream>>>(
            Xb, Wq, qkv_b + (size_t)l * 3 * Dn, QKVb, Vt, Mn, 3 * Dn, Dn, 12);
        // LDS-staged MFMA flash attention (8 waves, tile pair split) -> bf16
        k_attn_mfma<<<512, 512, 0, stream>>>(QKVb, Vt, AOb);
        // output projection -> fp32 BUF3
        k_gemm_mfma<0, 0, 2, 0><<<512, 256, 0, stream>>>(
            AOb, Wo, out_b + (size_t)l * Dn, BUF3, nullptr, Mn, Dn, Dn, 8);
        // x = LN(proj + x)
        k_residual_ln<<<Mn, 256, 0, stream>>>(BUF3, X, Xb,
            ln1_g + (size_t)l * Dn, ln1_b + (size_t)l * Dn);
        // MLP up + ReLU -> bf16 [M,2048]  (overwrites Vt alias; attn done)
        k_gemm_mfma<1, 1, 4, 0><<<1024, 256, 0, stream>>>(
            Xb, W1, mlp_b1 + (size_t)l * DFFn, Hb, nullptr, Mn, DFFn, Dn, 16);
        // MLP down -> fp32 BUF3
        k_gemm_mfma<0, 0, 2, 0><<<512, 256, 0, stream>>>(
            Hb, W2, mlp_b2 + (size_t)l * Dn, BUF3, nullptr, Mn, Dn, DFFn, 8);
        // x = LN(x + mlp)
        k_residual_ln<<<Mn, 256, 0, stream>>>(BUF3, X, Xb,
            ln2_g + (size_t)l * Dn, ln2_b + (size_t)l * Dn);
    }

    hipMemcpyAsync(d_out, X, xBytes, hipMemcpyDeviceToDevice, stream);
}

// Round 5
// 1042.500 us; speedup vs baseline: 1.4194x; 1.0211x over previous
//
#include <hip/hip_runtime.h>
#include <math.h>

// Problem constants
#define Bn   8
#define Sn   1024
#define Dn   512
#define Hn   8
#define DKn  64
#define Ln   6
#define DFFn 2048
#define Mn   (Bn * Sn)   // 8192 rows

typedef __bf16 bf16x8 __attribute__((ext_vector_type(8)));
typedef __bf16 bf16x4 __attribute__((ext_vector_type(4)));
typedef __bf16 bf16x2 __attribute__((ext_vector_type(2)));
typedef float  f32x4  __attribute__((ext_vector_type(4)));

// async global->LDS, 16B per lane. LDS dest must be wave-uniform base + lane*16.
__device__ __forceinline__ void gl_lds16(const void* g, void* l) {
    __builtin_amdgcn_global_load_lds(
        (const __attribute__((address_space(1))) void*)g,
        (__attribute__((address_space(3))) void*)l, 16, 0, 0);
}

// ---------------------------------------------------------------------------
// fp32 -> bf16 cast (input) and bf16 -> fp32 cast (final output, x4)
// ---------------------------------------------------------------------------
__global__ __launch_bounds__(256) void k_cast_bf16(const float* __restrict__ in,
                                                   __bf16* __restrict__ out, int n) {
    int i = blockIdx.x * 256 + threadIdx.x;
    if (i < n) out[i] = (__bf16)in[i];
}

__global__ __launch_bounds__(256) void k_cast_f32(const __bf16* __restrict__ in,
                                                  float* __restrict__ out, int n) {
    int i = (blockIdx.x * 256 + threadIdx.x) * 4;
    if (i < n) {
        bf16x4 v = *(const bf16x4*)&in[i];
        f32x4 o = {(float)v[0], (float)v[1], (float)v[2], (float)v[3]};
        *(f32x4*)&out[i] = o;
    }
}

// ---------------------------------------------------------------------------
// All 4 weight matrices of one layer: W[K][N] fp32 -> Wt[N][K] bf16.
// 32x32 tiles, 32x8 threads. Tile ranges: Wq 768 | Wo 256 | W1 1024 | W2 1024.
// ---------------------------------------------------------------------------
__global__ __launch_bounds__(256) void k_trans_all(
    const float* __restrict__ qkv_w, const float* __restrict__ out_w,
    const float* __restrict__ w1, const float* __restrict__ w2,
    __bf16* __restrict__ Wq, __bf16* __restrict__ Wo,
    __bf16* __restrict__ W1o, __bf16* __restrict__ W2o)
{
    const int t = blockIdx.x;
    const float* src; __bf16* dst; int K, N, n0, k0;
    if (t < 768)       { src = qkv_w; dst = Wq;  K = 512;  N = 1536; int u = t;        n0 = (u % 48) * 32; k0 = (u / 48) * 32; }
    else if (t < 1024) { src = out_w; dst = Wo;  K = 512;  N = 512;  int u = t - 768;  n0 = (u % 16) * 32; k0 = (u / 16) * 32; }
    else if (t < 2048) { src = w1;    dst = W1o; K = 512;  N = 2048; int u = t - 1024; n0 = (u % 64) * 32; k0 = (u / 64) * 32; }
    else               { src = w2;    dst = W2o; K = 2048; N = 512;  int u = t - 2048; n0 = (u % 16) * 32; k0 = (u / 16) * 32; }

    __shared__ float tt[32][33];
    const int tx = threadIdx.x, ty = threadIdx.y;
    #pragma unroll
    for (int r = 0; r < 4; r++)
        tt[ty + 8 * r][tx] = src[(size_t)(k0 + ty + 8 * r) * N + n0 + tx];
    __syncthreads();
    #pragma unroll
    for (int r = 0; r < 4; r++)
        dst[(size_t)(n0 + ty + 8 * r) * K + k0 + tx] = (__bf16)tt[tx][ty + 8 * r];
}

// ---------------------------------------------------------------------------
// MFMA GEMM: C[M,N] = act(A[M,K]bf16 @ Bt[N,K]bf16^T + bias[N]fp32)
// Block: 256 thr = 4 waves (2x2). Tile: 128 x (JT*32). BK=64.
// (a) 1D grid + bijective chunked XCD swizzle.
// (b) XOR LDS swizzle both-sides (rule #21).
// VW=1 (QKV only): cols >=1024 are V -> also scatter into Vt[b*8+h][d][s].
// ---------------------------------------------------------------------------
template <int RELU, int OUTBF, int JT, int VW>
__global__ __launch_bounds__(256) void k_gemm_mfma(
    const __bf16* __restrict__ A, const __bf16* __restrict__ Bt,
    const float* __restrict__ bias, void* __restrict__ Cout,
    __bf16* __restrict__ Vt, int M, int N, int K, int NBX)
{
    constexpr int BN = JT * 32;   // 128 or 64
    __shared__ __bf16 As[128][64];
    __shared__ __bf16 Bs[BN][64];
    const int tid  = threadIdx.x;
    const int lane = tid & 63;
    const int wave = tid >> 6;
    const int wy   = wave >> 1, wx = wave & 1;
    const int m16  = lane & 15, quad = lane >> 4;

    // chunked XCD swizzle (all launches have gridDim.x % 8 == 0)
    const int cpx = gridDim.x >> 3;
    const int id  = (blockIdx.x & 7) * cpx + (blockIdx.x >> 3);
    const int bm  = (id / NBX) * 128;
    const int bn  = (id % NBX) * BN;

    f32x4 acc[4][JT];
    #pragma unroll
    for (int i = 0; i < 4; i++)
        #pragma unroll
        for (int j = 0; j < JT; j++)
            acc[i][j] = (f32x4){0.f, 0.f, 0.f, 0.f};

    const __bf16* Ap = A  + (size_t)bm * K;
    const __bf16* Bp = Bt + (size_t)bn * K;

    // swizzled 16B-unit byte offsets for fragment reads (involution of stage)
    const int sw0 = ((quad    ) ^ (m16 & 7)) * 8;
    const int sw1 = ((quad + 4) ^ (m16 & 7)) * 8;

    for (int k0 = 0; k0 < K; k0 += 64) {
        __syncthreads();
        #pragma unroll
        for (int c = 0; c < 4; c++) {           // A: 128x64 bf16 = 1024 x 16B
            int lin = tid + c * 256;
            int row = lin >> 3, uu = lin & 7;
            int su  = (uu ^ (row & 7)) << 3;
            gl_lds16(Ap + (size_t)row * K + k0 + su, (void*)(&As[0][0] + lin * 8));
        }
        #pragma unroll
        for (int c = 0; c < JT; c++) {          // B: BNx64 bf16
            int lin = tid + c * 256;
            int row = lin >> 3, uu = lin & 7;
            int su  = (uu ^ (row & 7)) << 3;
            gl_lds16(Bp + (size_t)row * K + k0 + su, (void*)(&Bs[0][0] + lin * 8));
        }
        __syncthreads();

        bf16x8 af[4][2], bfr[JT][2];
        #pragma unroll
        for (int i = 0; i < 4; i++) {
            af[i][0] = *(const bf16x8*)&As[wy * 64 + i * 16 + m16][sw0];
            af[i][1] = *(const bf16x8*)&As[wy * 64 + i * 16 + m16][sw1];
        }
        #pragma unroll
        for (int j = 0; j < JT; j++) {
            bfr[j][0] = *(const bf16x8*)&Bs[wx * JT * 16 + j * 16 + m16][sw0];
            bfr[j][1] = *(const bf16x8*)&Bs[wx * JT * 16 + j * 16 + m16][sw1];
        }
        #pragma unroll
        for (int hc = 0; hc < 2; hc++)
            #pragma unroll
            for (int i = 0; i < 4; i++)
                #pragma unroll
                for (int j = 0; j < JT; j++)
                    acc[i][j] = __builtin_amdgcn_mfma_f32_16x16x32_bf16(
                        af[i][hc], bfr[j][hc], acc[i][j], 0, 0, 0);
    }

    float*  Cf = (float*)Cout;
    __bf16* Cb = (__bf16*)Cout;
    #pragma unroll
    for (int i = 0; i < 4; i++) {
        const int row0 = bm + wy * 64 + i * 16 + quad * 4;
        #pragma unroll
        for (int j = 0; j < JT; j++) {
            const int col = bn + wx * JT * 16 + j * 16 + m16;
            const float bv = bias[col];
            float vv[4];
            #pragma unroll
            for (int r = 0; r < 4; r++) {
                float v = acc[i][j][r] + bv;
                if (RELU) v = fmaxf(v, 0.f);
                vv[r] = v;
                if (OUTBF) Cb[(size_t)(row0 + r) * N + col] = (__bf16)v;
                else       Cf[(size_t)(row0 + r) * N + col] = v;
            }
            if (VW && col >= 1024) {            // V slice -> Vt[b*8+h][d][s]
                const int cc = col - 1024;
                const int bb = row0 >> 10, ss = row0 & 1023;
                bf16x4 pv;
                #pragma unroll
                for (int r = 0; r < 4; r++) pv[r] = (__bf16)vv[r];
                *(bf16x4*)&Vt[((size_t)(bb * Hn + (cc >> 6)) * DKn + (cc & 63)) * Sn + ss] = pv;
            }
        }
    }
}

// ---------------------------------------------------------------------------
// MFMA flash attention (causal), LDS-staged K/V, wave-split tile pair.
// Block = (pair pr, h, b), 512 threads = 8 waves:
//   waves 0-3 own q-tile qtA=pr (16 rows each), waves 4-7 own qtB=15-pr.
// K/V staged once per block (double-buffered LDS), XOR swizzle both sides.
// Grid linearized so id%8==h (XCD L2 sharing).
// v6: T13 defer-max — skip the O-rescale when the wave's row-max growth
// <= 8 (wave-uniform via __all); P bounded by e^8, fp32 accum tolerates.
// ---------------------------------------------------------------------------
__device__ __forceinline__ void softmax_update(
    f32x4 sv[4], float m[4], float l[4], f32x4 acc[4],
    bool diag, int wave16, int quad, int m16,
    __bf16 (*Pw)[72], bf16x8& pf0, bf16x8& pf1)
{
    #pragma unroll
    for (int j = 0; j < 4; j++)
        #pragma unroll
        for (int r = 0; r < 4; r++) {
            float v = sv[j][r] * 0.125f;    // 1/sqrt(64)
            if (diag && (j * 16 + m16) > (wave16 + quad * 4 + r)) v = -1e30f;
            sv[j][r] = v;
        }

    float pm[4];
    #pragma unroll
    for (int r = 0; r < 4; r++)
        pm[r] = fmaxf(fmaxf(sv[0][r], sv[1][r]), fmaxf(sv[2][r], sv[3][r]));
    #pragma unroll
    for (int off = 1; off < 16; off <<= 1)
        #pragma unroll
        for (int r = 0; r < 4; r++)
            pm[r] = fmaxf(pm[r], __shfl_xor(pm[r], off, 16));

    // T13 defer-max: only rescale when some row grew past m + 8
    bool grew = false;
    #pragma unroll
    for (int r = 0; r < 4; r++) grew = grew || (pm[r] > m[r] + 8.f);
    if (__any((int)grew)) {
        #pragma unroll
        for (int r = 0; r < 4; r++) {
            float mn = fmaxf(m[r], pm[r]);
            float al = __expf(m[r] - mn);
            m[r] = mn;
            l[r] *= al;
            #pragma unroll
            for (int j = 0; j < 4; j++) acc[j][r] *= al;
        }
    }

    float rs[4] = {0.f, 0.f, 0.f, 0.f};
    #pragma unroll
    for (int j = 0; j < 4; j++)
        #pragma unroll
        for (int r = 0; r < 4; r++) {
            float p = __expf(sv[j][r] - m[r]);   // bounded by e^8 when deferred
            rs[r] += p;
            Pw[quad * 4 + r][j * 16 + m16] = (__bf16)p;
        }
    #pragma unroll
    for (int off = 1; off < 16; off <<= 1)
        #pragma unroll
        for (int r = 0; r < 4; r++)
            rs[r] += __shfl_xor(rs[r], off, 16);
    #pragma unroll
    for (int r = 0; r < 4; r++) l[r] += rs[r];

    pf0 = *(const bf16x8*)&Pw[m16][quad * 8];
    pf1 = *(const bf16x8*)&Pw[m16][32 + quad * 8];
}

__global__ __launch_bounds__(512, 4) void k_attn_mfma(
    const __bf16* __restrict__ qkv, const __bf16* __restrict__ Vt,
    __bf16* __restrict__ o)
{
    const int id = blockIdx.x;
    const int pr = id >> 6;            // 0..7
    const int b  = (id >> 3) & 7;
    const int h  = id & 7;             // id%8 = h -> pr/b blocks of one h share an XCD
    const int tid  = threadIdx.x;
    const int lane = tid & 63, wave = tid >> 6;   // 0..7
    const int m16  = lane & 15, quad = lane >> 4;
    const int isB  = wave >> 2;        // 0: tile A (qtA=pr), 1: tile B (qtB=15-pr)
    const int wave16 = (wave & 3) * 16;
    const int qtA  = pr, qtB = 15 - pr;
    const int qt   = isB ? qtB : qtA;

    __shared__ __bf16 Kb[2][64][64];     // double-buffered K tile (swizzled)
    __shared__ __bf16 Vb[2][64][64];     // double-buffered V tile (swizzled)
    __shared__ __bf16 Ps[8][16][72];     // per-wave P scratch

    const __bf16* base = qkv + (size_t)b * Sn * 1536 + h * DKn;   // Q +0, K +512
    const __bf16* vtb  = Vt + (size_t)(b * Hn + h) * DKn * Sn;
    __bf16 (*Pw)[72] = Ps[wave];

    // swizzled 16B-unit offsets for fragment reads (involution of stage swizzle)
    const int sw0 = ((quad    ) ^ (m16 & 7)) * 8;
    const int sw1 = ((quad + 4) ^ (m16 & 7)) * 8;

    // staging coords: 512 threads x 16B cover one 64x64 bf16 tile per call
    const int srow = tid >> 3;
    const int ssu  = ((tid & 7) ^ (srow & 7)) * 8;

    #define STAGE(KT, BB)                                                       \
        {                                                                       \
            gl_lds16(base + (size_t)((KT) * 64 + srow) * 1536 + 512 + ssu,      \
                     (void*)(&Kb[BB][0][0] + tid * 8));                         \
            gl_lds16(vtb + (size_t)srow * Sn + (KT) * 64 + ssu,                 \
                     (void*)(&Vb[BB][0][0] + tid * 8));                         \
        }

    STAGE(0, 0);   // issue tile-0 staging first, Q loads overlap it

    bf16x8 q0, q1;
    {
        const __bf16* qa = base + (size_t)(qt * 64 + wave16 + m16) * 1536 + quad * 8;
        q0 = *(const bf16x8*)qa; q1 = *(const bf16x8*)(qa + 32);
    }

    float m[4], l[4];
    f32x4 acc[4];
    #pragma unroll
    for (int r = 0; r < 4; r++) {
        m[r] = -1e30f; l[r] = 0.f;
        acc[r] = (f32x4){0.f, 0.f, 0.f, 0.f};
    }

    __syncthreads();   // tile 0 staged (barrier drains vmcnt)

    for (int kt = 0; kt <= qtB; kt++) {
        const int buf = kt & 1;
        if (kt < qtB) STAGE(kt + 1, buf ^ 1);   // issue-only; drains at barrier

        if (isB || kt <= qtA) {
            // ---- S = Q K^T from LDS ----
            f32x4 sv[4];
            __builtin_amdgcn_s_setprio(1);
            #pragma unroll
            for (int j = 0; j < 4; j++) {
                const int rk = j * 16 + m16;
                bf16x8 kf0 = *(const bf16x8*)&Kb[buf][rk][sw0];
                bf16x8 kf1 = *(const bf16x8*)&Kb[buf][rk][sw1];
                f32x4 s = (f32x4){0.f, 0.f, 0.f, 0.f};
                s = __builtin_amdgcn_mfma_f32_16x16x32_bf16(q0, kf0, s, 0, 0, 0);
                s = __builtin_amdgcn_mfma_f32_16x16x32_bf16(q1, kf1, s, 0, 0, 0);
                sv[j] = s;
            }
            __builtin_amdgcn_s_setprio(0);

            // ---- V fragments from LDS (issued before softmax; latency hides) ----
            bf16x8 vf[4][2];
            #pragma unroll
            for (int jd = 0; jd < 4; jd++) {
                const int rv = jd * 16 + m16;
                vf[jd][0] = *(const bf16x8*)&Vb[buf][rv][sw0];
                vf[jd][1] = *(const bf16x8*)&Vb[buf][rv][sw1];
            }

            // ---- online softmax (per-wave LDS round-trip, in-order DS) ----
            bf16x8 p0, p1;
            softmax_update(sv, m, l, acc, kt == qt, wave16, quad, m16, Pw, p0, p1);

            // ---- O += P V ----
            __builtin_amdgcn_s_setprio(1);
            #pragma unroll
            for (int jd = 0; jd < 4; jd++) {
                acc[jd] = __builtin_amdgcn_mfma_f32_16x16x32_bf16(p0, vf[jd][0], acc[jd], 0, 0, 0);
                acc[jd] = __builtin_amdgcn_mfma_f32_16x16x32_bf16(p1, vf[jd][1], acc[jd], 0, 0, 0);
            }
            __builtin_amdgcn_s_setprio(0);
        }

        __syncthreads();   // all reads of buf done + next-tile staging drained
    }
    #undef STAGE

    // epilogue: O / l for own tile
    #pragma unroll
    for (int r = 0; r < 4; r++) l[r] = 1.0f / l[r];
    #pragma unroll
    for (int jd = 0; jd < 4; jd++)
        #pragma unroll
        for (int r = 0; r < 4; r++) {
            const int row = b * Sn + qt * 64 + wave16 + quad * 4 + r;
            o[(size_t)row * Dn + h * DKn + jd * 16 + m16] = (__bf16)(acc[jd][r] * l[r]);
        }
}

// ---------------------------------------------------------------------------
// xb = LayerNorm(t + xb), all bf16 I/O, fp32 math. One row per block,
// thread handles cols 2*tid, 2*tid+1 (bf16x2 / float2 vectorized).
// ---------------------------------------------------------------------------
__device__ inline float block_reduce_sum(float v, float* red, int tid) {
    red[tid] = v;
    __syncthreads();
    for (int s = 128; s > 0; s >>= 1) {
        if (tid < s) red[tid] += red[tid + s];
        __syncthreads();
    }
    float r = red[0];
    __syncthreads();
    return r;
}

__global__ __launch_bounds__(256) void k_residual_ln(
    const __bf16* __restrict__ t, __bf16* __restrict__ xb,
    const float* __restrict__ g, const float* __restrict__ be)
{
    __shared__ float red[256];
    const int row = blockIdx.x, tid = threadIdx.x;
    const size_t base = (size_t)row * Dn + tid * 2;

    bf16x2 tv = *(const bf16x2*)&t[base];
    bf16x2 xv = *(const bf16x2*)&xb[base];
    float v0 = (float)tv[0] + (float)xv[0];
    float v1 = (float)tv[1] + (float)xv[1];

    float mean = block_reduce_sum(v0 + v1, red, tid) * (1.0f / Dn);
    float d0 = v0 - mean, d1 = v1 - mean;
    float var = block_reduce_sum(d0 * d0 + d1 * d1, red, tid) * (1.0f / Dn);
    float inv = rsqrtf(var + 1e-5f);

    const float2 gv = *(const float2*)&g[tid * 2];
    const float2 bv = *(const float2*)&be[tid * 2];
    bf16x2 ov;
    ov[0] = (__bf16)(d0 * inv * gv.x + bv.x);
    ov[1] = (__bf16)(d1 * inv * gv.y + bv.y);
    *(bf16x2*)&xb[base] = ov;
}

// ---------------------------------------------------------------------------
// launcher
// ---------------------------------------------------------------------------
extern "C" void kernel_launch(void* const* d_in, const int* in_sizes, int n_in,
                              void* d_out, int out_size, void* d_ws, size_t ws_size,
                              hipStream_t stream)
{
    const float* x_in   = (const float*)d_in[0];
    const float* qkv_w  = (const float*)d_in[1];
    const float* qkv_b  = (const float*)d_in[2];
    const float* out_w  = (const float*)d_in[3];
    const float* out_b  = (const float*)d_in[4];
    const float* ln1_g  = (const float*)d_in[5];
    const float* ln1_b  = (const float*)d_in[6];
    const float* mlp_w1 = (const float*)d_in[7];
    const float* mlp_b1 = (const float*)d_in[8];
    const float* mlp_w2 = (const float*)d_in[9];
    const float* mlp_b2 = (const float*)d_in[10];
    const float* ln2_g  = (const float*)d_in[11];
    const float* ln2_b  = (const float*)d_in[12];

    // workspace layout (~78 MB); residual lives in bf16 Xb only
    char* p = (char*)d_ws;
    __bf16* Xb   = (__bf16*)p; p += (size_t)Mn * Dn * 2;        //  8 MB bf16 residual/x
    __bf16* QKVb = (__bf16*)p; p += (size_t)Mn * 3 * Dn * 2;    // 24 MB
    __bf16* AOb  = (__bf16*)p; p += (size_t)Mn * Dn * 2;        //  8 MB attn out
    __bf16* Hb   = (__bf16*)p; p += (size_t)Mn * DFFn * 2;      // 32 MB mlp hidden
    __bf16* Wq   = (__bf16*)p; p += (size_t)3 * Dn * Dn * 2;    // 1.5 MB  [1536][512]
    __bf16* Wo   = (__bf16*)p; p += (size_t)Dn * Dn * 2;        // 0.5 MB  [512][512]
    __bf16* W1   = (__bf16*)p; p += (size_t)DFFn * Dn * 2;      // 2 MB    [2048][512]
    __bf16* W2   = (__bf16*)p; p += (size_t)Dn * DFFn * 2;      // 2 MB    [512][2048]
    __bf16* Vt   = Hb;               // 8 MB, aliased: Hb dead during attention
    __bf16* BUF3b = (__bf16*)d_out;  // bf16 pre-LN temp lives in d_out (8 of 16 MB)

    k_cast_bf16<<<(Mn * Dn) / 256, 256, 0, stream>>>(x_in, Xb, Mn * Dn);

    for (int l = 0; l < Ln; l++) {
        // all 4 weight transposes in one launch
        k_trans_all<<<3072, dim3(32, 8), 0, stream>>>(
            qkv_w + (size_t)l * Dn * 3 * Dn, out_w + (size_t)l * Dn * Dn,
            mlp_w1 + (size_t)l * Dn * DFFn, mlp_w2 + (size_t)l * DFFn * Dn,
            Wq, Wo, W1, W2);

        // QKV projection -> bf16 [M,1536] + fused Vt scatter
        k_gemm_mfma<0, 1, 4, 1><<<768, 256, 0, stream>>>(
            Xb, Wq, qkv_b + (size_t)l * 3 * Dn, QKVb, Vt, Mn, 3 * Dn, Dn, 12);
        // LDS-staged MFMA flash attention (8 waves, tile pair split) -> bf16
        k_attn_mfma<<<512, 512, 0, stream>>>(QKVb, Vt, AOb);
        // output projection -> bf16 BUF3b
        k_gemm_mfma<0, 1, 2, 0><<<512, 256, 0, stream>>>(
            AOb, Wo, out_b + (size_t)l * Dn, BUF3b, nullptr, Mn, Dn, Dn, 8);
        // x = LN(proj + x)   (bf16 in/out, fp32 math)
        k_residual_ln<<<Mn, 256, 0, stream>>>(BUF3b, Xb,
            ln1_g + (size_t)l * Dn, ln1_b + (size_t)l * Dn);
        // MLP up + ReLU -> bf16 [M,2048]  (overwrites Vt alias; attn done)
        k_gemm_mfma<1, 1, 4, 0><<<1024, 256, 0, stream>>>(
            Xb, W1, mlp_b1 + (size_t)l * DFFn, Hb, nullptr, Mn, DFFn, Dn, 16);
        // MLP down -> bf16 BUF3b
        k_gemm_mfma<0, 1, 2, 0><<<512, 256, 0, stream>>>(
            Hb, W2, mlp_b2 + (size_t)l * Dn, BUF3b, nullptr, Mn, Dn, DFFn, 8);
        // x = LN(x + mlp)
        k_residual_ln<<<Mn, 256, 0, stream>>>(BUF3b, Xb,
            ln2_g + (size_t)l * Dn, ln2_b + (size_t)l * Dn);
    }

    // final bf16 -> fp32 output
    k_cast_f32<<<(Mn * Dn) / 1024, 256, 0, stream>>>(Xb, (float*)d_out, Mn * Dn);
}

// Round 6
// 956.149 us; speedup vs baseline: 1.5476x; 1.0903x over previous
//
#include <hip/hip_runtime.h>
#include <math.h>

// Problem constants
#define Bn   8
#define Sn   1024
#define Dn   512
#define Hn   8
#define DKn  64
#define Ln   6
#define DFFn 2048
#define Mn   (Bn * Sn)   // 8192 rows

typedef __bf16 bf16x8 __attribute__((ext_vector_type(8)));
typedef __bf16 bf16x4 __attribute__((ext_vector_type(4)));
typedef __bf16 bf16x2 __attribute__((ext_vector_type(2)));
typedef float  f32x4  __attribute__((ext_vector_type(4)));

// async global->LDS, 16B per lane. LDS dest must be wave-uniform base + lane*16.
__device__ __forceinline__ void gl_lds16(const void* g, void* l) {
    __builtin_amdgcn_global_load_lds(
        (const __attribute__((address_space(1))) void*)g,
        (__attribute__((address_space(3))) void*)l, 16, 0, 0);
}

// ---------------------------------------------------------------------------
// fp32 -> bf16 cast (input)
// ---------------------------------------------------------------------------
__global__ __launch_bounds__(256) void k_cast_bf16(const float* __restrict__ in,
                                                   __bf16* __restrict__ out, int n) {
    int i = blockIdx.x * 256 + threadIdx.x;
    if (i < n) out[i] = (__bf16)in[i];
}

// ---------------------------------------------------------------------------
// ALL weight matrices of ALL 6 layers: W[K][N] fp32 -> Wt[N][K] bf16.
// One launch (hoisted out of the layer loop; weights are layer-loop invariant).
// 32x32 tiles, 32x8 threads. Per-layer tile ranges: Wq 768 | Wo 256 | W1 1024
// | W2 1024 (3072 tiles/layer, 6 layers = 18432 blocks).
// ---------------------------------------------------------------------------
__global__ __launch_bounds__(256) void k_trans_all(
    const float* __restrict__ qkv_w, const float* __restrict__ out_w,
    const float* __restrict__ w1, const float* __restrict__ w2,
    __bf16* __restrict__ Wq, __bf16* __restrict__ Wo,
    __bf16* __restrict__ W1o, __bf16* __restrict__ W2o)
{
    const int lay = blockIdx.x / 3072;
    const int t   = blockIdx.x % 3072;
    const float* src; __bf16* dst; int K, N, n0, k0;
    if (t < 768)       { src = qkv_w + (size_t)lay * Dn * 3 * Dn; dst = Wq  + (size_t)lay * 3 * Dn * Dn;
                         K = 512;  N = 1536; int u = t;        n0 = (u % 48) * 32; k0 = (u / 48) * 32; }
    else if (t < 1024) { src = out_w + (size_t)lay * Dn * Dn;     dst = Wo  + (size_t)lay * Dn * Dn;
                         K = 512;  N = 512;  int u = t - 768;  n0 = (u % 16) * 32; k0 = (u / 16) * 32; }
    else if (t < 2048) { src = w1 + (size_t)lay * Dn * DFFn;      dst = W1o + (size_t)lay * DFFn * Dn;
                         K = 512;  N = 2048; int u = t - 1024; n0 = (u % 64) * 32; k0 = (u / 64) * 32; }
    else               { src = w2 + (size_t)lay * DFFn * Dn;      dst = W2o + (size_t)lay * Dn * DFFn;
                         K = 2048; N = 512;  int u = t - 2048; n0 = (u % 16) * 32; k0 = (u / 16) * 32; }

    __shared__ float tt[32][33];
    const int tx = threadIdx.x, ty = threadIdx.y;
    #pragma unroll
    for (int r = 0; r < 4; r++)
        tt[ty + 8 * r][tx] = src[(size_t)(k0 + ty + 8 * r) * N + n0 + tx];
    __syncthreads();
    #pragma unroll
    for (int r = 0; r < 4; r++)
        dst[(size_t)(n0 + ty + 8 * r) * K + k0 + tx] = (__bf16)tt[tx][ty + 8 * r];
}

// ---------------------------------------------------------------------------
// MFMA GEMM: C[M,N] = act(A[M,K]bf16 @ Bt[N,K]bf16^T + bias[N]fp32)
// Block: 256 thr = 4 waves (2x2). Tile: 128 x (JT*32). BK=64.
// (a) 1D grid + bijective chunked XCD swizzle.
// (b) XOR LDS swizzle both-sides (rule #21).
// VW=1 (QKV only): cols >=1024 are V -> also scatter into Vt[b*8+h][d][s].
// ---------------------------------------------------------------------------
template <int RELU, int OUTBF, int JT, int VW>
__global__ __launch_bounds__(256) void k_gemm_mfma(
    const __bf16* __restrict__ A, const __bf16* __restrict__ Bt,
    const float* __restrict__ bias, void* __restrict__ Cout,
    __bf16* __restrict__ Vt, int M, int N, int K, int NBX)
{
    constexpr int BN = JT * 32;   // 128 or 64
    __shared__ __bf16 As[128][64];
    __shared__ __bf16 Bs[BN][64];
    const int tid  = threadIdx.x;
    const int lane = tid & 63;
    const int wave = tid >> 6;
    const int wy   = wave >> 1, wx = wave & 1;
    const int m16  = lane & 15, quad = lane >> 4;

    // chunked XCD swizzle (all launches have gridDim.x % 8 == 0)
    const int cpx = gridDim.x >> 3;
    const int id  = (blockIdx.x & 7) * cpx + (blockIdx.x >> 3);
    const int bm  = (id / NBX) * 128;
    const int bn  = (id % NBX) * BN;

    f32x4 acc[4][JT];
    #pragma unroll
    for (int i = 0; i < 4; i++)
        #pragma unroll
        for (int j = 0; j < JT; j++)
            acc[i][j] = (f32x4){0.f, 0.f, 0.f, 0.f};

    const __bf16* Ap = A  + (size_t)bm * K;
    const __bf16* Bp = Bt + (size_t)bn * K;

    // swizzled 16B-unit byte offsets for fragment reads (involution of stage)
    const int sw0 = ((quad    ) ^ (m16 & 7)) * 8;
    const int sw1 = ((quad + 4) ^ (m16 & 7)) * 8;

    for (int k0 = 0; k0 < K; k0 += 64) {
        __syncthreads();
        #pragma unroll
        for (int c = 0; c < 4; c++) {           // A: 128x64 bf16 = 1024 x 16B
            int lin = tid + c * 256;
            int row = lin >> 3, uu = lin & 7;
            int su  = (uu ^ (row & 7)) << 3;
            gl_lds16(Ap + (size_t)row * K + k0 + su, (void*)(&As[0][0] + lin * 8));
        }
        #pragma unroll
        for (int c = 0; c < JT; c++) {          // B: BNx64 bf16
            int lin = tid + c * 256;
            int row = lin >> 3, uu = lin & 7;
            int su  = (uu ^ (row & 7)) << 3;
            gl_lds16(Bp + (size_t)row * K + k0 + su, (void*)(&Bs[0][0] + lin * 8));
        }
        __syncthreads();

        bf16x8 af[4][2], bfr[JT][2];
        #pragma unroll
        for (int i = 0; i < 4; i++) {
            af[i][0] = *(const bf16x8*)&As[wy * 64 + i * 16 + m16][sw0];
            af[i][1] = *(const bf16x8*)&As[wy * 64 + i * 16 + m16][sw1];
        }
        #pragma unroll
        for (int j = 0; j < JT; j++) {
            bfr[j][0] = *(const bf16x8*)&Bs[wx * JT * 16 + j * 16 + m16][sw0];
            bfr[j][1] = *(const bf16x8*)&Bs[wx * JT * 16 + j * 16 + m16][sw1];
        }
        #pragma unroll
        for (int hc = 0; hc < 2; hc++)
            #pragma unroll
            for (int i = 0; i < 4; i++)
                #pragma unroll
                for (int j = 0; j < JT; j++)
                    acc[i][j] = __builtin_amdgcn_mfma_f32_16x16x32_bf16(
                        af[i][hc], bfr[j][hc], acc[i][j], 0, 0, 0);
    }

    float*  Cf = (float*)Cout;
    __bf16* Cb = (__bf16*)Cout;
    #pragma unroll
    for (int i = 0; i < 4; i++) {
        const int row0 = bm + wy * 64 + i * 16 + quad * 4;
        #pragma unroll
        for (int j = 0; j < JT; j++) {
            const int col = bn + wx * JT * 16 + j * 16 + m16;
            const float bv = bias[col];
            float vv[4];
            #pragma unroll
            for (int r = 0; r < 4; r++) {
                float v = acc[i][j][r] + bv;
                if (RELU) v = fmaxf(v, 0.f);
                vv[r] = v;
                if (OUTBF) Cb[(size_t)(row0 + r) * N + col] = (__bf16)v;
                else       Cf[(size_t)(row0 + r) * N + col] = v;
            }
            if (VW && col >= 1024) {            // V slice -> Vt[b*8+h][d][s]
                const int cc = col - 1024;
                const int bb = row0 >> 10, ss = row0 & 1023;
                bf16x4 pv;
                #pragma unroll
                for (int r = 0; r < 4; r++) pv[r] = (__bf16)vv[r];
                *(bf16x4*)&Vt[((size_t)(bb * Hn + (cc >> 6)) * DKn + (cc & 63)) * Sn + ss] = pv;
            }
        }
    }
}

// ---------------------------------------------------------------------------
// MFMA flash attention (causal), LDS-staged K/V, wave-split tile pair.
// Block = (pair pr, h, b), 512 threads = 8 waves:
//   waves 0-3 own q-tile qtA=pr (16 rows each), waves 4-7 own qtB=15-pr.
// K/V staged once per block (double-buffered LDS), XOR swizzle both sides.
// Grid linearized so id%8==h (XCD L2 sharing). T13 defer-max.
// ---------------------------------------------------------------------------
__device__ __forceinline__ void softmax_update(
    f32x4 sv[4], float m[4], float l[4], f32x4 acc[4],
    bool diag, int wave16, int quad, int m16,
    __bf16 (*Pw)[72], bf16x8& pf0, bf16x8& pf1)
{
    #pragma unroll
    for (int j = 0; j < 4; j++)
        #pragma unroll
        for (int r = 0; r < 4; r++) {
            float v = sv[j][r] * 0.125f;    // 1/sqrt(64)
            if (diag && (j * 16 + m16) > (wave16 + quad * 4 + r)) v = -1e30f;
            sv[j][r] = v;
        }

    float pm[4];
    #pragma unroll
    for (int r = 0; r < 4; r++)
        pm[r] = fmaxf(fmaxf(sv[0][r], sv[1][r]), fmaxf(sv[2][r], sv[3][r]));
    #pragma unroll
    for (int off = 1; off < 16; off <<= 1)
        #pragma unroll
        for (int r = 0; r < 4; r++)
            pm[r] = fmaxf(pm[r], __shfl_xor(pm[r], off, 16));

    // T13 defer-max: only rescale when some row grew past m + 8
    bool grew = false;
    #pragma unroll
    for (int r = 0; r < 4; r++) grew = grew || (pm[r] > m[r] + 8.f);
    if (__any((int)grew)) {
        #pragma unroll
        for (int r = 0; r < 4; r++) {
            float mn = fmaxf(m[r], pm[r]);
            float al = __expf(m[r] - mn);
            m[r] = mn;
            l[r] *= al;
            #pragma unroll
            for (int j = 0; j < 4; j++) acc[j][r] *= al;
        }
    }

    float rs[4] = {0.f, 0.f, 0.f, 0.f};
    #pragma unroll
    for (int j = 0; j < 4; j++)
        #pragma unroll
        for (int r = 0; r < 4; r++) {
            float p = __expf(sv[j][r] - m[r]);   // bounded by e^8 when deferred
            rs[r] += p;
            Pw[quad * 4 + r][j * 16 + m16] = (__bf16)p;
        }
    #pragma unroll
    for (int off = 1; off < 16; off <<= 1)
        #pragma unroll
        for (int r = 0; r < 4; r++)
            rs[r] += __shfl_xor(rs[r], off, 16);
    #pragma unroll
    for (int r = 0; r < 4; r++) l[r] += rs[r];

    pf0 = *(const bf16x8*)&Pw[m16][quad * 8];
    pf1 = *(const bf16x8*)&Pw[m16][32 + quad * 8];
}

__global__ __launch_bounds__(512, 4) void k_attn_mfma(
    const __bf16* __restrict__ qkv, const __bf16* __restrict__ Vt,
    __bf16* __restrict__ o)
{
    const int id = blockIdx.x;
    const int pr = id >> 6;            // 0..7
    const int b  = (id >> 3) & 7;
    const int h  = id & 7;             // id%8 = h -> pr/b blocks of one h share an XCD
    const int tid  = threadIdx.x;
    const int lane = tid & 63, wave = tid >> 6;   // 0..7
    const int m16  = lane & 15, quad = lane >> 4;
    const int isB  = wave >> 2;        // 0: tile A (qtA=pr), 1: tile B (qtB=15-pr)
    const int wave16 = (wave & 3) * 16;
    const int qtA  = pr, qtB = 15 - pr;
    const int qt   = isB ? qtB : qtA;

    __shared__ __bf16 Kb[2][64][64];     // double-buffered K tile (swizzled)
    __shared__ __bf16 Vb[2][64][64];     // double-buffered V tile (swizzled)
    __shared__ __bf16 Ps[8][16][72];     // per-wave P scratch

    const __bf16* base = qkv + (size_t)b * Sn * 1536 + h * DKn;   // Q +0, K +512
    const __bf16* vtb  = Vt + (size_t)(b * Hn + h) * DKn * Sn;
    __bf16 (*Pw)[72] = Ps[wave];

    // swizzled 16B-unit offsets for fragment reads (involution of stage swizzle)
    const int sw0 = ((quad    ) ^ (m16 & 7)) * 8;
    const int sw1 = ((quad + 4) ^ (m16 & 7)) * 8;

    // staging coords: 512 threads x 16B cover one 64x64 bf16 tile per call
    const int srow = tid >> 3;
    const int ssu  = ((tid & 7) ^ (srow & 7)) * 8;

    #define STAGE(KT, BB)                                                       \
        {                                                                       \
            gl_lds16(base + (size_t)((KT) * 64 + srow) * 1536 + 512 + ssu,      \
                     (void*)(&Kb[BB][0][0] + tid * 8));                         \
            gl_lds16(vtb + (size_t)srow * Sn + (KT) * 64 + ssu,                 \
                     (void*)(&Vb[BB][0][0] + tid * 8));                         \
        }

    STAGE(0, 0);   // issue tile-0 staging first, Q loads overlap it

    bf16x8 q0, q1;
    {
        const __bf16* qa = base + (size_t)(qt * 64 + wave16 + m16) * 1536 + quad * 8;
        q0 = *(const bf16x8*)qa; q1 = *(const bf16x8*)(qa + 32);
    }

    float m[4], l[4];
    f32x4 acc[4];
    #pragma unroll
    for (int r = 0; r < 4; r++) {
        m[r] = -1e30f; l[r] = 0.f;
        acc[r] = (f32x4){0.f, 0.f, 0.f, 0.f};
    }

    __syncthreads();   // tile 0 staged (barrier drains vmcnt)

    for (int kt = 0; kt <= qtB; kt++) {
        const int buf = kt & 1;
        if (kt < qtB) STAGE(kt + 1, buf ^ 1);   // issue-only; drains at barrier

        if (isB || kt <= qtA) {
            // ---- S = Q K^T from LDS ----
            f32x4 sv[4];
            __builtin_amdgcn_s_setprio(1);
            #pragma unroll
            for (int j = 0; j < 4; j++) {
                const int rk = j * 16 + m16;
                bf16x8 kf0 = *(const bf16x8*)&Kb[buf][rk][sw0];
                bf16x8 kf1 = *(const bf16x8*)&Kb[buf][rk][sw1];
                f32x4 s = (f32x4){0.f, 0.f, 0.f, 0.f};
                s = __builtin_amdgcn_mfma_f32_16x16x32_bf16(q0, kf0, s, 0, 0, 0);
                s = __builtin_amdgcn_mfma_f32_16x16x32_bf16(q1, kf1, s, 0, 0, 0);
                sv[j] = s;
            }
            __builtin_amdgcn_s_setprio(0);

            // ---- V fragments from LDS (issued before softmax; latency hides) ----
            bf16x8 vf[4][2];
            #pragma unroll
            for (int jd = 0; jd < 4; jd++) {
                const int rv = jd * 16 + m16;
                vf[jd][0] = *(const bf16x8*)&Vb[buf][rv][sw0];
                vf[jd][1] = *(const bf16x8*)&Vb[buf][rv][sw1];
            }

            // ---- online softmax (per-wave LDS round-trip, in-order DS) ----
            bf16x8 p0, p1;
            softmax_update(sv, m, l, acc, kt == qt, wave16, quad, m16, Pw, p0, p1);

            // ---- O += P V ----
            __builtin_amdgcn_s_setprio(1);
            #pragma unroll
            for (int jd = 0; jd < 4; jd++) {
                acc[jd] = __builtin_amdgcn_mfma_f32_16x16x32_bf16(p0, vf[jd][0], acc[jd], 0, 0, 0);
                acc[jd] = __builtin_amdgcn_mfma_f32_16x16x32_bf16(p1, vf[jd][1], acc[jd], 0, 0, 0);
            }
            __builtin_amdgcn_s_setprio(0);
        }

        __syncthreads();   // all reads of buf done + next-tile staging drained
    }
    #undef STAGE

    // epilogue: O / l for own tile
    #pragma unroll
    for (int r = 0; r < 4; r++) l[r] = 1.0f / l[r];
    #pragma unroll
    for (int jd = 0; jd < 4; jd++)
        #pragma unroll
        for (int r = 0; r < 4; r++) {
            const int row = b * Sn + qt * 64 + wave16 + quad * 4 + r;
            o[(size_t)row * Dn + h * DKn + jd * 16 + m16] = (__bf16)(acc[jd][r] * l[r]);
        }
}

// ---------------------------------------------------------------------------
// Residual + LayerNorm, wave-per-row, barrier-free.
// Lane owns 8 consecutive cols (bf16x8 loads). 64-lane shfl_xor reductions.
// FINAL=0: xb = LN(t + xb) (bf16). FINAL=1: outf = LN(t + xb) (fp32).
// ---------------------------------------------------------------------------
template <int FINAL>
__global__ __launch_bounds__(256) void k_residual_ln(
    const __bf16* __restrict__ t, __bf16* __restrict__ xb,
    const float* __restrict__ g, const float* __restrict__ be,
    float* __restrict__ outf)
{
    const int row  = (blockIdx.x << 2) | (threadIdx.x >> 6);  // 4 rows/block
    const int lane = threadIdx.x & 63;
    const size_t base = (size_t)row * Dn + lane * 8;

    bf16x8 tv = *(const bf16x8*)&t[base];
    bf16x8 xv = *(const bf16x8*)&xb[base];
    float v[8];
    float s = 0.f;
    #pragma unroll
    for (int i = 0; i < 8; i++) {
        v[i] = (float)tv[i] + (float)xv[i];
        s += v[i];
    }
    #pragma unroll
    for (int off = 1; off < 64; off <<= 1) s += __shfl_xor(s, off);
    const float mean = s * (1.0f / Dn);

    float vs = 0.f;
    #pragma unroll
    for (int i = 0; i < 8; i++) {
        v[i] -= mean;
        vs += v[i] * v[i];
    }
    #pragma unroll
    for (int off = 1; off < 64; off <<= 1) vs += __shfl_xor(vs, off);
    const float inv = rsqrtf(vs * (1.0f / Dn) + 1e-5f);

    const f32x4 g0 = *(const f32x4*)&g[lane * 8];
    const f32x4 g1 = *(const f32x4*)&g[lane * 8 + 4];
    const f32x4 b0 = *(const f32x4*)&be[lane * 8];
    const f32x4 b1 = *(const f32x4*)&be[lane * 8 + 4];

    if (FINAL) {
        f32x4 o0, o1;
        #pragma unroll
        for (int i = 0; i < 4; i++) {
            o0[i] = v[i] * inv * g0[i] + b0[i];
            o1[i] = v[i + 4] * inv * g1[i] + b1[i];
        }
        *(f32x4*)&outf[base]     = o0;
        *(f32x4*)&outf[base + 4] = o1;
    } else {
        bf16x8 ov;
        #pragma unroll
        for (int i = 0; i < 4; i++) {
            ov[i]     = (__bf16)(v[i] * inv * g0[i] + b0[i]);
            ov[i + 4] = (__bf16)(v[i + 4] * inv * g1[i] + b1[i]);
        }
        *(bf16x8*)&xb[base] = ov;
    }
}

// ---------------------------------------------------------------------------
// launcher
// ---------------------------------------------------------------------------
extern "C" void kernel_launch(void* const* d_in, const int* in_sizes, int n_in,
                              void* d_out, int out_size, void* d_ws, size_t ws_size,
                              hipStream_t stream)
{
    const float* x_in   = (const float*)d_in[0];
    const float* qkv_w  = (const float*)d_in[1];
    const float* qkv_b  = (const float*)d_in[2];
    const float* out_w  = (const float*)d_in[3];
    const float* out_b  = (const float*)d_in[4];
    const float* ln1_g  = (const float*)d_in[5];
    const float* ln1_b  = (const float*)d_in[6];
    const float* mlp_w1 = (const float*)d_in[7];
    const float* mlp_b1 = (const float*)d_in[8];
    const float* mlp_w2 = (const float*)d_in[9];
    const float* mlp_b2 = (const float*)d_in[10];
    const float* ln2_g  = (const float*)d_in[11];
    const float* ln2_b  = (const float*)d_in[12];

    // workspace layout (~116 MB); residual lives in bf16 Xb only
    char* p = (char*)d_ws;
    __bf16* Xb    = (__bf16*)p; p += (size_t)Mn * Dn * 2;            //  8 MB
    __bf16* QKVb  = (__bf16*)p; p += (size_t)Mn * 3 * Dn * 2;        // 24 MB
    __bf16* AOb   = (__bf16*)p; p += (size_t)Mn * Dn * 2;            //  8 MB
    __bf16* Hb    = (__bf16*)p; p += (size_t)Mn * DFFn * 2;          // 32 MB
    __bf16* BUF3b = (__bf16*)p; p += (size_t)Mn * Dn * 2;            //  8 MB pre-LN temp
    __bf16* Wq    = (__bf16*)p; p += (size_t)Ln * 3 * Dn * Dn * 2;   //  9 MB
    __bf16* Wo    = (__bf16*)p; p += (size_t)Ln * Dn * Dn * 2;       //  3 MB
    __bf16* W1    = (__bf16*)p; p += (size_t)Ln * DFFn * Dn * 2;     // 12 MB
    __bf16* W2    = (__bf16*)p; p += (size_t)Ln * Dn * DFFn * 2;     // 12 MB
    __bf16* Vt    = Hb;   // 8 MB, aliased: Hb dead during attention

    k_cast_bf16<<<(Mn * Dn) / 256, 256, 0, stream>>>(x_in, Xb, Mn * Dn);

    // ALL weight transposes for all 6 layers in one launch (loop-invariant)
    k_trans_all<<<Ln * 3072, dim3(32, 8), 0, stream>>>(
        qkv_w, out_w, mlp_w1, mlp_w2, Wq, Wo, W1, W2);

    for (int l = 0; l < Ln; l++) {
        const __bf16* Wql = Wq + (size_t)l * 3 * Dn * Dn;
        const __bf16* Wol = Wo + (size_t)l * Dn * Dn;
        const __bf16* W1l = W1 + (size_t)l * DFFn * Dn;
        const __bf16* W2l = W2 + (size_t)l * Dn * DFFn;

        // QKV projection -> bf16 [M,1536] + fused Vt scatter
        k_gemm_mfma<0, 1, 4, 1><<<768, 256, 0, stream>>>(
            Xb, Wql, qkv_b + (size_t)l * 3 * Dn, QKVb, Vt, Mn, 3 * Dn, Dn, 12);
        // LDS-staged MFMA flash attention (8 waves, tile pair split) -> bf16
        k_attn_mfma<<<512, 512, 0, stream>>>(QKVb, Vt, AOb);
        // output projection -> bf16 BUF3b
        k_gemm_mfma<0, 1, 2, 0><<<512, 256, 0, stream>>>(
            AOb, Wol, out_b + (size_t)l * Dn, BUF3b, nullptr, Mn, Dn, Dn, 8);
        // x = LN(proj + x)   (bf16 in/out, fp32 math, wave-per-row)
        k_residual_ln<0><<<Mn / 4, 256, 0, stream>>>(BUF3b, Xb,
            ln1_g + (size_t)l * Dn, ln1_b + (size_t)l * Dn, nullptr);
        // MLP up + ReLU -> bf16 [M,2048]  (overwrites Vt alias; attn done)
        k_gemm_mfma<1, 1, 4, 0><<<1024, 256, 0, stream>>>(
            Xb, W1l, mlp_b1 + (size_t)l * DFFn, Hb, nullptr, Mn, DFFn, Dn, 16);
        // MLP down -> bf16 BUF3b
        k_gemm_mfma<0, 1, 2, 0><<<512, 256, 0, stream>>>(
            Hb, W2l, mlp_b2 + (size_t)l * Dn, BUF3b, nullptr, Mn, Dn, DFFn, 8);
        // x = LN(x + mlp); final layer writes fp32 straight to d_out
        if (l == Ln - 1)
            k_residual_ln<1><<<Mn / 4, 256, 0, stream>>>(BUF3b, Xb,
                ln2_g + (size_t)l * Dn, ln2_b + (size_t)l * Dn, (float*)d_out);
        else
            k_residual_ln<0><<<Mn / 4, 256, 0, stream>>>(BUF3b, Xb,
                ln2_g + (size_t)l * Dn, ln2_b + (size_t)l * Dn, nullptr);
    }
}

// Round 7
// 956.056 us; speedup vs baseline: 1.5477x; 1.0001x over previous
//
#include <hip/hip_runtime.h>
#include <math.h>

// Problem constants
#define Bn   8
#define Sn   1024
#define Dn   512
#define Hn   8
#define DKn  64
#define Ln   6
#define DFFn 2048
#define Mn   (Bn * Sn)   // 8192 rows

typedef __bf16 bf16x8 __attribute__((ext_vector_type(8)));
typedef __bf16 bf16x4 __attribute__((ext_vector_type(4)));
typedef __bf16 bf16x2 __attribute__((ext_vector_type(2)));
typedef float  f32x4  __attribute__((ext_vector_type(4)));

// async global->LDS, 16B per lane. LDS dest must be wave-uniform base + lane*16.
__device__ __forceinline__ void gl_lds16(const void* g, void* l) {
    __builtin_amdgcn_global_load_lds(
        (const __attribute__((address_space(1))) void*)g,
        (__attribute__((address_space(3))) void*)l, 16, 0, 0);
}

// ---------------------------------------------------------------------------
// fp32 -> bf16 cast (input)
// ---------------------------------------------------------------------------
__global__ __launch_bounds__(256) void k_cast_bf16(const float* __restrict__ in,
                                                   __bf16* __restrict__ out, int n) {
    int i = blockIdx.x * 256 + threadIdx.x;
    if (i < n) out[i] = (__bf16)in[i];
}

// ---------------------------------------------------------------------------
// ALL weight matrices of ALL 6 layers: W[K][N] fp32 -> Wt[N][K] bf16.
// One launch (weights are layer-loop invariant). 32x32 tiles, 32x8 threads.
// ---------------------------------------------------------------------------
__global__ __launch_bounds__(256) void k_trans_all(
    const float* __restrict__ qkv_w, const float* __restrict__ out_w,
    const float* __restrict__ w1, const float* __restrict__ w2,
    __bf16* __restrict__ Wq, __bf16* __restrict__ Wo,
    __bf16* __restrict__ W1o, __bf16* __restrict__ W2o)
{
    const int lay = blockIdx.x / 3072;
    const int t   = blockIdx.x % 3072;
    const float* src; __bf16* dst; int K, N, n0, k0;
    if (t < 768)       { src = qkv_w + (size_t)lay * Dn * 3 * Dn; dst = Wq  + (size_t)lay * 3 * Dn * Dn;
                         K = 512;  N = 1536; int u = t;        n0 = (u % 48) * 32; k0 = (u / 48) * 32; }
    else if (t < 1024) { src = out_w + (size_t)lay * Dn * Dn;     dst = Wo  + (size_t)lay * Dn * Dn;
                         K = 512;  N = 512;  int u = t - 768;  n0 = (u % 16) * 32; k0 = (u / 16) * 32; }
    else if (t < 2048) { src = w1 + (size_t)lay * Dn * DFFn;      dst = W1o + (size_t)lay * DFFn * Dn;
                         K = 512;  N = 2048; int u = t - 1024; n0 = (u % 64) * 32; k0 = (u / 64) * 32; }
    else               { src = w2 + (size_t)lay * DFFn * Dn;      dst = W2o + (size_t)lay * Dn * DFFn;
                         K = 2048; N = 512;  int u = t - 2048; n0 = (u % 16) * 32; k0 = (u / 16) * 32; }

    __shared__ float tt[32][33];
    const int tx = threadIdx.x, ty = threadIdx.y;
    #pragma unroll
    for (int r = 0; r < 4; r++)
        tt[ty + 8 * r][tx] = src[(size_t)(k0 + ty + 8 * r) * N + n0 + tx];
    __syncthreads();
    #pragma unroll
    for (int r = 0; r < 4; r++)
        dst[(size_t)(n0 + ty + 8 * r) * K + k0 + tx] = (__bf16)tt[tx][ty + 8 * r];
}

// ---------------------------------------------------------------------------
// MFMA GEMM: C[M,N] = act(A[M,K]bf16 @ Bt[N,K]bf16^T + bias[N]fp32)
// Block: 256 thr = 4 waves (2x2). Tile: 128 x (JT*32). K-step: BK (64 or 128).
// (a) 1D grid + bijective chunked XCD swizzle.
// (b) XOR LDS swizzle both-sides (rule #21): unit u' = u ^ (row & (UR-1)).
// v7: BK templated — JT=2 kernels (outproj/MLP-down, grid-limited to 2
// blocks/CU) use BK=128 to halve barrier-drain count; LDS 48KB, no
// occupancy loss (grid-limited). JT=4 kernels stay BK=64 (32KB LDS).
// VW=1 (QKV only): cols >=1024 are V -> also scatter into Vt[b*8+h][d][s].
// ---------------------------------------------------------------------------
template <int RELU, int OUTBF, int JT, int VW, int BK>
__global__ __launch_bounds__(256) void k_gemm_mfma(
    const __bf16* __restrict__ A, const __bf16* __restrict__ Bt,
    const float* __restrict__ bias, void* __restrict__ Cout,
    __bf16* __restrict__ Vt, int M, int N, int K, int NBX)
{
    constexpr int BN = JT * 32;   // 128 or 64
    constexpr int UR = BK / 8;    // 16B units per LDS row
    constexpr int HC = BK / 32;   // K=32 chunks per K-step
    __shared__ __bf16 As[128][BK];
    __shared__ __bf16 Bs[BN][BK];
    const int tid  = threadIdx.x;
    const int lane = tid & 63;
    const int wave = tid >> 6;
    const int wy   = wave >> 1, wx = wave & 1;
    const int m16  = lane & 15, quad = lane >> 4;

    // chunked XCD swizzle (all launches have gridDim.x % 8 == 0)
    const int cpx = gridDim.x >> 3;
    const int id  = (blockIdx.x & 7) * cpx + (blockIdx.x >> 3);
    const int bm  = (id / NBX) * 128;
    const int bn  = (id % NBX) * BN;

    f32x4 acc[4][JT];
    #pragma unroll
    for (int i = 0; i < 4; i++)
        #pragma unroll
        for (int j = 0; j < JT; j++)
            acc[i][j] = (f32x4){0.f, 0.f, 0.f, 0.f};

    const __bf16* Ap = A  + (size_t)bm * K;
    const __bf16* Bp = Bt + (size_t)bn * K;

    // swizzled 16B-unit byte offsets for fragment reads (involution of stage)
    int sw[HC];
    #pragma unroll
    for (int hc = 0; hc < HC; hc++)
        sw[hc] = ((quad + 4 * hc) ^ (m16 & (UR - 1))) * 8;

    for (int k0 = 0; k0 < K; k0 += BK) {
        __syncthreads();
        #pragma unroll
        for (int c = 0; c < UR / 2; c++) {        // A: 128 x UR units
            int lin = tid + c * 256;
            int row = lin / UR, uu = lin % UR;
            int su  = (uu ^ (row & (UR - 1))) << 3;
            gl_lds16(Ap + (size_t)row * K + k0 + su, (void*)(&As[0][0] + lin * 8));
        }
        #pragma unroll
        for (int c = 0; c < (JT * UR) / 8; c++) { // B: BN x UR units
            int lin = tid + c * 256;
            int row = lin / UR, uu = lin % UR;
            int su  = (uu ^ (row & (UR - 1))) << 3;
            gl_lds16(Bp + (size_t)row * K + k0 + su, (void*)(&Bs[0][0] + lin * 8));
        }
        __syncthreads();

        bf16x8 af[4][HC], bfr[JT][HC];
        #pragma unroll
        for (int i = 0; i < 4; i++)
            #pragma unroll
            for (int hc = 0; hc < HC; hc++)
                af[i][hc] = *(const bf16x8*)&As[wy * 64 + i * 16 + m16][sw[hc]];
        #pragma unroll
        for (int j = 0; j < JT; j++)
            #pragma unroll
            for (int hc = 0; hc < HC; hc++)
                bfr[j][hc] = *(const bf16x8*)&Bs[wx * JT * 16 + j * 16 + m16][sw[hc]];
        #pragma unroll
        for (int hc = 0; hc < HC; hc++)
            #pragma unroll
            for (int i = 0; i < 4; i++)
                #pragma unroll
                for (int j = 0; j < JT; j++)
                    acc[i][j] = __builtin_amdgcn_mfma_f32_16x16x32_bf16(
                        af[i][hc], bfr[j][hc], acc[i][j], 0, 0, 0);
    }

    float*  Cf = (float*)Cout;
    __bf16* Cb = (__bf16*)Cout;
    #pragma unroll
    for (int i = 0; i < 4; i++) {
        const int row0 = bm + wy * 64 + i * 16 + quad * 4;
        #pragma unroll
        for (int j = 0; j < JT; j++) {
            const int col = bn + wx * JT * 16 + j * 16 + m16;
            const float bv = bias[col];
            float vv[4];
            #pragma unroll
            for (int r = 0; r < 4; r++) {
                float v = acc[i][j][r] + bv;
                if (RELU) v = fmaxf(v, 0.f);
                vv[r] = v;
                if (OUTBF) Cb[(size_t)(row0 + r) * N + col] = (__bf16)v;
                else       Cf[(size_t)(row0 + r) * N + col] = v;
            }
            if (VW && col >= 1024) {            // V slice -> Vt[b*8+h][d][s]
                const int cc = col - 1024;
                const int bb = row0 >> 10, ss = row0 & 1023;
                bf16x4 pv;
                #pragma unroll
                for (int r = 0; r < 4; r++) pv[r] = (__bf16)vv[r];
                *(bf16x4*)&Vt[((size_t)(bb * Hn + (cc >> 6)) * DKn + (cc & 63)) * Sn + ss] = pv;
            }
        }
    }
}

// ---------------------------------------------------------------------------
// MFMA flash attention (causal), LDS-staged K/V, ONE q-tile per block.
// qkv: [M][1536] bf16; Vt: [b*8+h][64][1024] bf16.
// v7: block = (qt, b, h), 256 threads = 4 waves, wave w owns q-rows w*16..+15.
// Eliminates the pair-split's idle A-waves (68% -> ~100% wave utilization);
// grid 1024, LDS 41.2KB -> 3 blocks/CU (12 waves/CU, was 2x8=16 with 32% idle).
// qt-major id order spreads heavy (qt=15) and light (qt=0) blocks across CUs;
// id%8==h keeps all blocks of one (b,h) on one XCD's L2.
// K/V staged once per block (double-buffered LDS), XOR swizzle both sides.
// T13 defer-max.
// ---------------------------------------------------------------------------
__device__ __forceinline__ void softmax_update(
    f32x4 sv[4], float m[4], float l[4], f32x4 acc[4],
    bool diag, int wave16, int quad, int m16,
    __bf16 (*Pw)[72], bf16x8& pf0, bf16x8& pf1)
{
    #pragma unroll
    for (int j = 0; j < 4; j++)
        #pragma unroll
        for (int r = 0; r < 4; r++) {
            float v = sv[j][r] * 0.125f;    // 1/sqrt(64)
            if (diag && (j * 16 + m16) > (wave16 + quad * 4 + r)) v = -1e30f;
            sv[j][r] = v;
        }

    float pm[4];
    #pragma unroll
    for (int r = 0; r < 4; r++)
        pm[r] = fmaxf(fmaxf(sv[0][r], sv[1][r]), fmaxf(sv[2][r], sv[3][r]));
    #pragma unroll
    for (int off = 1; off < 16; off <<= 1)
        #pragma unroll
        for (int r = 0; r < 4; r++)
            pm[r] = fmaxf(pm[r], __shfl_xor(pm[r], off, 16));

    // T13 defer-max: only rescale when some row grew past m + 8
    bool grew = false;
    #pragma unroll
    for (int r = 0; r < 4; r++) grew = grew || (pm[r] > m[r] + 8.f);
    if (__any((int)grew)) {
        #pragma unroll
        for (int r = 0; r < 4; r++) {
            float mn = fmaxf(m[r], pm[r]);
            float al = __expf(m[r] - mn);
            m[r] = mn;
            l[r] *= al;
            #pragma unroll
            for (int j = 0; j < 4; j++) acc[j][r] *= al;
        }
    }

    float rs[4] = {0.f, 0.f, 0.f, 0.f};
    #pragma unroll
    for (int j = 0; j < 4; j++)
        #pragma unroll
        for (int r = 0; r < 4; r++) {
            float p = __expf(sv[j][r] - m[r]);   // bounded by e^8 when deferred
            rs[r] += p;
            Pw[quad * 4 + r][j * 16 + m16] = (__bf16)p;
        }
    #pragma unroll
    for (int off = 1; off < 16; off <<= 1)
        #pragma unroll
        for (int r = 0; r < 4; r++)
            rs[r] += __shfl_xor(rs[r], off, 16);
    #pragma unroll
    for (int r = 0; r < 4; r++) l[r] += rs[r];

    pf0 = *(const bf16x8*)&Pw[m16][quad * 8];
    pf1 = *(const bf16x8*)&Pw[m16][32 + quad * 8];
}

__global__ __launch_bounds__(256, 3) void k_attn_mfma(
    const __bf16* __restrict__ qkv, const __bf16* __restrict__ Vt,
    __bf16* __restrict__ o)
{
    const int id = blockIdx.x;
    const int h  = id & 7;             // id%8 = h -> blocks of one h share an XCD
    const int b  = (id >> 3) & 7;
    const int qt = id >> 6;            // 0..15, qt-major for CU load balance
    const int tid  = threadIdx.x;
    const int lane = tid & 63, wave = tid >> 6;   // 0..3
    const int m16  = lane & 15, quad = lane >> 4;
    const int wave16 = wave * 16;

    __shared__ __bf16 Kb[2][64][64];     // double-buffered K tile (swizzled)
    __shared__ __bf16 Vb[2][64][64];     // double-buffered V tile (swizzled)
    __shared__ __bf16 Ps[4][16][72];     // per-wave P scratch

    const __bf16* base = qkv + (size_t)b * Sn * 1536 + h * DKn;   // Q +0, K +512
    const __bf16* vtb  = Vt + (size_t)(b * Hn + h) * DKn * Sn;
    __bf16 (*Pw)[72] = Ps[wave];

    // swizzled 16B-unit offsets for fragment reads (involution of stage swizzle)
    const int sw0 = ((quad    ) ^ (m16 & 7)) * 8;
    const int sw1 = ((quad + 4) ^ (m16 & 7)) * 8;

    // staging: 256 threads x 2 chunks x 16B cover one 64x64 bf16 tile
    #define STAGE(KT, BB)                                                       \
        {                                                                       \
            _Pragma("unroll")                                                   \
            for (int c = 0; c < 2; c++) {                                       \
                const int lin = tid + c * 256;                                  \
                const int row = lin >> 3, uu = lin & 7;                         \
                const int su  = (uu ^ (row & 7)) * 8;                           \
                gl_lds16(base + (size_t)((KT) * 64 + row) * 1536 + 512 + su,    \
                         (void*)(&Kb[BB][0][0] + lin * 8));                     \
                gl_lds16(vtb + (size_t)row * Sn + (KT) * 64 + su,               \
                         (void*)(&Vb[BB][0][0] + lin * 8));                     \
            }                                                                   \
        }

    STAGE(0, 0);   // issue tile-0 staging first, Q loads overlap it

    bf16x8 q0, q1;
    {
        const __bf16* qa = base + (size_t)(qt * 64 + wave16 + m16) * 1536 + quad * 8;
        q0 = *(const bf16x8*)qa; q1 = *(const bf16x8*)(qa + 32);
    }

    float m[4], l[4];
    f32x4 acc[4];
    #pragma unroll
    for (int r = 0; r < 4; r++) {
        m[r] = -1e30f; l[r] = 0.f;
        acc[r] = (f32x4){0.f, 0.f, 0.f, 0.f};
    }

    __syncthreads();   // tile 0 staged (barrier drains vmcnt)

    for (int kt = 0; kt <= qt; kt++) {
        const int buf = kt & 1;
        if (kt < qt) STAGE(kt + 1, buf ^ 1);   // issue-only; drains at barrier

        // ---- S = Q K^T from LDS ----
        f32x4 sv[4];
        __builtin_amdgcn_s_setprio(1);
        #pragma unroll
        for (int j = 0; j < 4; j++) {
            const int rk = j * 16 + m16;
            bf16x8 kf0 = *(const bf16x8*)&Kb[buf][rk][sw0];
            bf16x8 kf1 = *(const bf16x8*)&Kb[buf][rk][sw1];
            f32x4 s = (f32x4){0.f, 0.f, 0.f, 0.f};
            s = __builtin_amdgcn_mfma_f32_16x16x32_bf16(q0, kf0, s, 0, 0, 0);
            s = __builtin_amdgcn_mfma_f32_16x16x32_bf16(q1, kf1, s, 0, 0, 0);
            sv[j] = s;
        }
        __builtin_amdgcn_s_setprio(0);

        // ---- V fragments from LDS (issued before softmax; latency hides) ----
        bf16x8 vf[4][2];
        #pragma unroll
        for (int jd = 0; jd < 4; jd++) {
            const int rv = jd * 16 + m16;
            vf[jd][0] = *(const bf16x8*)&Vb[buf][rv][sw0];
            vf[jd][1] = *(const bf16x8*)&Vb[buf][rv][sw1];
        }

        // ---- online softmax (per-wave LDS round-trip, in-order DS) ----
        bf16x8 p0, p1;
        softmax_update(sv, m, l, acc, kt == qt, wave16, quad, m16, Pw, p0, p1);

        // ---- O += P V ----
        __builtin_amdgcn_s_setprio(1);
        #pragma unroll
        for (int jd = 0; jd < 4; jd++) {
            acc[jd] = __builtin_amdgcn_mfma_f32_16x16x32_bf16(p0, vf[jd][0], acc[jd], 0, 0, 0);
            acc[jd] = __builtin_amdgcn_mfma_f32_16x16x32_bf16(p1, vf[jd][1], acc[jd], 0, 0, 0);
        }
        __builtin_amdgcn_s_setprio(0);

        __syncthreads();   // all reads of buf done + next-tile staging drained
    }
    #undef STAGE

    // epilogue: O / l
    #pragma unroll
    for (int r = 0; r < 4; r++) l[r] = 1.0f / l[r];
    #pragma unroll
    for (int jd = 0; jd < 4; jd++)
        #pragma unroll
        for (int r = 0; r < 4; r++) {
            const int row = b * Sn + qt * 64 + wave16 + quad * 4 + r;
            o[(size_t)row * Dn + h * DKn + jd * 16 + m16] = (__bf16)(acc[jd][r] * l[r]);
        }
}

// ---------------------------------------------------------------------------
// Residual + LayerNorm, wave-per-row, barrier-free.
// Lane owns 8 consecutive cols (bf16x8 loads). 64-lane shfl_xor reductions.
// FINAL=0: xb = LN(t + xb) (bf16). FINAL=1: outf = LN(t + xb) (fp32).
// ---------------------------------------------------------------------------
template <int FINAL>
__global__ __launch_bounds__(256) void k_residual_ln(
    const __bf16* __restrict__ t, __bf16* __restrict__ xb,
    const float* __restrict__ g, const float* __restrict__ be,
    float* __restrict__ outf)
{
    const int row  = (blockIdx.x << 2) | (threadIdx.x >> 6);  // 4 rows/block
    const int lane = threadIdx.x & 63;
    const size_t base = (size_t)row * Dn + lane * 8;

    bf16x8 tv = *(const bf16x8*)&t[base];
    bf16x8 xv = *(const bf16x8*)&xb[base];
    float v[8];
    float s = 0.f;
    #pragma unroll
    for (int i = 0; i < 8; i++) {
        v[i] = (float)tv[i] + (float)xv[i];
        s += v[i];
    }
    #pragma unroll
    for (int off = 1; off < 64; off <<= 1) s += __shfl_xor(s, off);
    const float mean = s * (1.0f / Dn);

    float vs = 0.f;
    #pragma unroll
    for (int i = 0; i < 8; i++) {
        v[i] -= mean;
        vs += v[i] * v[i];
    }
    #pragma unroll
    for (int off = 1; off < 64; off <<= 1) vs += __shfl_xor(vs, off);
    const float inv = rsqrtf(vs * (1.0f / Dn) + 1e-5f);

    const f32x4 g0 = *(const f32x4*)&g[lane * 8];
    const f32x4 g1 = *(const f32x4*)&g[lane * 8 + 4];
    const f32x4 b0 = *(const f32x4*)&be[lane * 8];
    const f32x4 b1 = *(const f32x4*)&be[lane * 8 + 4];

    if (FINAL) {
        f32x4 o0, o1;
        #pragma unroll
        for (int i = 0; i < 4; i++) {
            o0[i] = v[i] * inv * g0[i] + b0[i];
            o1[i] = v[i + 4] * inv * g1[i] + b1[i];
        }
        *(f32x4*)&outf[base]     = o0;
        *(f32x4*)&outf[base + 4] = o1;
    } else {
        bf16x8 ov;
        #pragma unroll
        for (int i = 0; i < 4; i++) {
            ov[i]     = (__bf16)(v[i] * inv * g0[i] + b0[i]);
            ov[i + 4] = (__bf16)(v[i + 4] * inv * g1[i] + b1[i]);
        }
        *(bf16x8*)&xb[base] = ov;
    }
}

// ---------------------------------------------------------------------------
// launcher
// ---------------------------------------------------------------------------
extern "C" void kernel_launch(void* const* d_in, const int* in_sizes, int n_in,
                              void* d_out, int out_size, void* d_ws, size_t ws_size,
                              hipStream_t stream)
{
    const float* x_in   = (const float*)d_in[0];
    const float* qkv_w  = (const float*)d_in[1];
    const float* qkv_b  = (const float*)d_in[2];
    const float* out_w  = (const float*)d_in[3];
    const float* out_b  = (const float*)d_in[4];
    const float* ln1_g  = (const float*)d_in[5];
    const float* ln1_b  = (const float*)d_in[6];
    const float* mlp_w1 = (const float*)d_in[7];
    const float* mlp_b1 = (const float*)d_in[8];
    const float* mlp_w2 = (const float*)d_in[9];
    const float* mlp_b2 = (const float*)d_in[10];
    const float* ln2_g  = (const float*)d_in[11];
    const float* ln2_b  = (const float*)d_in[12];

    // workspace layout (~116 MB); residual lives in bf16 Xb only
    char* p = (char*)d_ws;
    __bf16* Xb    = (__bf16*)p; p += (size_t)Mn * Dn * 2;            //  8 MB
    __bf16* QKVb  = (__bf16*)p; p += (size_t)Mn * 3 * Dn * 2;        // 24 MB
    __bf16* AOb   = (__bf16*)p; p += (size_t)Mn * Dn * 2;            //  8 MB
    __bf16* Hb    = (__bf16*)p; p += (size_t)Mn * DFFn * 2;          // 32 MB
    __bf16* BUF3b = (__bf16*)p; p += (size_t)Mn * Dn * 2;            //  8 MB pre-LN temp
    __bf16* Wq    = (__bf16*)p; p += (size_t)Ln * 3 * Dn * Dn * 2;   //  9 MB
    __bf16* Wo    = (__bf16*)p; p += (size_t)Ln * Dn * Dn * 2;       //  3 MB
    __bf16* W1    = (__bf16*)p; p += (size_t)Ln * DFFn * Dn * 2;     // 12 MB
    __bf16* W2    = (__bf16*)p; p += (size_t)Ln * Dn * DFFn * 2;     // 12 MB
    __bf16* Vt    = Hb;   // 8 MB, aliased: Hb dead during attention

    k_cast_bf16<<<(Mn * Dn) / 256, 256, 0, stream>>>(x_in, Xb, Mn * Dn);

    // ALL weight transposes for all 6 layers in one launch (loop-invariant)
    k_trans_all<<<Ln * 3072, dim3(32, 8), 0, stream>>>(
        qkv_w, out_w, mlp_w1, mlp_w2, Wq, Wo, W1, W2);

    for (int l = 0; l < Ln; l++) {
        const __bf16* Wql = Wq + (size_t)l * 3 * Dn * Dn;
        const __bf16* Wol = Wo + (size_t)l * Dn * Dn;
        const __bf16* W1l = W1 + (size_t)l * DFFn * Dn;
        const __bf16* W2l = W2 + (size_t)l * Dn * DFFn;

        // QKV projection -> bf16 [M,1536] + fused Vt scatter
        k_gemm_mfma<0, 1, 4, 1, 64><<<768, 256, 0, stream>>>(
            Xb, Wql, qkv_b + (size_t)l * 3 * Dn, QKVb, Vt, Mn, 3 * Dn, Dn, 12);
        // MFMA flash attention, one q-tile per block -> bf16
        k_attn_mfma<<<1024, 256, 0, stream>>>(QKVb, Vt, AOb);
        // output projection -> bf16 BUF3b  (BK=128: halved barrier drains)
        k_gemm_mfma<0, 1, 2, 0, 128><<<512, 256, 0, stream>>>(
            AOb, Wol, out_b + (size_t)l * Dn, BUF3b, nullptr, Mn, Dn, Dn, 8);
        // x = LN(proj + x)   (bf16 in/out, fp32 math, wave-per-row)
        k_residual_ln<0><<<Mn / 4, 256, 0, stream>>>(BUF3b, Xb,
            ln1_g + (size_t)l * Dn, ln1_b + (size_t)l * Dn, nullptr);
        // MLP up + ReLU -> bf16 [M,2048]  (overwrites Vt alias; attn done)
        k_gemm_mfma<1, 1, 4, 0, 64><<<1024, 256, 0, stream>>>(
            Xb, W1l, mlp_b1 + (size_t)l * DFFn, Hb, nullptr, Mn, DFFn, Dn, 16);
        // MLP down -> bf16 BUF3b  (BK=128)
        k_gemm_mfma<0, 1, 2, 0, 128><<<512, 256, 0, stream>>>(
            Hb, W2l, mlp_b2 + (size_t)l * Dn, BUF3b, nullptr, Mn, Dn, DFFn, 8);
        // x = LN(x + mlp); final layer writes fp32 straight to d_out
        if (l == Ln - 1)
            k_residual_ln<1><<<Mn / 4, 256, 0, stream>>>(BUF3b, Xb,
                ln2_g + (size_t)l * Dn, ln2_b + (size_t)l * Dn, (float*)d_out);
        else
            k_residual_ln<0><<<Mn / 4, 256, 0, stream>>>(BUF3b, Xb,
                ln2_g + (size_t)l * Dn, ln2_b + (size_t)l * Dn, nullptr);
    }
}

// Round 8
// 951.601 us; speedup vs baseline: 1.5550x; 1.0047x over previous
//
#include <hip/hip_runtime.h>
#include <math.h>

// Problem constants
#define Bn   8
#define Sn   1024
#define Dn   512
#define Hn   8
#define DKn  64
#define Ln   6
#define DFFn 2048
#define Mn   (Bn * Sn)   // 8192 rows

typedef __bf16 bf16x8 __attribute__((ext_vector_type(8)));
typedef __bf16 bf16x4 __attribute__((ext_vector_type(4)));
typedef __bf16 bf16x2 __attribute__((ext_vector_type(2)));
typedef float  f32x4  __attribute__((ext_vector_type(4)));

// async global->LDS, 16B per lane. LDS dest must be wave-uniform base + lane*16.
__device__ __forceinline__ void gl_lds16(const void* g, void* l) {
    __builtin_amdgcn_global_load_lds(
        (const __attribute__((address_space(1))) void*)g,
        (__attribute__((address_space(3))) void*)l, 16, 0, 0);
}

// ---------------------------------------------------------------------------
// fp32 -> bf16 cast (input)
// ---------------------------------------------------------------------------
__global__ __launch_bounds__(256) void k_cast_bf16(const float* __restrict__ in,
                                                   __bf16* __restrict__ out, int n) {
    int i = blockIdx.x * 256 + threadIdx.x;
    if (i < n) out[i] = (__bf16)in[i];
}

// ---------------------------------------------------------------------------
// ALL weight matrices of ALL 6 layers: W[K][N] fp32 -> Wt[N][K] bf16.
// One launch (weights are layer-loop invariant). 32x32 tiles, 32x8 threads.
// ---------------------------------------------------------------------------
__global__ __launch_bounds__(256) void k_trans_all(
    const float* __restrict__ qkv_w, const float* __restrict__ out_w,
    const float* __restrict__ w1, const float* __restrict__ w2,
    __bf16* __restrict__ Wq, __bf16* __restrict__ Wo,
    __bf16* __restrict__ W1o, __bf16* __restrict__ W2o)
{
    const int lay = blockIdx.x / 3072;
    const int t   = blockIdx.x % 3072;
    const float* src; __bf16* dst; int K, N, n0, k0;
    if (t < 768)       { src = qkv_w + (size_t)lay * Dn * 3 * Dn; dst = Wq  + (size_t)lay * 3 * Dn * Dn;
                         K = 512;  N = 1536; int u = t;        n0 = (u % 48) * 32; k0 = (u / 48) * 32; }
    else if (t < 1024) { src = out_w + (size_t)lay * Dn * Dn;     dst = Wo  + (size_t)lay * Dn * Dn;
                         K = 512;  N = 512;  int u = t - 768;  n0 = (u % 16) * 32; k0 = (u / 16) * 32; }
    else if (t < 2048) { src = w1 + (size_t)lay * Dn * DFFn;      dst = W1o + (size_t)lay * DFFn * Dn;
                         K = 512;  N = 2048; int u = t - 1024; n0 = (u % 64) * 32; k0 = (u / 64) * 32; }
    else               { src = w2 + (size_t)lay * DFFn * Dn;      dst = W2o + (size_t)lay * Dn * DFFn;
                         K = 2048; N = 512;  int u = t - 2048; n0 = (u % 16) * 32; k0 = (u / 16) * 32; }

    __shared__ float tt[32][33];
    const int tx = threadIdx.x, ty = threadIdx.y;
    #pragma unroll
    for (int r = 0; r < 4; r++)
        tt[ty + 8 * r][tx] = src[(size_t)(k0 + ty + 8 * r) * N + n0 + tx];
    __syncthreads();
    #pragma unroll
    for (int r = 0; r < 4; r++)
        dst[(size_t)(n0 + ty + 8 * r) * K + k0 + tx] = (__bf16)tt[tx][ty + 8 * r];
}

// ---------------------------------------------------------------------------
// MFMA GEMM: C[M,N] = act(A[M,K]bf16 @ Bt[N,K]bf16^T + bias[N]fp32)
// Block: 256 thr = 4 waves (2x2). Tile: 128 x (JT*32). K-step: BK (64 or 128).
// (a) 1D grid + bijective chunked XCD swizzle.
// (b) XOR LDS swizzle both-sides (rule #21): unit u' = u ^ (row & (UR-1)).
// BK=128 on JT=2 kernels (outproj/MLP-down): halved barrier-drain count
// (R7 evidence: ~-48us total vs BK=64).
// VW=1 (QKV only): cols >=1024 are V -> also scatter into Vt[b*8+h][d][s].
// ---------------------------------------------------------------------------
template <int RELU, int OUTBF, int JT, int VW, int BK>
__global__ __launch_bounds__(256) void k_gemm_mfma(
    const __bf16* __restrict__ A, const __bf16* __restrict__ Bt,
    const float* __restrict__ bias, void* __restrict__ Cout,
    __bf16* __restrict__ Vt, int M, int N, int K, int NBX)
{
    constexpr int BN = JT * 32;   // 128 or 64
    constexpr int UR = BK / 8;    // 16B units per LDS row
    constexpr int HC = BK / 32;   // K=32 chunks per K-step
    __shared__ __bf16 As[128][BK];
    __shared__ __bf16 Bs[BN][BK];
    const int tid  = threadIdx.x;
    const int lane = tid & 63;
    const int wave = tid >> 6;
    const int wy   = wave >> 1, wx = wave & 1;
    const int m16  = lane & 15, quad = lane >> 4;

    // chunked XCD swizzle (all launches have gridDim.x % 8 == 0)
    const int cpx = gridDim.x >> 3;
    const int id  = (blockIdx.x & 7) * cpx + (blockIdx.x >> 3);
    const int bm  = (id / NBX) * 128;
    const int bn  = (id % NBX) * BN;

    f32x4 acc[4][JT];
    #pragma unroll
    for (int i = 0; i < 4; i++)
        #pragma unroll
        for (int j = 0; j < JT; j++)
            acc[i][j] = (f32x4){0.f, 0.f, 0.f, 0.f};

    const __bf16* Ap = A  + (size_t)bm * K;
    const __bf16* Bp = Bt + (size_t)bn * K;

    // swizzled 16B-unit byte offsets for fragment reads (involution of stage)
    int sw[HC];
    #pragma unroll
    for (int hc = 0; hc < HC; hc++)
        sw[hc] = ((quad + 4 * hc) ^ (m16 & (UR - 1))) * 8;

    for (int k0 = 0; k0 < K; k0 += BK) {
        __syncthreads();
        #pragma unroll
        for (int c = 0; c < UR / 2; c++) {        // A: 128 x UR units
            int lin = tid + c * 256;
            int row = lin / UR, uu = lin % UR;
            int su  = (uu ^ (row & (UR - 1))) << 3;
            gl_lds16(Ap + (size_t)row * K + k0 + su, (void*)(&As[0][0] + lin * 8));
        }
        #pragma unroll
        for (int c = 0; c < (JT * UR) / 8; c++) { // B: BN x UR units
            int lin = tid + c * 256;
            int row = lin / UR, uu = lin % UR;
            int su  = (uu ^ (row & (UR - 1))) << 3;
            gl_lds16(Bp + (size_t)row * K + k0 + su, (void*)(&Bs[0][0] + lin * 8));
        }
        __syncthreads();

        bf16x8 af[4][HC], bfr[JT][HC];
        #pragma unroll
        for (int i = 0; i < 4; i++)
            #pragma unroll
            for (int hc = 0; hc < HC; hc++)
                af[i][hc] = *(const bf16x8*)&As[wy * 64 + i * 16 + m16][sw[hc]];
        #pragma unroll
        for (int j = 0; j < JT; j++)
            #pragma unroll
            for (int hc = 0; hc < HC; hc++)
                bfr[j][hc] = *(const bf16x8*)&Bs[wx * JT * 16 + j * 16 + m16][sw[hc]];
        #pragma unroll
        for (int hc = 0; hc < HC; hc++)
            #pragma unroll
            for (int i = 0; i < 4; i++)
                #pragma unroll
                for (int j = 0; j < JT; j++)
                    acc[i][j] = __builtin_amdgcn_mfma_f32_16x16x32_bf16(
                        af[i][hc], bfr[j][hc], acc[i][j], 0, 0, 0);
    }

    float*  Cf = (float*)Cout;
    __bf16* Cb = (__bf16*)Cout;
    #pragma unroll
    for (int i = 0; i < 4; i++) {
        const int row0 = bm + wy * 64 + i * 16 + quad * 4;
        #pragma unroll
        for (int j = 0; j < JT; j++) {
            const int col = bn + wx * JT * 16 + j * 16 + m16;
            const float bv = bias[col];
            float vv[4];
            #pragma unroll
            for (int r = 0; r < 4; r++) {
                float v = acc[i][j][r] + bv;
                if (RELU) v = fmaxf(v, 0.f);
                vv[r] = v;
                if (OUTBF) Cb[(size_t)(row0 + r) * N + col] = (__bf16)v;
                else       Cf[(size_t)(row0 + r) * N + col] = v;
            }
            if (VW && col >= 1024) {            // V slice -> Vt[b*8+h][d][s]
                const int cc = col - 1024;
                const int bb = row0 >> 10, ss = row0 & 1023;
                bf16x4 pv;
                #pragma unroll
                for (int r = 0; r < 4; r++) pv[r] = (__bf16)vv[r];
                *(bf16x4*)&Vt[((size_t)(bb * Hn + (cc >> 6)) * DKn + (cc & 63)) * Sn + ss] = pv;
            }
        }
    }
}

// ---------------------------------------------------------------------------
// MFMA flash attention (causal), LDS-staged K/V, wave-split tile pair.
// Block = (pair pr, h, b), 512 threads = 8 waves:
//   waves 0-3 own q-tile qtA=pr (16 rows each), waves 4-7 own qtB=15-pr.
// v8: T4 counted vmcnt — per thread each STAGE issues exactly 2 VMEM ops
// (1 K + 1 V gl_lds16). Loop: STAGE(kt+1); s_waitcnt vmcnt(2); s_barrier;
// compute(kt); lgkmcnt(0); s_barrier. Current tile's loads (issued last
// step) are complete at vmcnt(2) while next-tile loads stay IN FLIGHT
// across the barrier (never drain to 0 mid-loop — m201/AITER pattern).
// Last iter uses vmcnt(0) (its own loads are the outstanding ones).
// CU-pairing: u=id>>6 -> pr = u<4 ? u : 11-u, so co-resident block pairs
// (n, n+256) have step counts (16-p)+(9+p) = 25 constant.
// K/V staged once per block (shared by 8 waves); XOR swizzle both sides;
// id%8==h keeps one h's blocks on one XCD L2. T13 defer-max.
// ---------------------------------------------------------------------------
__device__ __forceinline__ void softmax_update(
    f32x4 sv[4], float m[4], float l[4], f32x4 acc[4],
    bool diag, int wave16, int quad, int m16,
    __bf16 (*Pw)[72], bf16x8& pf0, bf16x8& pf1)
{
    #pragma unroll
    for (int j = 0; j < 4; j++)
        #pragma unroll
        for (int r = 0; r < 4; r++) {
            float v = sv[j][r] * 0.125f;    // 1/sqrt(64)
            if (diag && (j * 16 + m16) > (wave16 + quad * 4 + r)) v = -1e30f;
            sv[j][r] = v;
        }

    float pm[4];
    #pragma unroll
    for (int r = 0; r < 4; r++)
        pm[r] = fmaxf(fmaxf(sv[0][r], sv[1][r]), fmaxf(sv[2][r], sv[3][r]));
    #pragma unroll
    for (int off = 1; off < 16; off <<= 1)
        #pragma unroll
        for (int r = 0; r < 4; r++)
            pm[r] = fmaxf(pm[r], __shfl_xor(pm[r], off, 16));

    // T13 defer-max: only rescale when some row grew past m + 8
    bool grew = false;
    #pragma unroll
    for (int r = 0; r < 4; r++) grew = grew || (pm[r] > m[r] + 8.f);
    if (__any((int)grew)) {
        #pragma unroll
        for (int r = 0; r < 4; r++) {
            float mn = fmaxf(m[r], pm[r]);
            float al = __expf(m[r] - mn);
            m[r] = mn;
            l[r] *= al;
            #pragma unroll
            for (int j = 0; j < 4; j++) acc[j][r] *= al;
        }
    }

    float rs[4] = {0.f, 0.f, 0.f, 0.f};
    #pragma unroll
    for (int j = 0; j < 4; j++)
        #pragma unroll
        for (int r = 0; r < 4; r++) {
            float p = __expf(sv[j][r] - m[r]);   // bounded by e^8 when deferred
            rs[r] += p;
            Pw[quad * 4 + r][j * 16 + m16] = (__bf16)p;
        }
    #pragma unroll
    for (int off = 1; off < 16; off <<= 1)
        #pragma unroll
        for (int r = 0; r < 4; r++)
            rs[r] += __shfl_xor(rs[r], off, 16);
    #pragma unroll
    for (int r = 0; r < 4; r++) l[r] += rs[r];

    pf0 = *(const bf16x8*)&Pw[m16][quad * 8];
    pf1 = *(const bf16x8*)&Pw[m16][32 + quad * 8];
}

__global__ __launch_bounds__(512, 4) void k_attn_mfma(
    const __bf16* __restrict__ qkv, const __bf16* __restrict__ Vt,
    __bf16* __restrict__ o)
{
    const int id = blockIdx.x;
    const int u  = id >> 6;            // 0..7
    const int pr = (u < 4) ? u : 11 - u;   // CU-pair balance: steps sum to 25
    const int b  = (id >> 3) & 7;
    const int h  = id & 7;             // id%8 = h -> blocks of one h share an XCD
    const int tid  = threadIdx.x;
    const int lane = tid & 63, wave = tid >> 6;   // 0..7
    const int m16  = lane & 15, quad = lane >> 4;
    const int isB  = wave >> 2;        // 0: tile A (qtA=pr), 1: tile B (qtB=15-pr)
    const int wave16 = (wave & 3) * 16;
    const int qtA  = pr, qtB = 15 - pr;
    const int qt   = isB ? qtB : qtA;

    __shared__ __bf16 Kb[2][64][64];     // double-buffered K tile (swizzled)
    __shared__ __bf16 Vb[2][64][64];     // double-buffered V tile (swizzled)
    __shared__ __bf16 Ps[8][16][72];     // per-wave P scratch

    const __bf16* base = qkv + (size_t)b * Sn * 1536 + h * DKn;   // Q +0, K +512
    const __bf16* vtb  = Vt + (size_t)(b * Hn + h) * DKn * Sn;
    __bf16 (*Pw)[72] = Ps[wave];

    // swizzled 16B-unit offsets for fragment reads (involution of stage swizzle)
    const int sw0 = ((quad    ) ^ (m16 & 7)) * 8;
    const int sw1 = ((quad + 4) ^ (m16 & 7)) * 8;

    // staging coords: 512 threads x 16B cover one 64x64 bf16 tile per call.
    // Exactly 2 VMEM ops per thread per STAGE (1 K + 1 V).
    const int srow = tid >> 3;
    const int ssu  = ((tid & 7) ^ (srow & 7)) * 8;

    #define STAGE(KT, BB)                                                       \
        {                                                                       \
            gl_lds16(base + (size_t)((KT) * 64 + srow) * 1536 + 512 + ssu,      \
                     (void*)(&Kb[BB][0][0] + tid * 8));                         \
            gl_lds16(vtb + (size_t)srow * Sn + (KT) * 64 + ssu,                 \
                     (void*)(&Vb[BB][0][0] + tid * 8));                         \
        }

    STAGE(0, 0);   // issue tile-0 staging first; Q loads overlap it

    bf16x8 q0, q1;
    {
        const __bf16* qa = base + (size_t)(qt * 64 + wave16 + m16) * 1536 + quad * 8;
        q0 = *(const bf16x8*)qa; q1 = *(const bf16x8*)(qa + 32);
    }

    float m[4], l[4];
    f32x4 acc[4];
    #pragma unroll
    for (int r = 0; r < 4; r++) {
        m[r] = -1e30f; l[r] = 0.f;
        acc[r] = (f32x4){0.f, 0.f, 0.f, 0.f};
    }

    for (int kt = 0; kt <= qtB; kt++) {
        const int buf = kt & 1;
        // issue next-tile staging, then wait only for CURRENT tile's loads:
        // exactly 2 loads (the new stage) remain outstanding across the barrier.
        if (kt < qtB) {
            STAGE(kt + 1, buf ^ 1);
            asm volatile("s_waitcnt vmcnt(2)" ::: "memory");
        } else {
            asm volatile("s_waitcnt vmcnt(0)" ::: "memory");
        }
        __builtin_amdgcn_s_barrier();   // cur buf fully written, all waves aligned

        if (isB || kt <= qtA) {
            // ---- S = Q K^T from LDS ----
            f32x4 sv[4];
            __builtin_amdgcn_s_setprio(1);
            #pragma unroll
            for (int j = 0; j < 4; j++) {
                const int rk = j * 16 + m16;
                bf16x8 kf0 = *(const bf16x8*)&Kb[buf][rk][sw0];
                bf16x8 kf1 = *(const bf16x8*)&Kb[buf][rk][sw1];
                f32x4 s = (f32x4){0.f, 0.f, 0.f, 0.f};
                s = __builtin_amdgcn_mfma_f32_16x16x32_bf16(q0, kf0, s, 0, 0, 0);
                s = __builtin_amdgcn_mfma_f32_16x16x32_bf16(q1, kf1, s, 0, 0, 0);
                sv[j] = s;
            }
            __builtin_amdgcn_s_setprio(0);

            // ---- V fragments from LDS (issued before softmax; latency hides) ----
            bf16x8 vf[4][2];
            #pragma unroll
            for (int jd = 0; jd < 4; jd++) {
                const int rv = jd * 16 + m16;
                vf[jd][0] = *(const bf16x8*)&Vb[buf][rv][sw0];
                vf[jd][1] = *(const bf16x8*)&Vb[buf][rv][sw1];
            }

            // ---- online softmax (per-wave LDS round-trip, in-order DS) ----
            bf16x8 p0, p1;
            softmax_update(sv, m, l, acc, kt == qt, wave16, quad, m16, Pw, p0, p1);

            // ---- O += P V ----
            __builtin_amdgcn_s_setprio(1);
            #pragma unroll
            for (int jd = 0; jd < 4; jd++) {
                acc[jd] = __builtin_amdgcn_mfma_f32_16x16x32_bf16(p0, vf[jd][0], acc[jd], 0, 0, 0);
                acc[jd] = __builtin_amdgcn_mfma_f32_16x16x32_bf16(p1, vf[jd][1], acc[jd], 0, 0, 0);
            }
            __builtin_amdgcn_s_setprio(0);
        }

        // my ds ops retired -> after the barrier the buffers may be overwritten
        asm volatile("s_waitcnt lgkmcnt(0)" ::: "memory");
        __builtin_amdgcn_s_barrier();
    }
    #undef STAGE

    // epilogue: O / l for own tile
    #pragma unroll
    for (int r = 0; r < 4; r++) l[r] = 1.0f / l[r];
    #pragma unroll
    for (int jd = 0; jd < 4; jd++)
        #pragma unroll
        for (int r = 0; r < 4; r++) {
            const int row = b * Sn + qt * 64 + wave16 + quad * 4 + r;
            o[(size_t)row * Dn + h * DKn + jd * 16 + m16] = (__bf16)(acc[jd][r] * l[r]);
        }
}

// ---------------------------------------------------------------------------
// Residual + LayerNorm, wave-per-row, barrier-free.
// Lane owns 8 consecutive cols (bf16x8 loads). 64-lane shfl_xor reductions.
// FINAL=0: xb = LN(t + xb) (bf16). FINAL=1: outf = LN(t + xb) (fp32).
// ---------------------------------------------------------------------------
template <int FINAL>
__global__ __launch_bounds__(256) void k_residual_ln(
    const __bf16* __restrict__ t, __bf16* __restrict__ xb,
    const float* __restrict__ g, const float* __restrict__ be,
    float* __restrict__ outf)
{
    const int row  = (blockIdx.x << 2) | (threadIdx.x >> 6);  // 4 rows/block
    const int lane = threadIdx.x & 63;
    const size_t base = (size_t)row * Dn + lane * 8;

    bf16x8 tv = *(const bf16x8*)&t[base];
    bf16x8 xv = *(const bf16x8*)&xb[base];
    float v[8];
    float s = 0.f;
    #pragma unroll
    for (int i = 0; i < 8; i++) {
        v[i] = (float)tv[i] + (float)xv[i];
        s += v[i];
    }
    #pragma unroll
    for (int off = 1; off < 64; off <<= 1) s += __shfl_xor(s, off);
    const float mean = s * (1.0f / Dn);

    float vs = 0.f;
    #pragma unroll
    for (int i = 0; i < 8; i++) {
        v[i] -= mean;
        vs += v[i] * v[i];
    }
    #pragma unroll
    for (int off = 1; off < 64; off <<= 1) vs += __shfl_xor(vs, off);
    const float inv = rsqrtf(vs * (1.0f / Dn) + 1e-5f);

    const f32x4 g0 = *(const f32x4*)&g[lane * 8];
    const f32x4 g1 = *(const f32x4*)&g[lane * 8 + 4];
    const f32x4 b0 = *(const f32x4*)&be[lane * 8];
    const f32x4 b1 = *(const f32x4*)&be[lane * 8 + 4];

    if (FINAL) {
        f32x4 o0, o1;
        #pragma unroll
        for (int i = 0; i < 4; i++) {
            o0[i] = v[i] * inv * g0[i] + b0[i];
            o1[i] = v[i + 4] * inv * g1[i] + b1[i];
        }
        *(f32x4*)&outf[base]     = o0;
        *(f32x4*)&outf[base + 4] = o1;
    } else {
        bf16x8 ov;
        #pragma unroll
        for (int i = 0; i < 4; i++) {
            ov[i]     = (__bf16)(v[i] * inv * g0[i] + b0[i]);
            ov[i + 4] = (__bf16)(v[i + 4] * inv * g1[i] + b1[i]);
        }
        *(bf16x8*)&xb[base] = ov;
    }
}

// ---------------------------------------------------------------------------
// launcher
// ---------------------------------------------------------------------------
extern "C" void kernel_launch(void* const* d_in, const int* in_sizes, int n_in,
                              void* d_out, int out_size, void* d_ws, size_t ws_size,
                              hipStream_t stream)
{
    const float* x_in   = (const float*)d_in[0];
    const float* qkv_w  = (const float*)d_in[1];
    const float* qkv_b  = (const float*)d_in[2];
    const float* out_w  = (const float*)d_in[3];
    const float* out_b  = (const float*)d_in[4];
    const float* ln1_g  = (const float*)d_in[5];
    const float* ln1_b  = (const float*)d_in[6];
    const float* mlp_w1 = (const float*)d_in[7];
    const float* mlp_b1 = (const float*)d_in[8];
    const float* mlp_w2 = (const float*)d_in[9];
    const float* mlp_b2 = (const float*)d_in[10];
    const float* ln2_g  = (const float*)d_in[11];
    const float* ln2_b  = (const float*)d_in[12];

    // workspace layout (~116 MB); residual lives in bf16 Xb only
    char* p = (char*)d_ws;
    __bf16* Xb    = (__bf16*)p; p += (size_t)Mn * Dn * 2;            //  8 MB
    __bf16* QKVb  = (__bf16*)p; p += (size_t)Mn * 3 * Dn * 2;        // 24 MB
    __bf16* AOb   = (__bf16*)p; p += (size_t)Mn * Dn * 2;            //  8 MB
    __bf16* Hb    = (__bf16*)p; p += (size_t)Mn * DFFn * 2;          // 32 MB
    __bf16* BUF3b = (__bf16*)p; p += (size_t)Mn * Dn * 2;            //  8 MB pre-LN temp
    __bf16* Wq    = (__bf16*)p; p += (size_t)Ln * 3 * Dn * Dn * 2;   //  9 MB
    __bf16* Wo    = (__bf16*)p; p += (size_t)Ln * Dn * Dn * 2;       //  3 MB
    __bf16* W1    = (__bf16*)p; p += (size_t)Ln * DFFn * Dn * 2;     // 12 MB
    __bf16* W2    = (__bf16*)p; p += (size_t)Ln * Dn * DFFn * 2;     // 12 MB
    __bf16* Vt    = Hb;   // 8 MB, aliased: Hb dead during attention

    k_cast_bf16<<<(Mn * Dn) / 256, 256, 0, stream>>>(x_in, Xb, Mn * Dn);

    // ALL weight transposes for all 6 layers in one launch (loop-invariant)
    k_trans_all<<<Ln * 3072, dim3(32, 8), 0, stream>>>(
        qkv_w, out_w, mlp_w1, mlp_w2, Wq, Wo, W1, W2);

    for (int l = 0; l < Ln; l++) {
        const __bf16* Wql = Wq + (size_t)l * 3 * Dn * Dn;
        const __bf16* Wol = Wo + (size_t)l * Dn * Dn;
        const __bf16* W1l = W1 + (size_t)l * DFFn * Dn;
        const __bf16* W2l = W2 + (size_t)l * Dn * DFFn;

        // QKV projection -> bf16 [M,1536] + fused Vt scatter
        k_gemm_mfma<0, 1, 4, 1, 64><<<768, 256, 0, stream>>>(
            Xb, Wql, qkv_b + (size_t)l * 3 * Dn, QKVb, Vt, Mn, 3 * Dn, Dn, 12);
        // MFMA flash attention (8 waves, pair split, counted vmcnt) -> bf16
        k_attn_mfma<<<512, 512, 0, stream>>>(QKVb, Vt, AOb);
        // output projection -> bf16 BUF3b  (BK=128: halved barrier drains)
        k_gemm_mfma<0, 1, 2, 0, 128><<<512, 256, 0, stream>>>(
            AOb, Wol, out_b + (size_t)l * Dn, BUF3b, nullptr, Mn, Dn, Dn, 8);
        // x = LN(proj + x)   (bf16 in/out, fp32 math, wave-per-row)
        k_residual_ln<0><<<Mn / 4, 256, 0, stream>>>(BUF3b, Xb,
            ln1_g + (size_t)l * Dn, ln1_b + (size_t)l * Dn, nullptr);
        // MLP up + ReLU -> bf16 [M,2048]  (overwrites Vt alias; attn done)
        k_gemm_mfma<1, 1, 4, 0, 64><<<1024, 256, 0, stream>>>(
            Xb, W1l, mlp_b1 + (size_t)l * DFFn, Hb, nullptr, Mn, DFFn, Dn, 16);
        // MLP down -> bf16 BUF3b  (BK=128)
        k_gemm_mfma<0, 1, 2, 0, 128><<<512, 256, 0, stream>>>(
            Hb, W2l, mlp_b2 + (size_t)l * Dn, BUF3b, nullptr, Mn, Dn, DFFn, 8);
        // x = LN(x + mlp); final layer writes fp32 straight to d_out
        if (l == Ln - 1)
            k_residual_ln<1><<<Mn / 4, 256, 0, stream>>>(BUF3b, Xb,
                ln2_g + (size_t)l * Dn, ln2_b + (size_t)l * Dn, (float*)d_out);
        else
            k_residual_ln<0><<<Mn / 4, 256, 0, stream>>>(BUF3b, Xb,
                ln2_g + (size_t)l * Dn, ln2_b + (size_t)l * Dn, nullptr);
    }
}

// Round 9
// 847.578 us; speedup vs baseline: 1.7458x; 1.1227x over previous
//
#include <hip/hip_runtime.h>
#include <math.h>

// Problem constants
#define Bn   8
#define Sn   1024
#define Dn   512
#define Hn   8
#define DKn  64
#define Ln   6
#define DFFn 2048
#define Mn   (Bn * Sn)   // 8192 rows

typedef __bf16 bf16x8 __attribute__((ext_vector_type(8)));
typedef __bf16 bf16x4 __attribute__((ext_vector_type(4)));
typedef __bf16 bf16x2 __attribute__((ext_vector_type(2)));
typedef float  f32x4  __attribute__((ext_vector_type(4)));

// async global->LDS, 16B per lane. LDS dest must be wave-uniform base + lane*16.
__device__ __forceinline__ void gl_lds16(const void* g, void* l) {
    __builtin_amdgcn_global_load_lds(
        (const __attribute__((address_space(1))) void*)g,
        (__attribute__((address_space(3))) void*)l, 16, 0, 0);
}

// ---------------------------------------------------------------------------
// fp32 -> bf16 cast (input)
// ---------------------------------------------------------------------------
__global__ __launch_bounds__(256) void k_cast_bf16(const float* __restrict__ in,
                                                   __bf16* __restrict__ out, int n) {
    int i = blockIdx.x * 256 + threadIdx.x;
    if (i < n) out[i] = (__bf16)in[i];
}

// ---------------------------------------------------------------------------
// ALL weight matrices of ALL 6 layers: W[K][N] fp32 -> Wt[N][K] bf16.
// One launch (weights are layer-loop invariant). 32x32 tiles, 32x8 threads.
// ---------------------------------------------------------------------------
__global__ __launch_bounds__(256) void k_trans_all(
    const float* __restrict__ qkv_w, const float* __restrict__ out_w,
    const float* __restrict__ w1, const float* __restrict__ w2,
    __bf16* __restrict__ Wq, __bf16* __restrict__ Wo,
    __bf16* __restrict__ W1o, __bf16* __restrict__ W2o)
{
    const int lay = blockIdx.x / 3072;
    const int t   = blockIdx.x % 3072;
    const float* src; __bf16* dst; int K, N, n0, k0;
    if (t < 768)       { src = qkv_w + (size_t)lay * Dn * 3 * Dn; dst = Wq  + (size_t)lay * 3 * Dn * Dn;
                         K = 512;  N = 1536; int u = t;        n0 = (u % 48) * 32; k0 = (u / 48) * 32; }
    else if (t < 1024) { src = out_w + (size_t)lay * Dn * Dn;     dst = Wo  + (size_t)lay * Dn * Dn;
                         K = 512;  N = 512;  int u = t - 768;  n0 = (u % 16) * 32; k0 = (u / 16) * 32; }
    else if (t < 2048) { src = w1 + (size_t)lay * Dn * DFFn;      dst = W1o + (size_t)lay * DFFn * Dn;
                         K = 512;  N = 2048; int u = t - 1024; n0 = (u % 64) * 32; k0 = (u / 64) * 32; }
    else               { src = w2 + (size_t)lay * DFFn * Dn;      dst = W2o + (size_t)lay * Dn * DFFn;
                         K = 2048; N = 512;  int u = t - 2048; n0 = (u % 16) * 32; k0 = (u / 16) * 32; }

    __shared__ float tt[32][33];
    const int tx = threadIdx.x, ty = threadIdx.y;
    #pragma unroll
    for (int r = 0; r < 4; r++)
        tt[ty + 8 * r][tx] = src[(size_t)(k0 + ty + 8 * r) * N + n0 + tx];
    __syncthreads();
    #pragma unroll
    for (int r = 0; r < 4; r++)
        dst[(size_t)(n0 + ty + 8 * r) * K + k0 + tx] = (__bf16)tt[tx][ty + 8 * r];
}

// ---------------------------------------------------------------------------
// MFMA GEMM: C[M,N] = act(A[M,K]bf16 @ Bt[N,K]bf16^T + bias[N]fp32)
// Block: 256 thr = 4 waves (2x2). Tile: 128 x (JT*32). K-step: BK (64 or 128).
// (a) 1D grid + bijective chunked XCD swizzle.
// (b) XOR LDS swizzle both-sides (rule #21): unit u' = u ^ (row & (UR-1)).
// BK=128 on JT=2 kernels (outproj/MLP-down): halved barrier-drain count.
// VW=1 (QKV only): cols >=1024 are V -> also scatter into Vt[b*8+h][d][s].
// ---------------------------------------------------------------------------
template <int RELU, int OUTBF, int JT, int VW, int BK>
__global__ __launch_bounds__(256) void k_gemm_mfma(
    const __bf16* __restrict__ A, const __bf16* __restrict__ Bt,
    const float* __restrict__ bias, void* __restrict__ Cout,
    __bf16* __restrict__ Vt, int M, int N, int K, int NBX)
{
    constexpr int BN = JT * 32;   // 128 or 64
    constexpr int UR = BK / 8;    // 16B units per LDS row
    constexpr int HC = BK / 32;   // K=32 chunks per K-step
    __shared__ __bf16 As[128][BK];
    __shared__ __bf16 Bs[BN][BK];
    const int tid  = threadIdx.x;
    const int lane = tid & 63;
    const int wave = tid >> 6;
    const int wy   = wave >> 1, wx = wave & 1;
    const int m16  = lane & 15, quad = lane >> 4;

    // chunked XCD swizzle (all launches have gridDim.x % 8 == 0)
    const int cpx = gridDim.x >> 3;
    const int id  = (blockIdx.x & 7) * cpx + (blockIdx.x >> 3);
    const int bm  = (id / NBX) * 128;
    const int bn  = (id % NBX) * BN;

    f32x4 acc[4][JT];
    #pragma unroll
    for (int i = 0; i < 4; i++)
        #pragma unroll
        for (int j = 0; j < JT; j++)
            acc[i][j] = (f32x4){0.f, 0.f, 0.f, 0.f};

    const __bf16* Ap = A  + (size_t)bm * K;
    const __bf16* Bp = Bt + (size_t)bn * K;

    // swizzled 16B-unit byte offsets for fragment reads (involution of stage)
    int sw[HC];
    #pragma unroll
    for (int hc = 0; hc < HC; hc++)
        sw[hc] = ((quad + 4 * hc) ^ (m16 & (UR - 1))) * 8;

    for (int k0 = 0; k0 < K; k0 += BK) {
        __syncthreads();
        #pragma unroll
        for (int c = 0; c < UR / 2; c++) {        // A: 128 x UR units
            int lin = tid + c * 256;
            int row = lin / UR, uu = lin % UR;
            int su  = (uu ^ (row & (UR - 1))) << 3;
            gl_lds16(Ap + (size_t)row * K + k0 + su, (void*)(&As[0][0] + lin * 8));
        }
        #pragma unroll
        for (int c = 0; c < (JT * UR) / 8; c++) { // B: BN x UR units
            int lin = tid + c * 256;
            int row = lin / UR, uu = lin % UR;
            int su  = (uu ^ (row & (UR - 1))) << 3;
            gl_lds16(Bp + (size_t)row * K + k0 + su, (void*)(&Bs[0][0] + lin * 8));
        }
        __syncthreads();

        bf16x8 af[4][HC], bfr[JT][HC];
        #pragma unroll
        for (int i = 0; i < 4; i++)
            #pragma unroll
            for (int hc = 0; hc < HC; hc++)
                af[i][hc] = *(const bf16x8*)&As[wy * 64 + i * 16 + m16][sw[hc]];
        #pragma unroll
        for (int j = 0; j < JT; j++)
            #pragma unroll
            for (int hc = 0; hc < HC; hc++)
                bfr[j][hc] = *(const bf16x8*)&Bs[wx * JT * 16 + j * 16 + m16][sw[hc]];
        #pragma unroll
        for (int hc = 0; hc < HC; hc++)
            #pragma unroll
            for (int i = 0; i < 4; i++)
                #pragma unroll
                for (int j = 0; j < JT; j++)
                    acc[i][j] = __builtin_amdgcn_mfma_f32_16x16x32_bf16(
                        af[i][hc], bfr[j][hc], acc[i][j], 0, 0, 0);
    }

    float*  Cf = (float*)Cout;
    __bf16* Cb = (__bf16*)Cout;
    #pragma unroll
    for (int i = 0; i < 4; i++) {
        const int row0 = bm + wy * 64 + i * 16 + quad * 4;
        #pragma unroll
        for (int j = 0; j < JT; j++) {
            const int col = bn + wx * JT * 16 + j * 16 + m16;
            const float bv = bias[col];
            float vv[4];
            #pragma unroll
            for (int r = 0; r < 4; r++) {
                float v = acc[i][j][r] + bv;
                if (RELU) v = fmaxf(v, 0.f);
                vv[r] = v;
                if (OUTBF) Cb[(size_t)(row0 + r) * N + col] = (__bf16)v;
                else       Cf[(size_t)(row0 + r) * N + col] = v;
            }
            if (VW && col >= 1024) {            // V slice -> Vt[b*8+h][d][s]
                const int cc = col - 1024;
                const int bb = row0 >> 10, ss = row0 & 1023;
                bf16x4 pv;
                #pragma unroll
                for (int r = 0; r < 4; r++) pv[r] = (__bf16)vv[r];
                *(bf16x4*)&Vt[((size_t)(bb * Hn + (cc >> 6)) * DKn + (cc & 63)) * Sn + ss] = pv;
            }
        }
    }
}

// ---------------------------------------------------------------------------
// MFMA flash attention (causal), LDS-staged K/V, wave-split tile pair,
// counted vmcnt (T4), SWAPPED QK^T (T12-style lane-local softmax).
// v9: S' = mfma(K_frag, Q_frag) — A/B fragments have identical layouts so
// loads are unchanged; C/D flips to S'[k=quad*4+r (+j*16)][q=m16]. Each
// thread then owns one q-row's softmax: max/sum = 15 local ops + 2 shfl_xor
// (16,32) on a SCALAR (was 32 shfl steps on 4 regs); m,l scalar; P-store is
// 4x ds_write_b64 contiguous (was 16x ds_write_b16); exp in log2 domain
// (v_exp native, scale folded with log2e). acc rows are q=quad*4+r, so the
// (rare) rescale broadcasts al via 4 width-16 shfls; epilogue shfls l.
// PV side unchanged: P read Pw[m16][quad*8+e] is exactly the A-fragment.
// ---------------------------------------------------------------------------
__device__ __forceinline__ void softmax_update_sw(
    f32x4 sv[4], float& m, float& l, f32x4 acc[4],
    bool diag, int wave16, int quad, int m16,
    __bf16 (*Pw)[72], bf16x8& pf0, bf16x8& pf1)
{
    const float SC = 0.125f * 1.44269504089f;   // 1/sqrt(64) * log2(e)
    float pmax = -1e30f;
    #pragma unroll
    for (int j = 0; j < 4; j++)
        #pragma unroll
        for (int r = 0; r < 4; r++) {
            float v = sv[j][r] * SC;
            if (diag && (j * 16 + quad * 4 + r) > (wave16 + m16)) v = -1e30f;
            sv[j][r] = v;
            pmax = fmaxf(pmax, v);
        }
    // cross-quad reduce: lanes {m16, m16+16, m16+32, m16+48} share q=m16
    pmax = fmaxf(pmax, __shfl_xor(pmax, 16));
    pmax = fmaxf(pmax, __shfl_xor(pmax, 32));

    // T13 defer-max (log2 domain; 11.54 = 8*log2e -> P bounded by e^8)
    if (__any((int)(pmax > m + 11.54f))) {
        float mn = fmaxf(m, pmax);
        float al = __builtin_amdgcn_exp2f(m - mn);
        m = mn;
        l *= al;
        float alr[4];
        #pragma unroll
        for (int r = 0; r < 4; r++) alr[r] = __shfl(al, quad * 4 + r, 16);
        #pragma unroll
        for (int j = 0; j < 4; j++)
            #pragma unroll
            for (int r = 0; r < 4; r++) acc[j][r] *= alr[r];
    }

    float rs = 0.f;
    #pragma unroll
    for (int j = 0; j < 4; j++) {
        bf16x4 pw;
        #pragma unroll
        for (int r = 0; r < 4; r++) {
            float p = __builtin_amdgcn_exp2f(sv[j][r] - m);
            rs += p;
            pw[r] = (__bf16)p;
        }
        *(bf16x4*)&Pw[m16][j * 16 + quad * 4] = pw;   // contiguous 8B store
    }
    rs += __shfl_xor(rs, 16);
    rs += __shfl_xor(rs, 32);
    l += rs;

    // per-wave in-order DS: the 4 writes above retire before these reads
    pf0 = *(const bf16x8*)&Pw[m16][quad * 8];
    pf1 = *(const bf16x8*)&Pw[m16][32 + quad * 8];
}

__global__ __launch_bounds__(512, 4) void k_attn_mfma(
    const __bf16* __restrict__ qkv, const __bf16* __restrict__ Vt,
    __bf16* __restrict__ o)
{
    const int id = blockIdx.x;
    const int u  = id >> 6;            // 0..7
    const int pr = (u < 4) ? u : 11 - u;   // CU-pair balance: steps sum to 25
    const int b  = (id >> 3) & 7;
    const int h  = id & 7;             // id%8 = h -> blocks of one h share an XCD
    const int tid  = threadIdx.x;
    const int lane = tid & 63, wave = tid >> 6;   // 0..7
    const int m16  = lane & 15, quad = lane >> 4;
    const int isB  = wave >> 2;        // 0: tile A (qtA=pr), 1: tile B (qtB=15-pr)
    const int wave16 = (wave & 3) * 16;
    const int qtA  = pr, qtB = 15 - pr;
    const int qt   = isB ? qtB : qtA;

    __shared__ __bf16 Kb[2][64][64];     // double-buffered K tile (swizzled)
    __shared__ __bf16 Vb[2][64][64];     // double-buffered V tile (swizzled)
    __shared__ __bf16 Ps[8][16][72];     // per-wave P scratch

    const __bf16* base = qkv + (size_t)b * Sn * 1536 + h * DKn;   // Q +0, K +512
    const __bf16* vtb  = Vt + (size_t)(b * Hn + h) * DKn * Sn;
    __bf16 (*Pw)[72] = Ps[wave];

    // swizzled 16B-unit offsets for fragment reads (involution of stage swizzle)
    const int sw0 = ((quad    ) ^ (m16 & 7)) * 8;
    const int sw1 = ((quad + 4) ^ (m16 & 7)) * 8;

    // staging coords: 512 threads x 16B cover one 64x64 bf16 tile per call.
    // Exactly 2 VMEM ops per thread per STAGE (1 K + 1 V).
    const int srow = tid >> 3;
    const int ssu  = ((tid & 7) ^ (srow & 7)) * 8;

    #define STAGE(KT, BB)                                                       \
        {                                                                       \
            gl_lds16(base + (size_t)((KT) * 64 + srow) * 1536 + 512 + ssu,      \
                     (void*)(&Kb[BB][0][0] + tid * 8));                         \
            gl_lds16(vtb + (size_t)srow * Sn + (KT) * 64 + ssu,                 \
                     (void*)(&Vb[BB][0][0] + tid * 8));                         \
        }

    STAGE(0, 0);   // issue tile-0 staging first; Q loads overlap it

    bf16x8 q0, q1;
    {
        const __bf16* qa = base + (size_t)(qt * 64 + wave16 + m16) * 1536 + quad * 8;
        q0 = *(const bf16x8*)qa; q1 = *(const bf16x8*)(qa + 32);
    }

    float m = -1e30f, l = 0.f;
    f32x4 acc[4];
    #pragma unroll
    for (int r = 0; r < 4; r++) acc[r] = (f32x4){0.f, 0.f, 0.f, 0.f};

    for (int kt = 0; kt <= qtB; kt++) {
        const int buf = kt & 1;
        // issue next-tile staging, then wait only for CURRENT tile's loads:
        // exactly 2 loads (the new stage) remain outstanding across the barrier.
        if (kt < qtB) {
            STAGE(kt + 1, buf ^ 1);
            asm volatile("s_waitcnt vmcnt(2)" ::: "memory");
        } else {
            asm volatile("s_waitcnt vmcnt(0)" ::: "memory");
        }
        __builtin_amdgcn_s_barrier();   // cur buf fully written, all waves aligned

        if (isB || kt <= qtA) {
            // ---- S' = K Q^T from LDS (swapped operands; loads unchanged) ----
            f32x4 sv[4];
            __builtin_amdgcn_s_setprio(1);
            #pragma unroll
            for (int j = 0; j < 4; j++) {
                const int rk = j * 16 + m16;
                bf16x8 kf0 = *(const bf16x8*)&Kb[buf][rk][sw0];
                bf16x8 kf1 = *(const bf16x8*)&Kb[buf][rk][sw1];
                f32x4 s = (f32x4){0.f, 0.f, 0.f, 0.f};
                s = __builtin_amdgcn_mfma_f32_16x16x32_bf16(kf0, q0, s, 0, 0, 0);
                s = __builtin_amdgcn_mfma_f32_16x16x32_bf16(kf1, q1, s, 0, 0, 0);
                sv[j] = s;
            }
            __builtin_amdgcn_s_setprio(0);

            // ---- V fragments from LDS (issued before softmax; latency hides) ----
            bf16x8 vf[4][2];
            #pragma unroll
            for (int jd = 0; jd < 4; jd++) {
                const int rv = jd * 16 + m16;
                vf[jd][0] = *(const bf16x8*)&Vb[buf][rv][sw0];
                vf[jd][1] = *(const bf16x8*)&Vb[buf][rv][sw1];
            }

            // ---- online softmax (lane-local q-row, scalar m/l) ----
            bf16x8 p0, p1;
            softmax_update_sw(sv, m, l, acc, kt == qt, wave16, quad, m16, Pw, p0, p1);

            // ---- O += P V ----
            __builtin_amdgcn_s_setprio(1);
            #pragma unroll
            for (int jd = 0; jd < 4; jd++) {
                acc[jd] = __builtin_amdgcn_mfma_f32_16x16x32_bf16(p0, vf[jd][0], acc[jd], 0, 0, 0);
                acc[jd] = __builtin_amdgcn_mfma_f32_16x16x32_bf16(p1, vf[jd][1], acc[jd], 0, 0, 0);
            }
            __builtin_amdgcn_s_setprio(0);
        }

        // my ds ops retired -> after the barrier the buffers may be overwritten
        asm volatile("s_waitcnt lgkmcnt(0)" ::: "memory");
        __builtin_amdgcn_s_barrier();
    }
    #undef STAGE

    // epilogue: O / l — l lives at lane q=m16; acc rows are q=quad*4+r
    float linv[4];
    #pragma unroll
    for (int r = 0; r < 4; r++) linv[r] = 1.0f / __shfl(l, quad * 4 + r, 16);
    #pragma unroll
    for (int jd = 0; jd < 4; jd++)
        #pragma unroll
        for (int r = 0; r < 4; r++) {
            const int row = b * Sn + qt * 64 + wave16 + quad * 4 + r;
            o[(size_t)row * Dn + h * DKn + jd * 16 + m16] = (__bf16)(acc[jd][r] * linv[r]);
        }
}

// ---------------------------------------------------------------------------
// Residual + LayerNorm, wave-per-row, barrier-free.
// Lane owns 8 consecutive cols (bf16x8 loads). 64-lane shfl_xor reductions.
// FINAL=0: xb = LN(t + xb) (bf16). FINAL=1: outf = LN(t + xb) (fp32).
// ---------------------------------------------------------------------------
template <int FINAL>
__global__ __launch_bounds__(256) void k_residual_ln(
    const __bf16* __restrict__ t, __bf16* __restrict__ xb,
    const float* __restrict__ g, const float* __restrict__ be,
    float* __restrict__ outf)
{
    const int row  = (blockIdx.x << 2) | (threadIdx.x >> 6);  // 4 rows/block
    const int lane = threadIdx.x & 63;
    const size_t base = (size_t)row * Dn + lane * 8;

    bf16x8 tv = *(const bf16x8*)&t[base];
    bf16x8 xv = *(const bf16x8*)&xb[base];
    float v[8];
    float s = 0.f;
    #pragma unroll
    for (int i = 0; i < 8; i++) {
        v[i] = (float)tv[i] + (float)xv[i];
        s += v[i];
    }
    #pragma unroll
    for (int off = 1; off < 64; off <<= 1) s += __shfl_xor(s, off);
    const float mean = s * (1.0f / Dn);

    float vs = 0.f;
    #pragma unroll
    for (int i = 0; i < 8; i++) {
        v[i] -= mean;
        vs += v[i] * v[i];
    }
    #pragma unroll
    for (int off = 1; off < 64; off <<= 1) vs += __shfl_xor(vs, off);
    const float inv = rsqrtf(vs * (1.0f / Dn) + 1e-5f);

    const f32x4 g0 = *(const f32x4*)&g[lane * 8];
    const f32x4 g1 = *(const f32x4*)&g[lane * 8 + 4];
    const f32x4 b0 = *(const f32x4*)&be[lane * 8];
    const f32x4 b1 = *(const f32x4*)&be[lane * 8 + 4];

    if (FINAL) {
        f32x4 o0, o1;
        #pragma unroll
        for (int i = 0; i < 4; i++) {
            o0[i] = v[i] * inv * g0[i] + b0[i];
            o1[i] = v[i + 4] * inv * g1[i] + b1[i];
        }
        *(f32x4*)&outf[base]     = o0;
        *(f32x4*)&outf[base + 4] = o1;
    } else {
        bf16x8 ov;
        #pragma unroll
        for (int i = 0; i < 4; i++) {
            ov[i]     = (__bf16)(v[i] * inv * g0[i] + b0[i]);
            ov[i + 4] = (__bf16)(v[i + 4] * inv * g1[i] + b1[i]);
        }
        *(bf16x8*)&xb[base] = ov;
    }
}

// ---------------------------------------------------------------------------
// launcher
// ---------------------------------------------------------------------------
extern "C" void kernel_launch(void* const* d_in, const int* in_sizes, int n_in,
                              void* d_out, int out_size, void* d_ws, size_t ws_size,
                              hipStream_t stream)
{
    const float* x_in   = (const float*)d_in[0];
    const float* qkv_w  = (const float*)d_in[1];
    const float* qkv_b  = (const float*)d_in[2];
    const float* out_w  = (const float*)d_in[3];
    const float* out_b  = (const float*)d_in[4];
    const float* ln1_g  = (const float*)d_in[5];
    const float* ln1_b  = (const float*)d_in[6];
    const float* mlp_w1 = (const float*)d_in[7];
    const float* mlp_b1 = (const float*)d_in[8];
    const float* mlp_w2 = (const float*)d_in[9];
    const float* mlp_b2 = (const float*)d_in[10];
    const float* ln2_g  = (const float*)d_in[11];
    const float* ln2_b  = (const float*)d_in[12];

    // workspace layout (~116 MB); residual lives in bf16 Xb only
    char* p = (char*)d_ws;
    __bf16* Xb    = (__bf16*)p; p += (size_t)Mn * Dn * 2;            //  8 MB
    __bf16* QKVb  = (__bf16*)p; p += (size_t)Mn * 3 * Dn * 2;        // 24 MB
    __bf16* AOb   = (__bf16*)p; p += (size_t)Mn * Dn * 2;            //  8 MB
    __bf16* Hb    = (__bf16*)p; p += (size_t)Mn * DFFn * 2;          // 32 MB
    __bf16* BUF3b = (__bf16*)p; p += (size_t)Mn * Dn * 2;            //  8 MB pre-LN temp
    __bf16* Wq    = (__bf16*)p; p += (size_t)Ln * 3 * Dn * Dn * 2;   //  9 MB
    __bf16* Wo    = (__bf16*)p; p += (size_t)Ln * Dn * Dn * 2;       //  3 MB
    __bf16* W1    = (__bf16*)p; p += (size_t)Ln * DFFn * Dn * 2;     // 12 MB
    __bf16* W2    = (__bf16*)p; p += (size_t)Ln * Dn * DFFn * 2;     // 12 MB
    __bf16* Vt    = Hb;   // 8 MB, aliased: Hb dead during attention

    k_cast_bf16<<<(Mn * Dn) / 256, 256, 0, stream>>>(x_in, Xb, Mn * Dn);

    // ALL weight transposes for all 6 layers in one launch (loop-invariant)
    k_trans_all<<<Ln * 3072, dim3(32, 8), 0, stream>>>(
        qkv_w, out_w, mlp_w1, mlp_w2, Wq, Wo, W1, W2);

    for (int l = 0; l < Ln; l++) {
        const __bf16* Wql = Wq + (size_t)l * 3 * Dn * Dn;
        const __bf16* Wol = Wo + (size_t)l * Dn * Dn;
        const __bf16* W1l = W1 + (size_t)l * DFFn * Dn;
        const __bf16* W2l = W2 + (size_t)l * Dn * DFFn;

        // QKV projection -> bf16 [M,1536] + fused Vt scatter
        k_gemm_mfma<0, 1, 4, 1, 64><<<768, 256, 0, stream>>>(
            Xb, Wql, qkv_b + (size_t)l * 3 * Dn, QKVb, Vt, Mn, 3 * Dn, Dn, 12);
        // MFMA flash attention (pair split, counted vmcnt, swapped QK) -> bf16
        k_attn_mfma<<<512, 512, 0, stream>>>(QKVb, Vt, AOb);
        // output projection -> bf16 BUF3b  (BK=128: halved barrier drains)
        k_gemm_mfma<0, 1, 2, 0, 128><<<512, 256, 0, stream>>>(
            AOb, Wol, out_b + (size_t)l * Dn, BUF3b, nullptr, Mn, Dn, Dn, 8);
        // x = LN(proj + x)   (bf16 in/out, fp32 math, wave-per-row)
        k_residual_ln<0><<<Mn / 4, 256, 0, stream>>>(BUF3b, Xb,
            ln1_g + (size_t)l * Dn, ln1_b + (size_t)l * Dn, nullptr);
        // MLP up + ReLU -> bf16 [M,2048]  (overwrites Vt alias; attn done)
        k_gemm_mfma<1, 1, 4, 0, 64><<<1024, 256, 0, stream>>>(
            Xb, W1l, mlp_b1 + (size_t)l * DFFn, Hb, nullptr, Mn, DFFn, Dn, 16);
        // MLP down -> bf16 BUF3b  (BK=128)
        k_gemm_mfma<0, 1, 2, 0, 128><<<512, 256, 0, stream>>>(
            Hb, W2l, mlp_b2 + (size_t)l * Dn, BUF3b, nullptr, Mn, Dn, DFFn, 8);
        // x = LN(x + mlp); final layer writes fp32 straight to d_out
        if (l == Ln - 1)
            k_residual_ln<1><<<Mn / 4, 256, 0, stream>>>(BUF3b, Xb,
                ln2_g + (size_t)l * Dn, ln2_b + (size_t)l * Dn, (float*)d_out);
        else
            k_residual_ln<0><<<Mn / 4, 256, 0, stream>>>(BUF3b, Xb,
                ln2_g + (size_t)l * Dn, ln2_b + (size_t)l * Dn, nullptr);
    }
}